// Round 1
// baseline (753.146 us; speedup 1.0000x reference)
//
#include <hip/hip_runtime.h>
#include <hip/hip_bf16.h>
#include <math.h>

typedef __attribute__((ext_vector_type(8))) short short8;
typedef __attribute__((ext_vector_type(4))) float floatx4;
typedef __attribute__((ext_vector_type(4))) unsigned short ushortx4;

__device__ __forceinline__ float bf2f(unsigned short u) {
    union { unsigned int i; float f; } c; c.i = ((unsigned int)u) << 16; return c.f;
}
__device__ __forceinline__ unsigned short f2bf(float f) {
    union { float f; unsigned int i; } c; c.f = f;
    unsigned int x = c.i;
    return (unsigned short)((x + 0x7FFFu + ((x >> 16) & 1u)) >> 16);
}

// ---------------- CSR build ----------------
__global__ void k_zero(int* p, int n) {
    int i = blockIdx.x * blockDim.x + threadIdx.x;
    if (i < n) p[i] = 0;
}

__global__ void k_count(const int* dst, int E, int* deg) {
    int e = blockIdx.x * blockDim.x + threadIdx.x;
    if (e < E) atomicAdd(&deg[dst[e]], 1);
}

// single-block chunked exclusive scan: deg[N] -> rowptr[N+1]
__global__ void k_scan(const int* deg, int* rowptr, int N) {
    __shared__ int sums[1024];
    int t = threadIdx.x;
    int C = (N + 1023) >> 10;
    int lo = t * C;
    int hi = min(lo + C, N);
    int s = 0;
    for (int i = lo; i < hi; i++) s += deg[i];
    sums[t] = s;
    __syncthreads();
    for (int off = 1; off < 1024; off <<= 1) {
        int v = (t >= off) ? sums[t - off] : 0;
        __syncthreads();
        sums[t] += v;
        __syncthreads();
    }
    int run = (t == 0) ? 0 : sums[t - 1];
    for (int i = lo; i < hi; i++) { rowptr[i] = run; run += deg[i]; }
    if (hi == N) rowptr[N] = run;
}

__global__ void k_fill(const int* src, const int* dst, int E, const int* rowptr,
                       int* cursor, int* adj) {
    int e = blockIdx.x * blockDim.x + threadIdx.x;
    if (e < E) {
        int d = dst[e];
        int slot = atomicAdd(&cursor[d], 1);
        adj[rowptr[d] + slot] = src[e];
    }
}

// ---------------- dtype conversion ----------------
__global__ void k_cvt(const float* x, unsigned short* xb, int n) {
    int i = blockIdx.x * blockDim.x + threadIdx.x;
    int idx = i * 4;
    if (idx < n) {
        float4 v = *(const float4*)(x + idx);
        ushortx4 o;
        o[0] = f2bf(v.x); o[1] = f2bf(v.y); o[2] = f2bf(v.z); o[3] = f2bf(v.w);
        *(ushortx4*)(xb + idx) = o;
    }
}

// arrange W2 = [Wl^T ; Wr^T] (256 x Do) into MFMA B-fragment order:
// w2f[((ks*NOC+oc)*64+lane)*8 + j] = W2[ks*32 + (lane>>4)*8 + j][oc*16 + (lane&15)]
__global__ void k_prep_w(const float* Wl, const float* Wr, unsigned short* w2f, int Do) {
    int t = blockIdx.x * blockDim.x + threadIdx.x;
    int NOC = Do >> 4;
    int total = 8 * NOC * 64 * 8;
    if (t >= total) return;
    int j = t & 7;
    int lane = (t >> 3) & 63;
    int rest = t >> 9;
    int oc = rest % NOC;
    int ks = rest / NOC;
    int k = ks * 32 + ((lane >> 4) << 3) + j;
    int o = oc * 16 + (lane & 15);
    float v = (k < 128) ? Wl[o * 128 + k] : Wr[o * 128 + (k - 128)];
    w2f[t] = f2bf(v);
}

// ---------------- mean aggregation (32-lane group per node) ----------------
__global__ void k_aggr(const unsigned short* feat, const int* rowptr, const int* adj,
                       unsigned short* aggr, int N) {
    int g = (blockIdx.x * blockDim.x + threadIdx.x) >> 5;
    int lane = threadIdx.x & 31;
    if (g >= N) return;
    int lo = rowptr[g], hi = rowptr[g + 1];
    float a0 = 0.f, a1 = 0.f, a2 = 0.f, a3 = 0.f;
    int col = lane * 4;
    for (int j = lo; j < hi; j++) {
        int s = adj[j];
        ushortx4 v = *(const ushortx4*)(feat + (size_t)s * 128 + col);
        a0 += bf2f(v[0]); a1 += bf2f(v[1]); a2 += bf2f(v[2]); a3 += bf2f(v[3]);
    }
    float inv = 1.0f / (float)max(hi - lo, 1);
    ushortx4 o;
    o[0] = f2bf(a0 * inv); o[1] = f2bf(a1 * inv); o[2] = f2bf(a2 * inv); o[3] = f2bf(a3 * inv);
    *(ushortx4*)(aggr + (size_t)g * 128 + col) = o;
}

// ---------------- fused transform: out = [aggr|feat] @ W2 + b (+relu) ----------------
template <int DO, bool RELU, bool OUTBF>
__global__ __launch_bounds__(256) void k_xform(const unsigned short* aggr,
                                               const unsigned short* feat,
                                               const unsigned short* w2f,
                                               const float* bias, void* outp, int N) {
    const int wave = threadIdx.x >> 6;
    const int lane = threadIdx.x & 63;
    const int nodeBase = blockIdx.x * 64 + wave * 16;
    const int row = nodeBase + (lane & 15);
    const int kq = lane >> 4;  // 0..3
    constexpr int NOC = DO / 16;
    floatx4 acc[NOC];
#pragma unroll
    for (int i = 0; i < NOC; i++) acc[i] = (floatx4)0.0f;
    const bool rowOK = row < N;
    const unsigned short* arow = aggr + (size_t)row * 128;
    const unsigned short* frow = feat + (size_t)row * 128;
    const short8* bbase = (const short8*)w2f;
#pragma unroll
    for (int ks = 0; ks < 8; ks++) {
        short8 a;
        if (rowOK) {
            const unsigned short* srcp =
                (ks < 4) ? (arow + ks * 32 + kq * 8) : (frow + (ks - 4) * 32 + kq * 8);
            a = *(const short8*)srcp;
        } else {
            a = (short8)0;
        }
#pragma unroll
        for (int oc = 0; oc < NOC; oc++) {
            short8 b = bbase[(ks * NOC + oc) * 64 + lane];
            acc[oc] = __builtin_amdgcn_mfma_f32_16x16x32_bf16(a, b, acc[oc], 0, 0, 0);
        }
    }
#pragma unroll
    for (int oc = 0; oc < NOC; oc++) {
        int o = oc * 16 + (lane & 15);
        float bv = bias[o];
#pragma unroll
        for (int j = 0; j < 4; j++) {
            int node = nodeBase + kq * 4 + j;
            if (node < N) {
                float v = acc[oc][j] + bv;
                if (RELU) v = fmaxf(v, 0.0f);
                if (OUTBF)
                    ((unsigned short*)outp)[(size_t)node * DO + o] = f2bf(v);
                else
                    ((float*)outp)[(size_t)node * DO + o] = v;
            }
        }
    }
}

// ---------------- row-wise log_softmax (in place, 64 cols, wave per row) ----------------
__global__ void k_lsm(float* out, int N) {
    int wave = threadIdx.x >> 6;
    int lane = threadIdx.x & 63;
    int rowi = blockIdx.x * 4 + wave;
    if (rowi >= N) return;
    float v = out[(size_t)rowi * 64 + lane];
    float m = v;
    for (int off = 32; off; off >>= 1) m = fmaxf(m, __shfl_xor(m, off, 64));
    float e = expf(v - m);
    float s = e;
    for (int off = 32; off; off >>= 1) s += __shfl_xor(s, off, 64);
    out[(size_t)rowi * 64 + lane] = v - m - logf(s);
}

extern "C" void kernel_launch(void* const* d_in, const int* in_sizes, int n_in,
                              void* d_out, int out_size, void* d_ws, size_t ws_size,
                              hipStream_t stream) {
    const float* x = (const float*)d_in[0];
    const int* ei = (const int*)d_in[1];
    const float* Wl0 = (const float*)d_in[2];
    const float* bl0 = (const float*)d_in[3];
    const float* Wr0 = (const float*)d_in[4];
    const float* Wl1 = (const float*)d_in[5];
    const float* bl1 = (const float*)d_in[6];
    const float* Wr1 = (const float*)d_in[7];
    const float* Wl2 = (const float*)d_in[8];
    const float* bl2 = (const float*)d_in[9];
    const float* Wr2 = (const float*)d_in[10];

    const int N = in_sizes[0] / 128;
    const int E = in_sizes[1] / 2;
    const int* src = ei;
    const int* dst = ei + E;

    char* ws = (char*)d_ws;
    size_t off = 0;
    auto alloc = [&](size_t bytes) {
        void* p = ws + off;
        off += (bytes + 255) & ~(size_t)255;
        return p;
    };
    int* deg = (int*)alloc((size_t)N * 4);
    int* cursor = (int*)alloc((size_t)N * 4);
    int* rowptr = (int*)alloc((size_t)(N + 1) * 4);
    int* adj = (int*)alloc((size_t)E * 4);
    unsigned short* xb = (unsigned short*)alloc((size_t)N * 128 * 2);
    unsigned short* aggr = (unsigned short*)alloc((size_t)N * 128 * 2);
    unsigned short* hA = (unsigned short*)alloc((size_t)N * 128 * 2);
    unsigned short* hB = (unsigned short*)alloc((size_t)N * 128 * 2);
    unsigned short* w0 = (unsigned short*)alloc(8 * 8 * 64 * 8 * 2);
    unsigned short* w1 = (unsigned short*)alloc(8 * 8 * 64 * 8 * 2);
    unsigned short* w2 = (unsigned short*)alloc(8 * 4 * 64 * 8 * 2);

    // CSR build
    k_zero<<<(2 * N + 255) / 256, 256, 0, stream>>>(deg, N);      // deg
    k_zero<<<(N + 255) / 256, 256, 0, stream>>>(cursor, N);       // cursor
    k_count<<<(E + 255) / 256, 256, 0, stream>>>(dst, E, deg);
    k_scan<<<1, 1024, 0, stream>>>(deg, rowptr, N);
    k_fill<<<(E + 255) / 256, 256, 0, stream>>>(src, dst, E, rowptr, cursor, adj);

    // conversions / weight prep
    k_cvt<<<((N * 128 / 4) + 255) / 256, 256, 0, stream>>>(x, xb, N * 128);
    k_prep_w<<<(32768 + 255) / 256, 256, 0, stream>>>(Wl0, Wr0, w0, 128);
    k_prep_w<<<(32768 + 255) / 256, 256, 0, stream>>>(Wl1, Wr1, w1, 128);
    k_prep_w<<<(16384 + 255) / 256, 256, 0, stream>>>(Wl2, Wr2, w2, 64);

    const int aggrGrid = ((N * 32) + 255) / 256;
    const int xfGrid = (N + 63) / 64;

    // layer 0
    k_aggr<<<aggrGrid, 256, 0, stream>>>(xb, rowptr, adj, aggr, N);
    k_xform<128, true, true><<<xfGrid, 256, 0, stream>>>(aggr, xb, w0, bl0, hA, N);
    // layer 1
    k_aggr<<<aggrGrid, 256, 0, stream>>>(hA, rowptr, adj, aggr, N);
    k_xform<128, true, true><<<xfGrid, 256, 0, stream>>>(aggr, hA, w1, bl1, hB, N);
    // layer 2
    k_aggr<<<aggrGrid, 256, 0, stream>>>(hB, rowptr, adj, aggr, N);
    k_xform<64, false, false><<<xfGrid, 256, 0, stream>>>(aggr, hB, w2, bl2, d_out, N);

    // log_softmax
    k_lsm<<<(N + 3) / 4, 256, 0, stream>>>((float*)d_out, N);
}

// Round 2
// 587.674 us; speedup vs baseline: 1.2816x; 1.2816x over previous
//
#include <hip/hip_runtime.h>
#include <hip/hip_bf16.h>
#include <math.h>

typedef __attribute__((ext_vector_type(8))) short short8;
typedef __attribute__((ext_vector_type(4))) float floatx4;
typedef __attribute__((ext_vector_type(4))) unsigned short ushortx4;

__device__ __forceinline__ float bf2f(unsigned short u) {
    union { unsigned int i; float f; } c; c.i = ((unsigned int)u) << 16; return c.f;
}
__device__ __forceinline__ unsigned short f2bf(float f) {
    union { float f; unsigned int i; } c; c.f = f;
    unsigned int x = c.i;
    return (unsigned short)((x + 0x7FFFu + ((x >> 16) & 1u)) >> 16);
}

// ---------------- CSR build ----------------
__global__ void k_zero(int* p, int n) {
    int i = blockIdx.x * blockDim.x + threadIdx.x;
    if (i < n) p[i] = 0;
}

__global__ void k_count(const int* dst, int E, int* deg) {
    int e = blockIdx.x * blockDim.x + threadIdx.x;
    if (e < E) atomicAdd(&deg[dst[e]], 1);
}

// ---- hierarchical exclusive scan: deg[N] -> rowptr[N+1] ----
constexpr int SCAN_T = 256;
constexpr int SCAN_V = 8;
constexpr int SCAN_CHUNK = SCAN_T * SCAN_V;  // 2048 elems per block

__global__ void k_scan_part(const int* deg, int* bsum, int N) {
    int b = blockIdx.x, t = threadIdx.x;
    int base = b * SCAN_CHUNK + t * SCAN_V;
    int s = 0;
#pragma unroll
    for (int j = 0; j < SCAN_V; j++) {
        int i = base + j;
        if (i < N) s += deg[i];
    }
    __shared__ int wsums[SCAN_T / 64];
    for (int off = 32; off; off >>= 1) s += __shfl_down(s, off, 64);
    if ((t & 63) == 0) wsums[t >> 6] = s;
    __syncthreads();
    if (t == 0) {
        int tot = 0;
#pragma unroll
        for (int w = 0; w < SCAN_T / 64; w++) tot += wsums[w];
        bsum[b] = tot;
    }
}

__global__ void k_scan_top(int* bsum, int nb) {
    if (threadIdx.x == 0) {
        int run = 0;
        for (int i = 0; i < nb; i++) {
            int v = bsum[i];
            bsum[i] = run;
            run += v;
        }
    }
}

__global__ void k_scan_apply(const int* deg, const int* bsum, int* rowptr, int N) {
    int b = blockIdx.x, t = threadIdx.x;
    int base = b * SCAN_CHUNK + t * SCAN_V;
    int v[SCAN_V];
    int s = 0;
#pragma unroll
    for (int j = 0; j < SCAN_V; j++) {
        int i = base + j;
        v[j] = (i < N) ? deg[i] : 0;
        s += v[j];
    }
    __shared__ int sums[SCAN_T];
    sums[t] = s;
    __syncthreads();
    for (int off = 1; off < SCAN_T; off <<= 1) {
        int x = (t >= off) ? sums[t - off] : 0;
        __syncthreads();
        sums[t] += x;
        __syncthreads();
    }
    int pre = bsum[b] + ((t == 0) ? 0 : sums[t - 1]);
#pragma unroll
    for (int j = 0; j < SCAN_V; j++) {
        int i = base + j;
        if (i < N) {
            rowptr[i] = pre;
            pre += v[j];
            if (i == N - 1) rowptr[N] = pre;
        }
    }
}

__global__ void k_fill(const int* src, const int* dst, int E, const int* rowptr,
                       int* cursor, int* adj) {
    int e = blockIdx.x * blockDim.x + threadIdx.x;
    if (e < E) {
        int d = dst[e];
        int slot = atomicAdd(&cursor[d], 1);
        adj[rowptr[d] + slot] = src[e];
    }
}

// ---------------- dtype conversion ----------------
__global__ void k_cvt(const float* x, unsigned short* xb, int n) {
    int i = blockIdx.x * blockDim.x + threadIdx.x;
    int idx = i * 4;
    if (idx < n) {
        float4 v = *(const float4*)(x + idx);
        ushortx4 o;
        o[0] = f2bf(v.x); o[1] = f2bf(v.y); o[2] = f2bf(v.z); o[3] = f2bf(v.w);
        *(ushortx4*)(xb + idx) = o;
    }
}

// arrange W2 = [Wl^T ; Wr^T] (256 x Do) into MFMA B-fragment order:
// w2f[((ks*NOC+oc)*64+lane)*8 + j] = W2[ks*32 + (lane>>4)*8 + j][oc*16 + (lane&15)]
__global__ void k_prep_w(const float* Wl, const float* Wr, unsigned short* w2f, int Do) {
    int t = blockIdx.x * blockDim.x + threadIdx.x;
    int NOC = Do >> 4;
    int total = 8 * NOC * 64 * 8;
    if (t >= total) return;
    int j = t & 7;
    int lane = (t >> 3) & 63;
    int rest = t >> 9;
    int oc = rest % NOC;
    int ks = rest / NOC;
    int k = ks * 32 + ((lane >> 4) << 3) + j;
    int o = oc * 16 + (lane & 15);
    float v = (k < 128) ? Wl[o * 128 + k] : Wr[o * 128 + (k - 128)];
    w2f[t] = f2bf(v);
}

// ---------------- mean aggregation (32-lane group per node) ----------------
__global__ void k_aggr(const unsigned short* feat, const int* rowptr, const int* adj,
                       unsigned short* aggr, int N) {
    int g = (blockIdx.x * blockDim.x + threadIdx.x) >> 5;
    int lane = threadIdx.x & 31;
    if (g >= N) return;
    int lo = rowptr[g], hi = rowptr[g + 1];
    float a0 = 0.f, a1 = 0.f, a2 = 0.f, a3 = 0.f;
    int col = lane * 4;
    for (int j = lo; j < hi; j++) {
        int s = adj[j];
        ushortx4 v = *(const ushortx4*)(feat + (size_t)s * 128 + col);
        a0 += bf2f(v[0]); a1 += bf2f(v[1]); a2 += bf2f(v[2]); a3 += bf2f(v[3]);
    }
    float inv = 1.0f / (float)max(hi - lo, 1);
    ushortx4 o;
    o[0] = f2bf(a0 * inv); o[1] = f2bf(a1 * inv); o[2] = f2bf(a2 * inv); o[3] = f2bf(a3 * inv);
    *(ushortx4*)(aggr + (size_t)g * 128 + col) = o;
}

// ---------------- fused transform: out = [aggr|feat] @ W2 + b (+relu) ----------------
template <int DO, bool RELU, bool OUTBF>
__global__ __launch_bounds__(256) void k_xform(const unsigned short* aggr,
                                               const unsigned short* feat,
                                               const unsigned short* w2f,
                                               const float* bias, void* outp, int N) {
    const int wave = threadIdx.x >> 6;
    const int lane = threadIdx.x & 63;
    const int nodeBase = blockIdx.x * 64 + wave * 16;
    const int row = nodeBase + (lane & 15);
    const int kq = lane >> 4;  // 0..3
    constexpr int NOC = DO / 16;
    floatx4 acc[NOC];
#pragma unroll
    for (int i = 0; i < NOC; i++) acc[i] = (floatx4)0.0f;
    const bool rowOK = row < N;
    const unsigned short* arow = aggr + (size_t)row * 128;
    const unsigned short* frow = feat + (size_t)row * 128;
    const short8* bbase = (const short8*)w2f;
#pragma unroll
    for (int ks = 0; ks < 8; ks++) {
        short8 a;
        if (rowOK) {
            const unsigned short* srcp =
                (ks < 4) ? (arow + ks * 32 + kq * 8) : (frow + (ks - 4) * 32 + kq * 8);
            a = *(const short8*)srcp;
        } else {
            a = (short8)0;
        }
#pragma unroll
        for (int oc = 0; oc < NOC; oc++) {
            short8 b = bbase[(ks * NOC + oc) * 64 + lane];
            acc[oc] = __builtin_amdgcn_mfma_f32_16x16x32_bf16(a, b, acc[oc], 0, 0, 0);
        }
    }
#pragma unroll
    for (int oc = 0; oc < NOC; oc++) {
        int o = oc * 16 + (lane & 15);
        float bv = bias[o];
#pragma unroll
        for (int j = 0; j < 4; j++) {
            int node = nodeBase + kq * 4 + j;
            if (node < N) {
                float v = acc[oc][j] + bv;
                if (RELU) v = fmaxf(v, 0.0f);
                if (OUTBF)
                    ((unsigned short*)outp)[(size_t)node * DO + o] = f2bf(v);
                else
                    ((float*)outp)[(size_t)node * DO + o] = v;
            }
        }
    }
}

// ---------------- row-wise log_softmax (in place, 64 cols, wave per row) ----------------
__global__ void k_lsm(float* out, int N) {
    int wave = threadIdx.x >> 6;
    int lane = threadIdx.x & 63;
    int rowi = blockIdx.x * 4 + wave;
    if (rowi >= N) return;
    float v = out[(size_t)rowi * 64 + lane];
    float m = v;
    for (int off = 32; off; off >>= 1) m = fmaxf(m, __shfl_xor(m, off, 64));
    float e = expf(v - m);
    float s = e;
    for (int off = 32; off; off >>= 1) s += __shfl_xor(s, off, 64);
    out[(size_t)rowi * 64 + lane] = v - m - logf(s);
}

extern "C" void kernel_launch(void* const* d_in, const int* in_sizes, int n_in,
                              void* d_out, int out_size, void* d_ws, size_t ws_size,
                              hipStream_t stream) {
    const float* x = (const float*)d_in[0];
    const int* ei = (const int*)d_in[1];
    const float* Wl0 = (const float*)d_in[2];
    const float* bl0 = (const float*)d_in[3];
    const float* Wr0 = (const float*)d_in[4];
    const float* Wl1 = (const float*)d_in[5];
    const float* bl1 = (const float*)d_in[6];
    const float* Wr1 = (const float*)d_in[7];
    const float* Wl2 = (const float*)d_in[8];
    const float* bl2 = (const float*)d_in[9];
    const float* Wr2 = (const float*)d_in[10];

    const int N = in_sizes[0] / 128;
    const int E = in_sizes[1] / 2;
    const int* src = ei;
    const int* dst = ei + E;

    char* ws = (char*)d_ws;
    size_t off = 0;
    auto alloc = [&](size_t bytes) {
        void* p = ws + off;
        off += (bytes + 255) & ~(size_t)255;
        return p;
    };
    int* deg = (int*)alloc((size_t)N * 4);
    int* cursor = (int*)alloc((size_t)N * 4);
    int* rowptr = (int*)alloc((size_t)(N + 1) * 4);
    int* bsum = (int*)alloc(1024 * 4);
    int* adj = (int*)alloc((size_t)E * 4);
    unsigned short* xb = (unsigned short*)alloc((size_t)N * 128 * 2);
    unsigned short* aggr = (unsigned short*)alloc((size_t)N * 128 * 2);
    unsigned short* hA = (unsigned short*)alloc((size_t)N * 128 * 2);
    unsigned short* hB = (unsigned short*)alloc((size_t)N * 128 * 2);
    unsigned short* w0 = (unsigned short*)alloc(8 * 8 * 64 * 8 * 2);
    unsigned short* w1 = (unsigned short*)alloc(8 * 8 * 64 * 8 * 2);
    unsigned short* w2 = (unsigned short*)alloc(8 * 4 * 64 * 8 * 2);

    // CSR build
    k_zero<<<(N + 255) / 256, 256, 0, stream>>>(deg, N);
    k_zero<<<(N + 255) / 256, 256, 0, stream>>>(cursor, N);
    k_count<<<(E + 255) / 256, 256, 0, stream>>>(dst, E, deg);
    const int nScanBlocks = (N + SCAN_CHUNK - 1) / SCAN_CHUNK;
    k_scan_part<<<nScanBlocks, SCAN_T, 0, stream>>>(deg, bsum, N);
    k_scan_top<<<1, 64, 0, stream>>>(bsum, nScanBlocks);
    k_scan_apply<<<nScanBlocks, SCAN_T, 0, stream>>>(deg, bsum, rowptr, N);
    k_fill<<<(E + 255) / 256, 256, 0, stream>>>(src, dst, E, rowptr, cursor, adj);

    // conversions / weight prep
    k_cvt<<<((N * 128 / 4) + 255) / 256, 256, 0, stream>>>(x, xb, N * 128);
    k_prep_w<<<(32768 + 255) / 256, 256, 0, stream>>>(Wl0, Wr0, w0, 128);
    k_prep_w<<<(32768 + 255) / 256, 256, 0, stream>>>(Wl1, Wr1, w1, 128);
    k_prep_w<<<(16384 + 255) / 256, 256, 0, stream>>>(Wl2, Wr2, w2, 64);

    const int aggrGrid = ((N * 32) + 255) / 256;
    const int xfGrid = (N + 63) / 64;

    // layer 0
    k_aggr<<<aggrGrid, 256, 0, stream>>>(xb, rowptr, adj, aggr, N);
    k_xform<128, true, true><<<xfGrid, 256, 0, stream>>>(aggr, xb, w0, bl0, hA, N);
    // layer 1
    k_aggr<<<aggrGrid, 256, 0, stream>>>(hA, rowptr, adj, aggr, N);
    k_xform<128, true, true><<<xfGrid, 256, 0, stream>>>(aggr, hA, w1, bl1, hB, N);
    // layer 2
    k_aggr<<<aggrGrid, 256, 0, stream>>>(hB, rowptr, adj, aggr, N);
    k_xform<64, false, false><<<xfGrid, 256, 0, stream>>>(aggr, hB, w2, bl2, d_out, N);

    // log_softmax
    k_lsm<<<(N + 3) / 4, 256, 0, stream>>>((float*)d_out, N);
}

// Round 3
// 451.405 us; speedup vs baseline: 1.6685x; 1.3019x over previous
//
#include <hip/hip_runtime.h>
#include <hip/hip_bf16.h>
#include <math.h>

typedef __attribute__((ext_vector_type(8))) short short8;
typedef __attribute__((ext_vector_type(4))) float floatx4;
typedef __attribute__((ext_vector_type(4))) unsigned short ushortx4;

__device__ __forceinline__ float bf2f(unsigned short u) {
    union { unsigned int i; float f; } c; c.i = ((unsigned int)u) << 16; return c.f;
}
__device__ __forceinline__ unsigned short f2bf(float f) {
    union { float f; unsigned int i; } c; c.f = f;
    unsigned int x = c.i;
    return (unsigned short)((x + 0x7FFFu + ((x >> 16) & 1u)) >> 16);
}

// ---------------- CSR build ----------------
__global__ void k_zero(int* p, int n) {
    int i = blockIdx.x * blockDim.x + threadIdx.x;
    if (i < n) p[i] = 0;
}

__global__ void k_count(const int* dst, int E, int* deg) {
    int e = blockIdx.x * blockDim.x + threadIdx.x;
    if (e < E) atomicAdd(&deg[dst[e]], 1);
}

// ---- hierarchical exclusive scan: deg[N] -> rowptr[N+1] ----
constexpr int SCAN_T = 256;
constexpr int SCAN_V = 8;
constexpr int SCAN_CHUNK = SCAN_T * SCAN_V;  // 2048 elems per block

__global__ void k_scan_part(const int* deg, int* bsum, int N) {
    int b = blockIdx.x, t = threadIdx.x;
    int base = b * SCAN_CHUNK + t * SCAN_V;
    int s = 0;
#pragma unroll
    for (int j = 0; j < SCAN_V; j++) {
        int i = base + j;
        if (i < N) s += deg[i];
    }
    __shared__ int wsums[SCAN_T / 64];
    for (int off = 32; off; off >>= 1) s += __shfl_down(s, off, 64);
    if ((t & 63) == 0) wsums[t >> 6] = s;
    __syncthreads();
    if (t == 0) {
        int tot = 0;
#pragma unroll
        for (int w = 0; w < SCAN_T / 64; w++) tot += wsums[w];
        bsum[b] = tot;
    }
}

__global__ void k_scan_top(int* bsum, int nb) {
    if (threadIdx.x == 0) {
        int run = 0;
        for (int i = 0; i < nb; i++) {
            int v = bsum[i];
            bsum[i] = run;
            run += v;
        }
    }
}

__global__ void k_scan_apply(const int* deg, const int* bsum, int* rowptr, int N) {
    int b = blockIdx.x, t = threadIdx.x;
    int base = b * SCAN_CHUNK + t * SCAN_V;
    int v[SCAN_V];
    int s = 0;
#pragma unroll
    for (int j = 0; j < SCAN_V; j++) {
        int i = base + j;
        v[j] = (i < N) ? deg[i] : 0;
        s += v[j];
    }
    __shared__ int sums[SCAN_T];
    sums[t] = s;
    __syncthreads();
    for (int off = 1; off < SCAN_T; off <<= 1) {
        int x = (t >= off) ? sums[t - off] : 0;
        __syncthreads();
        sums[t] += x;
        __syncthreads();
    }
    int pre = bsum[b] + ((t == 0) ? 0 : sums[t - 1]);
#pragma unroll
    for (int j = 0; j < SCAN_V; j++) {
        int i = base + j;
        if (i < N) {
            rowptr[i] = pre;
            pre += v[j];
            if (i == N - 1) rowptr[N] = pre;
        }
    }
}

__global__ void k_fill(const int* src, const int* dst, int E, const int* rowptr,
                       int* cursor, int* adj) {
    int e = blockIdx.x * blockDim.x + threadIdx.x;
    if (e < E) {
        int d = dst[e];
        int slot = atomicAdd(&cursor[d], 1);
        adj[rowptr[d] + slot] = src[e];
    }
}

// ---------------- dtype conversion ----------------
__global__ void k_cvt(const float* x, unsigned short* xb, int n) {
    int i = blockIdx.x * blockDim.x + threadIdx.x;
    int idx = i * 4;
    if (idx < n) {
        float4 v = *(const float4*)(x + idx);
        ushortx4 o;
        o[0] = f2bf(v.x); o[1] = f2bf(v.y); o[2] = f2bf(v.z); o[3] = f2bf(v.w);
        *(ushortx4*)(xb + idx) = o;
    }
}

// arrange W2 = [Wl^T ; Wr^T] (256 x Do) into MFMA B-fragment order:
// w2f[((ks*NOC+oc)*64+lane)*8 + j] = W2[ks*32 + (lane>>4)*8 + j][oc*16 + (lane&15)]
__global__ void k_prep_w(const float* Wl, const float* Wr, unsigned short* w2f, int Do) {
    int t = blockIdx.x * blockDim.x + threadIdx.x;
    int NOC = Do >> 4;
    int total = 8 * NOC * 64 * 8;
    if (t >= total) return;
    int j = t & 7;
    int lane = (t >> 3) & 63;
    int rest = t >> 9;
    int oc = rest % NOC;
    int ks = rest / NOC;
    int k = ks * 32 + ((lane >> 4) << 3) + j;
    int o = oc * 16 + (lane & 15);
    float v = (k < 128) ? Wl[o * 128 + k] : Wr[o * 128 + (k - 128)];
    w2f[t] = f2bf(v);
}

// layer-2 concat weights: K=128, 8 output blocks (0..3 = Wl2 -> t2, 4..7 = Wr2 -> self)
__global__ void k_prep_w2(const float* Wl, const float* Wr, unsigned short* wf) {
    int t = blockIdx.x * blockDim.x + threadIdx.x;
    int total = 4 * 8 * 64 * 8;
    if (t >= total) return;
    int j = t & 7;
    int lane = (t >> 3) & 63;
    int rest = t >> 9;
    int oc = rest % 8;
    int ks = rest / 8;
    int k = ks * 32 + ((lane >> 4) << 3) + j;
    int o16 = lane & 15;
    float v = (oc < 4) ? Wl[(oc * 16 + o16) * 128 + k] : Wr[((oc - 4) * 16 + o16) * 128 + k];
    wf[t] = f2bf(v);
}

// ---------------- mean aggregation (32-lane group per node, unroll-8 MLP) ----------------
__global__ __launch_bounds__(256) void k_aggr(const unsigned short* feat, const int* rowptr,
                                              const int* adj, unsigned short* aggr, int N) {
    int g = (blockIdx.x * blockDim.x + threadIdx.x) >> 5;
    int lane = threadIdx.x & 31;
    if (g >= N) return;
    int lo = rowptr[g], hi = rowptr[g + 1];
    float a0 = 0.f, a1 = 0.f, a2 = 0.f, a3 = 0.f;
    const unsigned short* fb = feat + lane * 4;
    int j = lo;
    for (; j + 8 <= hi; j += 8) {
        ushortx4 v[8];
#pragma unroll
        for (int u = 0; u < 8; u++) {
            int s = adj[j + u];
            v[u] = *(const ushortx4*)(fb + (size_t)s * 128);
        }
#pragma unroll
        for (int u = 0; u < 8; u++) {
            a0 += bf2f(v[u][0]); a1 += bf2f(v[u][1]);
            a2 += bf2f(v[u][2]); a3 += bf2f(v[u][3]);
        }
    }
    if (j < hi) {  // masked tail chunk: all loads issued back-to-back
        ushortx4 v[8];
        float w[8];
#pragma unroll
        for (int u = 0; u < 8; u++) {
            int jj = j + u;
            int s = adj[jj < hi ? jj : hi - 1];
            v[u] = *(const ushortx4*)(fb + (size_t)s * 128);
            w[u] = (jj < hi) ? 1.0f : 0.0f;
        }
#pragma unroll
        for (int u = 0; u < 8; u++) {
            a0 = fmaf(w[u], bf2f(v[u][0]), a0);
            a1 = fmaf(w[u], bf2f(v[u][1]), a1);
            a2 = fmaf(w[u], bf2f(v[u][2]), a2);
            a3 = fmaf(w[u], bf2f(v[u][3]), a3);
        }
    }
    float inv = 1.0f / (float)max(hi - lo, 1);
    ushortx4 o;
    o[0] = f2bf(a0 * inv); o[1] = f2bf(a1 * inv); o[2] = f2bf(a2 * inv); o[3] = f2bf(a3 * inv);
    *(ushortx4*)(aggr + (size_t)g * 128 + lane * 4) = o;
}

// 64-wide mean aggregation of t2, added into f32 out (16-lane group per node)
__global__ __launch_bounds__(256) void k_aggr64(const unsigned short* t2, const int* rowptr,
                                                const int* adj, float* out, int N) {
    int g = (blockIdx.x * blockDim.x + threadIdx.x) >> 4;
    int lane = threadIdx.x & 15;
    if (g >= N) return;
    int lo = rowptr[g], hi = rowptr[g + 1];
    float a0 = 0.f, a1 = 0.f, a2 = 0.f, a3 = 0.f;
    const unsigned short* fb = t2 + lane * 4;
    int j = lo;
    for (; j + 8 <= hi; j += 8) {
        ushortx4 v[8];
#pragma unroll
        for (int u = 0; u < 8; u++) {
            int s = adj[j + u];
            v[u] = *(const ushortx4*)(fb + (size_t)s * 64);
        }
#pragma unroll
        for (int u = 0; u < 8; u++) {
            a0 += bf2f(v[u][0]); a1 += bf2f(v[u][1]);
            a2 += bf2f(v[u][2]); a3 += bf2f(v[u][3]);
        }
    }
    if (j < hi) {
        ushortx4 v[8];
        float w[8];
#pragma unroll
        for (int u = 0; u < 8; u++) {
            int jj = j + u;
            int s = adj[jj < hi ? jj : hi - 1];
            v[u] = *(const ushortx4*)(fb + (size_t)s * 64);
            w[u] = (jj < hi) ? 1.0f : 0.0f;
        }
#pragma unroll
        for (int u = 0; u < 8; u++) {
            a0 = fmaf(w[u], bf2f(v[u][0]), a0);
            a1 = fmaf(w[u], bf2f(v[u][1]), a1);
            a2 = fmaf(w[u], bf2f(v[u][2]), a2);
            a3 = fmaf(w[u], bf2f(v[u][3]), a3);
        }
    }
    float inv = 1.0f / (float)max(hi - lo, 1);
    float* op = out + (size_t)g * 64 + lane * 4;
    float4 cur = *(float4*)op;
    cur.x += a0 * inv; cur.y += a1 * inv; cur.z += a2 * inv; cur.w += a3 * inv;
    *(float4*)op = cur;
}

// ---------------- fused transform: out = [aggr|feat] @ W2 + b (+relu) ----------------
template <int DO, bool RELU, bool OUTBF>
__global__ __launch_bounds__(256) void k_xform(const unsigned short* aggr,
                                               const unsigned short* feat,
                                               const unsigned short* w2f,
                                               const float* bias, void* outp, int N) {
    const int wave = threadIdx.x >> 6;
    const int lane = threadIdx.x & 63;
    const int nodeBase = blockIdx.x * 64 + wave * 16;
    const int row = nodeBase + (lane & 15);
    const int kq = lane >> 4;  // 0..3
    constexpr int NOC = DO / 16;
    floatx4 acc[NOC];
#pragma unroll
    for (int i = 0; i < NOC; i++) acc[i] = (floatx4)0.0f;
    const bool rowOK = row < N;
    const unsigned short* arow = aggr + (size_t)row * 128;
    const unsigned short* frow = feat + (size_t)row * 128;
    const short8* bbase = (const short8*)w2f;
#pragma unroll
    for (int ks = 0; ks < 8; ks++) {
        short8 a;
        if (rowOK) {
            const unsigned short* srcp =
                (ks < 4) ? (arow + ks * 32 + kq * 8) : (frow + (ks - 4) * 32 + kq * 8);
            a = *(const short8*)srcp;
        } else {
            a = (short8)0;
        }
#pragma unroll
        for (int oc = 0; oc < NOC; oc++) {
            short8 b = bbase[(ks * NOC + oc) * 64 + lane];
            acc[oc] = __builtin_amdgcn_mfma_f32_16x16x32_bf16(a, b, acc[oc], 0, 0, 0);
        }
    }
#pragma unroll
    for (int oc = 0; oc < NOC; oc++) {
        int o = oc * 16 + (lane & 15);
        float bv = bias[o];
#pragma unroll
        for (int j = 0; j < 4; j++) {
            int node = nodeBase + kq * 4 + j;
            if (node < N) {
                float v = acc[oc][j] + bv;
                if (RELU) v = fmaxf(v, 0.0f);
                if (OUTBF)
                    ((unsigned short*)outp)[(size_t)node * DO + o] = f2bf(v);
                else
                    ((float*)outp)[(size_t)node * DO + o] = v;
            }
        }
    }
}

// layer-2 split transform: t2 = h @ Wl2^T (bf16), self = h @ Wr2^T + bl2 (f32 -> out)
__global__ __launch_bounds__(256) void k_xform2(const unsigned short* feat,
                                                const unsigned short* wf,
                                                const float* bias,
                                                unsigned short* t2, float* out, int N) {
    const int wave = threadIdx.x >> 6;
    const int lane = threadIdx.x & 63;
    const int nodeBase = blockIdx.x * 64 + wave * 16;
    const int row = nodeBase + (lane & 15);
    const int kq = lane >> 4;
    floatx4 acc[8];
#pragma unroll
    for (int i = 0; i < 8; i++) acc[i] = (floatx4)0.0f;
    const bool rowOK = row < N;
    const unsigned short* frow = feat + (size_t)row * 128;
    const short8* bbase = (const short8*)wf;
#pragma unroll
    for (int ks = 0; ks < 4; ks++) {
        short8 a;
        if (rowOK)
            a = *(const short8*)(frow + ks * 32 + kq * 8);
        else
            a = (short8)0;
#pragma unroll
        for (int oc = 0; oc < 8; oc++) {
            short8 b = bbase[(ks * 8 + oc) * 64 + lane];
            acc[oc] = __builtin_amdgcn_mfma_f32_16x16x32_bf16(a, b, acc[oc], 0, 0, 0);
        }
    }
#pragma unroll
    for (int oc = 0; oc < 8; oc++) {
        int o16 = lane & 15;
#pragma unroll
        for (int j = 0; j < 4; j++) {
            int node = nodeBase + kq * 4 + j;
            if (node < N) {
                if (oc < 4) {
                    t2[(size_t)node * 64 + oc * 16 + o16] = f2bf(acc[oc][j]);
                } else {
                    int o = (oc - 4) * 16 + o16;
                    out[(size_t)node * 64 + o] = acc[oc][j] + bias[o];
                }
            }
        }
    }
}

// ---------------- row-wise log_softmax (in place, 64 cols, wave per row) ----------------
__global__ void k_lsm(float* out, int N) {
    int wave = threadIdx.x >> 6;
    int lane = threadIdx.x & 63;
    int rowi = blockIdx.x * 4 + wave;
    if (rowi >= N) return;
    float v = out[(size_t)rowi * 64 + lane];
    float m = v;
    for (int off = 32; off; off >>= 1) m = fmaxf(m, __shfl_xor(m, off, 64));
    float e = expf(v - m);
    float s = e;
    for (int off = 32; off; off >>= 1) s += __shfl_xor(s, off, 64);
    out[(size_t)rowi * 64 + lane] = v - m - logf(s);
}

extern "C" void kernel_launch(void* const* d_in, const int* in_sizes, int n_in,
                              void* d_out, int out_size, void* d_ws, size_t ws_size,
                              hipStream_t stream) {
    const float* x = (const float*)d_in[0];
    const int* ei = (const int*)d_in[1];
    const float* Wl0 = (const float*)d_in[2];
    const float* bl0 = (const float*)d_in[3];
    const float* Wr0 = (const float*)d_in[4];
    const float* Wl1 = (const float*)d_in[5];
    const float* bl1 = (const float*)d_in[6];
    const float* Wr1 = (const float*)d_in[7];
    const float* Wl2 = (const float*)d_in[8];
    const float* bl2 = (const float*)d_in[9];
    const float* Wr2 = (const float*)d_in[10];

    const int N = in_sizes[0] / 128;
    const int E = in_sizes[1] / 2;
    const int* src = ei;
    const int* dst = ei + E;

    char* ws = (char*)d_ws;
    size_t off = 0;
    auto alloc = [&](size_t bytes) {
        void* p = ws + off;
        off += (bytes + 255) & ~(size_t)255;
        return p;
    };
    int* deg = (int*)alloc((size_t)N * 4);
    int* cursor = (int*)alloc((size_t)N * 4);
    int* rowptr = (int*)alloc((size_t)(N + 1) * 4);
    int* bsum = (int*)alloc(1024 * 4);
    int* adj = (int*)alloc((size_t)E * 4);
    unsigned short* xb = (unsigned short*)alloc((size_t)N * 128 * 2);
    unsigned short* aggr = (unsigned short*)alloc((size_t)N * 128 * 2);  // also reused as t2
    unsigned short* hA = (unsigned short*)alloc((size_t)N * 128 * 2);
    unsigned short* hB = (unsigned short*)alloc((size_t)N * 128 * 2);
    unsigned short* w0 = (unsigned short*)alloc(8 * 8 * 64 * 8 * 2);
    unsigned short* w1 = (unsigned short*)alloc(8 * 8 * 64 * 8 * 2);
    unsigned short* w2 = (unsigned short*)alloc(4 * 8 * 64 * 8 * 2);

    // CSR build
    k_zero<<<(N + 255) / 256, 256, 0, stream>>>(deg, N);
    k_zero<<<(N + 255) / 256, 256, 0, stream>>>(cursor, N);
    k_count<<<(E + 255) / 256, 256, 0, stream>>>(dst, E, deg);
    const int nScanBlocks = (N + SCAN_CHUNK - 1) / SCAN_CHUNK;
    k_scan_part<<<nScanBlocks, SCAN_T, 0, stream>>>(deg, bsum, N);
    k_scan_top<<<1, 64, 0, stream>>>(bsum, nScanBlocks);
    k_scan_apply<<<nScanBlocks, SCAN_T, 0, stream>>>(deg, bsum, rowptr, N);
    k_fill<<<(E + 255) / 256, 256, 0, stream>>>(src, dst, E, rowptr, cursor, adj);

    // conversions / weight prep
    k_cvt<<<((N * 128 / 4) + 255) / 256, 256, 0, stream>>>(x, xb, N * 128);
    k_prep_w<<<(32768 + 255) / 256, 256, 0, stream>>>(Wl0, Wr0, w0, 128);
    k_prep_w<<<(32768 + 255) / 256, 256, 0, stream>>>(Wl1, Wr1, w1, 128);
    k_prep_w2<<<(16384 + 255) / 256, 256, 0, stream>>>(Wl2, Wr2, w2);

    const int aggrGrid = ((N * 32) + 255) / 256;
    const int aggr64Grid = ((N * 16) + 255) / 256;
    const int xfGrid = (N + 63) / 64;

    // layer 0
    k_aggr<<<aggrGrid, 256, 0, stream>>>(xb, rowptr, adj, aggr, N);
    k_xform<128, true, true><<<xfGrid, 256, 0, stream>>>(aggr, xb, w0, bl0, hA, N);
    // layer 1
    k_aggr<<<aggrGrid, 256, 0, stream>>>(hA, rowptr, adj, aggr, N);
    k_xform<128, true, true><<<xfGrid, 256, 0, stream>>>(aggr, hA, w1, bl1, hB, N);
    // layer 2: transform first (commutes with mean), then 64-wide aggregate
    k_xform2<<<xfGrid, 256, 0, stream>>>(hB, w2, bl2, aggr /*t2*/, (float*)d_out, N);
    k_aggr64<<<aggr64Grid, 256, 0, stream>>>(aggr /*t2*/, rowptr, adj, (float*)d_out, N);

    // log_softmax
    k_lsm<<<(N + 3) / 4, 256, 0, stream>>>((float*)d_out, N);
}

// Round 5
// 334.739 us; speedup vs baseline: 2.2500x; 1.3485x over previous
//
#include <hip/hip_runtime.h>
#include <hip/hip_bf16.h>
#include <math.h>

typedef __attribute__((ext_vector_type(8))) short short8;
typedef __attribute__((ext_vector_type(4))) float floatx4;
typedef __attribute__((ext_vector_type(4))) unsigned short ushortx4;

__device__ __forceinline__ float bf2f(unsigned short u) {
    union { unsigned int i; float f; } c; c.i = ((unsigned int)u) << 16; return c.f;
}
__device__ __forceinline__ unsigned short f2bf(float f) {
    union { float f; unsigned int i; } c; c.f = f;
    unsigned int x = c.i;
    return (unsigned short)((x + 0x7FFFu + ((x >> 16) & 1u)) >> 16);
}

// ================= bucketed CSR build =================
// coarse bucket = dst >> 8 (256 nodes per bucket), NB buckets, B1 partition blocks
constexpr int NB = 512;
constexpr int B1 = 256;

// phase A: per-block per-bucket histogram (no global atomics)
__global__ __launch_bounds__(256) void k_bhist(const int* dst, int E, int* cnt) {
    __shared__ int h[NB];
    int t = threadIdx.x, b = blockIdx.x;
    h[t] = 0; h[t + 256] = 0;
    __syncthreads();
    int chunk = (E + B1 - 1) / B1;
    int lo = b * chunk, hi = min(E, lo + chunk);
    for (int e = lo + t; e < hi; e += 256) atomicAdd(&h[dst[e] >> 8], 1);
    __syncthreads();
    cnt[(size_t)t * B1 + b] = h[t];
    cnt[(size_t)(t + 256) * B1 + b] = h[t + 256];
}

// ---- hierarchical exclusive scan (generic length) ----
constexpr int SCAN_T = 256;
constexpr int SCAN_V = 8;
constexpr int SCAN_CHUNK = SCAN_T * SCAN_V;  // 2048

__global__ void k_scan_part(const int* in, int* bsum, int N) {
    int b = blockIdx.x, t = threadIdx.x;
    int base = b * SCAN_CHUNK + t * SCAN_V;
    int s = 0;
#pragma unroll
    for (int j = 0; j < SCAN_V; j++) {
        int i = base + j;
        if (i < N) s += in[i];
    }
    __shared__ int wsums[SCAN_T / 64];
    for (int off = 32; off; off >>= 1) s += __shfl_down(s, off, 64);
    if ((t & 63) == 0) wsums[t >> 6] = s;
    __syncthreads();
    if (t == 0) {
        int tot = 0;
#pragma unroll
        for (int w = 0; w < SCAN_T / 64; w++) tot += wsums[w];
        bsum[b] = tot;
    }
}

__global__ void k_scan_top(int* bsum, int nb) {
    if (threadIdx.x == 0) {
        int run = 0;
        for (int i = 0; i < nb; i++) {
            int v = bsum[i];
            bsum[i] = run;
            run += v;
        }
    }
}

__global__ void k_scan_apply(const int* in, const int* bsum, int* out, int N) {
    int b = blockIdx.x, t = threadIdx.x;
    int base = b * SCAN_CHUNK + t * SCAN_V;
    int v[SCAN_V];
    int s = 0;
#pragma unroll
    for (int j = 0; j < SCAN_V; j++) {
        int i = base + j;
        v[j] = (i < N) ? in[i] : 0;
        s += v[j];
    }
    __shared__ int sums[SCAN_T];
    sums[t] = s;
    __syncthreads();
    for (int off = 1; off < SCAN_T; off <<= 1) {
        int x = (t >= off) ? sums[t - off] : 0;
        __syncthreads();
        sums[t] += x;
        __syncthreads();
    }
    int pre = bsum[b] + ((t == 0) ? 0 : sums[t - 1]);
#pragma unroll
    for (int j = 0; j < SCAN_V; j++) {
        int i = base + j;
        if (i < N) {
            out[i] = pre;
            pre += v[j];
            if (i == N - 1) out[N] = pre;
        }
    }
}

// phase C: scatter edges into bucket-partitioned ebuf, private sequential regions
__global__ __launch_bounds__(256) void k_bscatter(const int* src, const int* dst, int E,
                                                  const int* cntoff, unsigned int* ebuf) {
    __shared__ int base[NB];
    __shared__ int lcur[NB];
    int t = threadIdx.x, b = blockIdx.x;
    for (int i = t; i < NB; i += 256) {
        base[i] = cntoff[(size_t)i * B1 + b];
        lcur[i] = 0;
    }
    __syncthreads();
    int chunk = (E + B1 - 1) / B1;
    int lo = b * chunk, hi = min(E, lo + chunk);
    for (int e = lo + t; e < hi; e += 256) {
        int d = dst[e];
        int cb = d >> 8;
        int slot = atomicAdd(&lcur[cb], 1);
        ebuf[base[cb] + slot] = (unsigned int)src[e] | ((unsigned int)(d & 255) << 17);
    }
}

// phase D: per-bucket local CSR: rowptr + adj (256 nodes per bucket, bucket-local writes)
__global__ __launch_bounds__(256) void k_build(const unsigned int* ebuf, const int* cntoff,
                                               int* rowptr, int* adj, int N, int E) {
    __shared__ int ldeg[256];
    __shared__ int lptr[256];
    __shared__ int lcur[256];
    __shared__ int tsum[256];
    int t = threadIdx.x, cb = blockIdx.x;
    int bbase = cntoff[(size_t)cb * B1];
    int bend = cntoff[(size_t)(cb + 1) * B1];
    ldeg[t] = 0;
    lcur[t] = 0;
    __syncthreads();
    for (int e = bbase + t; e < bend; e += 256) atomicAdd(&ldeg[ebuf[e] >> 17], 1);
    __syncthreads();
    tsum[t] = ldeg[t];
    __syncthreads();
    for (int off = 1; off < 256; off <<= 1) {
        int v = (t >= off) ? tsum[t - off] : 0;
        __syncthreads();
        tsum[t] += v;
        __syncthreads();
    }
    lptr[t] = tsum[t] - ldeg[t];  // exclusive prefix within bucket
    __syncthreads();
    int node = cb * 256 + t;
    if (node < N) rowptr[node] = bbase + lptr[t];
    if (cb == 0 && t == 0) rowptr[N] = E;
    for (int e = bbase + t; e < bend; e += 256) {
        unsigned int pk = ebuf[e];
        int dl = pk >> 17;
        int ls = atomicAdd(&lcur[dl], 1);
        adj[bbase + lptr[dl] + ls] = (int)(pk & 0x1FFFF);
    }
}

// ---------------- dtype conversion ----------------
__global__ void k_cvt(const float* x, unsigned short* xb, int n) {
    int i = blockIdx.x * blockDim.x + threadIdx.x;
    int idx = i * 4;
    if (idx < n) {
        float4 v = *(const float4*)(x + idx);
        ushortx4 o;
        o[0] = f2bf(v.x); o[1] = f2bf(v.y); o[2] = f2bf(v.z); o[3] = f2bf(v.w);
        *(ushortx4*)(xb + idx) = o;
    }
}

// arrange W = [Wl^T ; Wr^T] (256 x Do) into MFMA B-fragment order
__global__ void k_prep_w(const float* Wl, const float* Wr, unsigned short* w2f, int Do) {
    int t = blockIdx.x * blockDim.x + threadIdx.x;
    int NOC = Do >> 4;
    int total = 8 * NOC * 64 * 8;
    if (t >= total) return;
    int j = t & 7;
    int lane = (t >> 3) & 63;
    int rest = t >> 9;
    int oc = rest % NOC;
    int ks = rest / NOC;
    int k = ks * 32 + ((lane >> 4) << 3) + j;
    int o = oc * 16 + (lane & 15);
    float v = (k < 128) ? Wl[o * 128 + k] : Wr[o * 128 + (k - 128)];
    w2f[t] = f2bf(v);
}

// layer-2 concat weights: K=128, 8 output blocks (0..3 = Wl2 -> t2, 4..7 = Wr2 -> self)
__global__ void k_prep_w2(const float* Wl, const float* Wr, unsigned short* wf) {
    int t = blockIdx.x * blockDim.x + threadIdx.x;
    int total = 4 * 8 * 64 * 8;
    if (t >= total) return;
    int j = t & 7;
    int lane = (t >> 3) & 63;
    int rest = t >> 9;
    int oc = rest % 8;
    int ks = rest / 8;
    int k = ks * 32 + ((lane >> 4) << 3) + j;
    int o16 = lane & 15;
    float v = (oc < 4) ? Wl[(oc * 16 + o16) * 128 + k] : Wr[((oc - 4) * 16 + o16) * 128 + k];
    wf[t] = f2bf(v);
}

// ---------------- mean aggregation (32-lane group per node, unroll-8 MLP) ----------------
__global__ __launch_bounds__(256) void k_aggr(const unsigned short* feat, const int* rowptr,
                                              const int* adj, unsigned short* aggr, int N) {
    int g = (blockIdx.x * blockDim.x + threadIdx.x) >> 5;
    int lane = threadIdx.x & 31;
    if (g >= N) return;
    int lo = rowptr[g], hi = rowptr[g + 1];
    float a0 = 0.f, a1 = 0.f, a2 = 0.f, a3 = 0.f;
    const unsigned short* fb = feat + lane * 4;
    int j = lo;
    for (; j + 8 <= hi; j += 8) {
        ushortx4 v[8];
#pragma unroll
        for (int u = 0; u < 8; u++) {
            int s = adj[j + u];
            v[u] = *(const ushortx4*)(fb + (size_t)s * 128);
        }
#pragma unroll
        for (int u = 0; u < 8; u++) {
            a0 += bf2f(v[u][0]); a1 += bf2f(v[u][1]);
            a2 += bf2f(v[u][2]); a3 += bf2f(v[u][3]);
        }
    }
    if (j < hi) {
        ushortx4 v[8];
        float w[8];
#pragma unroll
        for (int u = 0; u < 8; u++) {
            int jj = j + u;
            int s = adj[jj < hi ? jj : hi - 1];
            v[u] = *(const ushortx4*)(fb + (size_t)s * 128);
            w[u] = (jj < hi) ? 1.0f : 0.0f;
        }
#pragma unroll
        for (int u = 0; u < 8; u++) {
            a0 = fmaf(w[u], bf2f(v[u][0]), a0);
            a1 = fmaf(w[u], bf2f(v[u][1]), a1);
            a2 = fmaf(w[u], bf2f(v[u][2]), a2);
            a3 = fmaf(w[u], bf2f(v[u][3]), a3);
        }
    }
    float inv = 1.0f / (float)max(hi - lo, 1);
    ushortx4 o;
    o[0] = f2bf(a0 * inv); o[1] = f2bf(a1 * inv); o[2] = f2bf(a2 * inv); o[3] = f2bf(a3 * inv);
    *(ushortx4*)(aggr + (size_t)g * 128 + lane * 4) = o;
}

// 64-wide mean aggregation of t2, added into f32 out (16-lane group per node)
__global__ __launch_bounds__(256) void k_aggr64(const unsigned short* t2, const int* rowptr,
                                                const int* adj, float* out, int N) {
    int g = (blockIdx.x * blockDim.x + threadIdx.x) >> 4;
    int lane = threadIdx.x & 15;
    if (g >= N) return;
    int lo = rowptr[g], hi = rowptr[g + 1];
    float a0 = 0.f, a1 = 0.f, a2 = 0.f, a3 = 0.f;
    const unsigned short* fb = t2 + lane * 4;
    int j = lo;
    for (; j + 8 <= hi; j += 8) {
        ushortx4 v[8];
#pragma unroll
        for (int u = 0; u < 8; u++) {
            int s = adj[j + u];
            v[u] = *(const ushortx4*)(fb + (size_t)s * 64);
        }
#pragma unroll
        for (int u = 0; u < 8; u++) {
            a0 += bf2f(v[u][0]); a1 += bf2f(v[u][1]);
            a2 += bf2f(v[u][2]); a3 += bf2f(v[u][3]);
        }
    }
    if (j < hi) {
        ushortx4 v[8];
        float w[8];
#pragma unroll
        for (int u = 0; u < 8; u++) {
            int jj = j + u;
            int s = adj[jj < hi ? jj : hi - 1];
            v[u] = *(const ushortx4*)(fb + (size_t)s * 64);
            w[u] = (jj < hi) ? 1.0f : 0.0f;
        }
#pragma unroll
        for (int u = 0; u < 8; u++) {
            a0 = fmaf(w[u], bf2f(v[u][0]), a0);
            a1 = fmaf(w[u], bf2f(v[u][1]), a1);
            a2 = fmaf(w[u], bf2f(v[u][2]), a2);
            a3 = fmaf(w[u], bf2f(v[u][3]), a3);
        }
    }
    float inv = 1.0f / (float)max(hi - lo, 1);
    float* op = out + (size_t)g * 64 + lane * 4;
    float4 cur = *(float4*)op;
    cur.x += a0 * inv; cur.y += a1 * inv; cur.z += a2 * inv; cur.w += a3 * inv;
    *(float4*)op = cur;
}

// ---------------- fused transform: out = [aggr|feat] @ W + b (+relu) ----------------
template <int DO, bool RELU, bool OUTBF>
__global__ __launch_bounds__(256) void k_xform(const unsigned short* aggr,
                                               const unsigned short* feat,
                                               const unsigned short* w2f,
                                               const float* bias, void* outp, int N) {
    const int wave = threadIdx.x >> 6;
    const int lane = threadIdx.x & 63;
    const int nodeBase = blockIdx.x * 64 + wave * 16;
    const int row = nodeBase + (lane & 15);
    const int kq = lane >> 4;
    constexpr int NOC = DO / 16;
    floatx4 acc[NOC];
#pragma unroll
    for (int i = 0; i < NOC; i++) acc[i] = (floatx4)0.0f;
    const bool rowOK = row < N;
    const unsigned short* arow = aggr + (size_t)row * 128;
    const unsigned short* frow = feat + (size_t)row * 128;
    const short8* bbase = (const short8*)w2f;
#pragma unroll
    for (int ks = 0; ks < 8; ks++) {
        short8 a;
        if (rowOK) {
            const unsigned short* srcp =
                (ks < 4) ? (arow + ks * 32 + kq * 8) : (frow + (ks - 4) * 32 + kq * 8);
            a = *(const short8*)srcp;
        } else {
            a = (short8)0;
        }
#pragma unroll
        for (int oc = 0; oc < NOC; oc++) {
            short8 b = bbase[(ks * NOC + oc) * 64 + lane];
            acc[oc] = __builtin_amdgcn_mfma_f32_16x16x32_bf16(a, b, acc[oc], 0, 0, 0);
        }
    }
#pragma unroll
    for (int oc = 0; oc < NOC; oc++) {
        int o = oc * 16 + (lane & 15);
        float bv = bias[o];
#pragma unroll
        for (int j = 0; j < 4; j++) {
            int node = nodeBase + kq * 4 + j;
            if (node < N) {
                float v = acc[oc][j] + bv;
                if (RELU) v = fmaxf(v, 0.0f);
                if (OUTBF)
                    ((unsigned short*)outp)[(size_t)node * DO + o] = f2bf(v);
                else
                    ((float*)outp)[(size_t)node * DO + o] = v;
            }
        }
    }
}

// layer-2 split transform: t2 = h @ Wl2^T (bf16), self = h @ Wr2^T + bl2 (f32 -> out)
__global__ __launch_bounds__(256) void k_xform2(const unsigned short* feat,
                                                const unsigned short* wf,
                                                const float* bias,
                                                unsigned short* t2, float* out, int N) {
    const int wave = threadIdx.x >> 6;
    const int lane = threadIdx.x & 63;
    const int nodeBase = blockIdx.x * 64 + wave * 16;
    const int row = nodeBase + (lane & 15);
    const int kq = lane >> 4;
    floatx4 acc[8];
#pragma unroll
    for (int i = 0; i < 8; i++) acc[i] = (floatx4)0.0f;
    const bool rowOK = row < N;
    const unsigned short* frow = feat + (size_t)row * 128;
    const short8* bbase = (const short8*)wf;
#pragma unroll
    for (int ks = 0; ks < 4; ks++) {
        short8 a;
        if (rowOK)
            a = *(const short8*)(frow + ks * 32 + kq * 8);
        else
            a = (short8)0;
#pragma unroll
        for (int oc = 0; oc < 8; oc++) {
            short8 b = bbase[(ks * 8 + oc) * 64 + lane];
            acc[oc] = __builtin_amdgcn_mfma_f32_16x16x32_bf16(a, b, acc[oc], 0, 0, 0);
        }
    }
#pragma unroll
    for (int oc = 0; oc < 8; oc++) {
        int o16 = lane & 15;
#pragma unroll
        for (int j = 0; j < 4; j++) {
            int node = nodeBase + kq * 4 + j;
            if (node < N) {
                if (oc < 4) {
                    t2[(size_t)node * 64 + oc * 16 + o16] = f2bf(acc[oc][j]);
                } else {
                    int o = (oc - 4) * 16 + o16;
                    out[(size_t)node * 64 + o] = acc[oc][j] + bias[o];
                }
            }
        }
    }
}

// ---------------- row-wise log_softmax ----------------
__global__ void k_lsm(float* out, int N) {
    int wave = threadIdx.x >> 6;
    int lane = threadIdx.x & 63;
    int rowi = blockIdx.x * 4 + wave;
    if (rowi >= N) return;
    float v = out[(size_t)rowi * 64 + lane];
    float m = v;
    for (int off = 32; off; off >>= 1) m = fmaxf(m, __shfl_xor(m, off, 64));
    float e = expf(v - m);
    float s = e;
    for (int off = 32; off; off >>= 1) s += __shfl_xor(s, off, 64);
    out[(size_t)rowi * 64 + lane] = v - m - logf(s);
}

extern "C" void kernel_launch(void* const* d_in, const int* in_sizes, int n_in,
                              void* d_out, int out_size, void* d_ws, size_t ws_size,
                              hipStream_t stream) {
    const float* x = (const float*)d_in[0];
    const int* ei = (const int*)d_in[1];
    const float* Wl0 = (const float*)d_in[2];
    const float* bl0 = (const float*)d_in[3];
    const float* Wr0 = (const float*)d_in[4];
    const float* Wl1 = (const float*)d_in[5];
    const float* bl1 = (const float*)d_in[6];
    const float* Wr1 = (const float*)d_in[7];
    const float* Wl2 = (const float*)d_in[8];
    const float* bl2 = (const float*)d_in[9];
    const float* Wr2 = (const float*)d_in[10];

    const int N = in_sizes[0] / 128;
    const int E = in_sizes[1] / 2;
    const int* src = ei;
    const int* dst = ei + E;

    char* ws = (char*)d_ws;
    size_t off = 0;
    auto alloc = [&](size_t bytes) {
        void* p = ws + off;
        off += (bytes + 255) & ~(size_t)255;
        return p;
    };
    int* cntin = (int*)alloc((size_t)NB * B1 * 4);
    int* cntoff = (int*)alloc(((size_t)NB * B1 + 1) * 4);
    int* bsum = (int*)alloc(1024 * 4);
    unsigned int* ebuf = (unsigned int*)alloc((size_t)E * 4);
    int* rowptr = (int*)alloc((size_t)(N + 1) * 4);
    int* adj = (int*)alloc((size_t)E * 4);
    unsigned short* xb = (unsigned short*)alloc((size_t)N * 128 * 2);
    unsigned short* aggr = (unsigned short*)alloc((size_t)N * 128 * 2);  // also t2
    unsigned short* hA = (unsigned short*)alloc((size_t)N * 128 * 2);
    unsigned short* hB = (unsigned short*)alloc((size_t)N * 128 * 2);
    unsigned short* w0 = (unsigned short*)alloc(8 * 8 * 64 * 8 * 2);
    unsigned short* w1 = (unsigned short*)alloc(8 * 8 * 64 * 8 * 2);
    unsigned short* w2 = (unsigned short*)alloc(4 * 8 * 64 * 8 * 2);

    // ---- bucketed CSR build ----
    const int NBUCK = (N + 255) >> 8;  // active buckets
    k_bhist<<<B1, 256, 0, stream>>>(dst, E, cntin);
    const int scanLen = NB * B1;
    const int nScanBlocks = (scanLen + SCAN_CHUNK - 1) / SCAN_CHUNK;
    k_scan_part<<<nScanBlocks, SCAN_T, 0, stream>>>(cntin, bsum, scanLen);
    k_scan_top<<<1, 64, 0, stream>>>(bsum, nScanBlocks);
    k_scan_apply<<<nScanBlocks, SCAN_T, 0, stream>>>(cntin, bsum, cntoff, scanLen);
    k_bscatter<<<B1, 256, 0, stream>>>(src, dst, E, cntoff, ebuf);
    k_build<<<NBUCK, 256, 0, stream>>>(ebuf, cntoff, rowptr, adj, N, E);

    // conversions / weight prep
    k_cvt<<<((N * 128 / 4) + 255) / 256, 256, 0, stream>>>(x, xb, N * 128);
    k_prep_w<<<(32768 + 255) / 256, 256, 0, stream>>>(Wl0, Wr0, w0, 128);
    k_prep_w<<<(32768 + 255) / 256, 256, 0, stream>>>(Wl1, Wr1, w1, 128);
    k_prep_w2<<<(16384 + 255) / 256, 256, 0, stream>>>(Wl2, Wr2, w2);

    const int aggrGrid = ((N * 32) + 255) / 256;
    const int aggr64Grid = ((N * 16) + 255) / 256;
    const int xfGrid = (N + 63) / 64;

    // layer 0
    k_aggr<<<aggrGrid, 256, 0, stream>>>(xb, rowptr, adj, aggr, N);
    k_xform<128, true, true><<<xfGrid, 256, 0, stream>>>(aggr, xb, w0, bl0, hA, N);
    // layer 1
    k_aggr<<<aggrGrid, 256, 0, stream>>>(hA, rowptr, adj, aggr, N);
    k_xform<128, true, true><<<xfGrid, 256, 0, stream>>>(aggr, hA, w1, bl1, hB, N);
    // layer 2: transform first (commutes with mean), then 64-wide aggregate
    k_xform2<<<xfGrid, 256, 0, stream>>>(hB, w2, bl2, aggr /*t2*/, (float*)d_out, N);
    k_aggr64<<<aggr64Grid, 256, 0, stream>>>(aggr /*t2*/, rowptr, adj, (float*)d_out, N);

    // log_softmax
    k_lsm<<<(N + 3) / 4, 256, 0, stream>>>((float*)d_out, N);
}

// Round 6
// 298.099 us; speedup vs baseline: 2.5265x; 1.1229x over previous
//
#include <hip/hip_runtime.h>
#include <hip/hip_bf16.h>
#include <math.h>

typedef __attribute__((ext_vector_type(8))) short short8;
typedef __attribute__((ext_vector_type(4))) float floatx4;
typedef __attribute__((ext_vector_type(2))) float floatx2;
typedef __attribute__((ext_vector_type(4))) unsigned short ushortx4;

__device__ __forceinline__ float bf2f(unsigned short u) {
    union { unsigned int i; float f; } c; c.i = ((unsigned int)u) << 16; return c.f;
}
__device__ __forceinline__ unsigned short f2bf(float f) {
    union { float f; unsigned int i; } c; c.f = f;
    unsigned int x = c.i;
    return (unsigned short)((x + 0x7FFFu + ((x >> 16) & 1u)) >> 16);
}

// ---------- fp8 e4m3fn (OCP) encode/decode ----------
__device__ __forceinline__ unsigned char f2fp8(float f) {
    unsigned int u = __float_as_uint(f);
    unsigned int sign = (u >> 24) & 0x80u;
    unsigned int a = u & 0x7FFFFFFFu;
    if (a >= 0x43E00000u) return (unsigned char)(sign | 0x7Eu);  // saturate at 448
    if (a < 0x3C800000u) {  // below smallest normal 2^-6: denormal units of 2^-9
        int unit = (int)rintf(__uint_as_float(a) * 512.0f);
        return (unsigned char)(sign | (unsigned int)unit);
    }
    unsigned int r = a + 0x7FFFFu + ((a >> 20) & 1u);  // RNE at bit 20
    unsigned int e = (r >> 23) - 120u;
    unsigned int m = (r >> 20) & 7u;
    return (unsigned char)(sign | (e << 3) | m);
}

__device__ __forceinline__ float fp8dec1(unsigned int b) {
    unsigned int s = (b & 0x80u) << 24;
    unsigned int mag = (b & 0x7Fu) << 20;
    return __uint_as_float(s | mag) * __uint_as_float(0x7B800000u);  // * 2^120
}

template <bool W>
__device__ __forceinline__ floatx2 fp8pk2f(unsigned int v) {
#if defined(__has_builtin) && __has_builtin(__builtin_amdgcn_cvt_pk_f32_fp8)
    return __builtin_amdgcn_cvt_pk_f32_fp8(v, W);
#else
    floatx2 r;
    r[0] = fp8dec1((v >> (W ? 16 : 0)) & 0xFFu);
    r[1] = fp8dec1((v >> (W ? 24 : 8)) & 0xFFu);
    return r;
#endif
}

// ================= bucketed CSR build =================
constexpr int NB = 512;
constexpr int B1 = 256;

__global__ __launch_bounds__(256) void k_bhist(const int* dst, int E, int* cnt) {
    __shared__ int h[NB];
    int t = threadIdx.x, b = blockIdx.x;
    h[t] = 0; h[t + 256] = 0;
    __syncthreads();
    int chunk = (E + B1 - 1) / B1;
    int lo = b * chunk, hi = min(E, lo + chunk);
    for (int e = lo + t; e < hi; e += 256) atomicAdd(&h[dst[e] >> 8], 1);
    __syncthreads();
    cnt[(size_t)t * B1 + b] = h[t];
    cnt[(size_t)(t + 256) * B1 + b] = h[t + 256];
}

constexpr int SCAN_T = 256;
constexpr int SCAN_V = 8;
constexpr int SCAN_CHUNK = SCAN_T * SCAN_V;

__global__ void k_scan_part(const int* in, int* bsum, int N) {
    int b = blockIdx.x, t = threadIdx.x;
    int base = b * SCAN_CHUNK + t * SCAN_V;
    int s = 0;
#pragma unroll
    for (int j = 0; j < SCAN_V; j++) {
        int i = base + j;
        if (i < N) s += in[i];
    }
    __shared__ int wsums[SCAN_T / 64];
    for (int off = 32; off; off >>= 1) s += __shfl_down(s, off, 64);
    if ((t & 63) == 0) wsums[t >> 6] = s;
    __syncthreads();
    if (t == 0) {
        int tot = 0;
#pragma unroll
        for (int w = 0; w < SCAN_T / 64; w++) tot += wsums[w];
        bsum[b] = tot;
    }
}

__global__ void k_scan_top(int* bsum, int nb) {
    if (threadIdx.x == 0) {
        int run = 0;
        for (int i = 0; i < nb; i++) {
            int v = bsum[i];
            bsum[i] = run;
            run += v;
        }
    }
}

__global__ void k_scan_apply(const int* in, const int* bsum, int* out, int N) {
    int b = blockIdx.x, t = threadIdx.x;
    int base = b * SCAN_CHUNK + t * SCAN_V;
    int v[SCAN_V];
    int s = 0;
#pragma unroll
    for (int j = 0; j < SCAN_V; j++) {
        int i = base + j;
        v[j] = (i < N) ? in[i] : 0;
        s += v[j];
    }
    __shared__ int sums[SCAN_T];
    sums[t] = s;
    __syncthreads();
    for (int off = 1; off < SCAN_T; off <<= 1) {
        int x = (t >= off) ? sums[t - off] : 0;
        __syncthreads();
        sums[t] += x;
        __syncthreads();
    }
    int pre = bsum[b] + ((t == 0) ? 0 : sums[t - 1]);
#pragma unroll
    for (int j = 0; j < SCAN_V; j++) {
        int i = base + j;
        if (i < N) {
            out[i] = pre;
            pre += v[j];
            if (i == N - 1) out[N] = pre;
        }
    }
}

__global__ __launch_bounds__(256) void k_bscatter(const int* src, const int* dst, int E,
                                                  const int* cntoff, unsigned int* ebuf) {
    __shared__ int base[NB];
    __shared__ int lcur[NB];
    int t = threadIdx.x, b = blockIdx.x;
    for (int i = t; i < NB; i += 256) {
        base[i] = cntoff[(size_t)i * B1 + b];
        lcur[i] = 0;
    }
    __syncthreads();
    int chunk = (E + B1 - 1) / B1;
    int lo = b * chunk, hi = min(E, lo + chunk);
    for (int e = lo + t; e < hi; e += 256) {
        int d = dst[e];
        int cb = d >> 8;
        int slot = atomicAdd(&lcur[cb], 1);
        ebuf[base[cb] + slot] = (unsigned int)src[e] | ((unsigned int)(d & 255) << 17);
    }
}

__global__ __launch_bounds__(256) void k_build(const unsigned int* ebuf, const int* cntoff,
                                               int* rowptr, int* adj, int N, int E) {
    __shared__ int ldeg[256];
    __shared__ int lptr[256];
    __shared__ int lcur[256];
    __shared__ int tsum[256];
    int t = threadIdx.x, cb = blockIdx.x;
    int bbase = cntoff[(size_t)cb * B1];
    int bend = cntoff[(size_t)(cb + 1) * B1];
    ldeg[t] = 0;
    lcur[t] = 0;
    __syncthreads();
    for (int e = bbase + t; e < bend; e += 256) atomicAdd(&ldeg[ebuf[e] >> 17], 1);
    __syncthreads();
    tsum[t] = ldeg[t];
    __syncthreads();
    for (int off = 1; off < 256; off <<= 1) {
        int v = (t >= off) ? tsum[t - off] : 0;
        __syncthreads();
        tsum[t] += v;
        __syncthreads();
    }
    lptr[t] = tsum[t] - ldeg[t];
    __syncthreads();
    int node = cb * 256 + t;
    if (node < N) rowptr[node] = bbase + lptr[t];
    if (cb == 0 && t == 0) rowptr[N] = E;
    for (int e = bbase + t; e < bend; e += 256) {
        unsigned int pk = ebuf[e];
        int dl = pk >> 17;
        int ls = atomicAdd(&lcur[dl], 1);
        adj[bbase + lptr[dl] + ls] = (int)(pk & 0x1FFFF);
    }
}

// ---------------- dtype conversion (f32 -> bf16 + fp8) ----------------
__global__ void k_cvt(const float* x, unsigned short* xb, unsigned char* xq, int n) {
    int i = blockIdx.x * blockDim.x + threadIdx.x;
    int idx = i * 4;
    if (idx < n) {
        float4 v = *(const float4*)(x + idx);
        ushortx4 o;
        o[0] = f2bf(v.x); o[1] = f2bf(v.y); o[2] = f2bf(v.z); o[3] = f2bf(v.w);
        *(ushortx4*)(xb + idx) = o;
        unsigned int qw = (unsigned int)f2fp8(v.x) | ((unsigned int)f2fp8(v.y) << 8) |
                          ((unsigned int)f2fp8(v.z) << 16) | ((unsigned int)f2fp8(v.w) << 24);
        *(unsigned int*)(xq + idx) = qw;
    }
}

// arrange W = [Wl^T ; Wr^T] (256 x Do) into MFMA B-fragment order
__global__ void k_prep_w(const float* Wl, const float* Wr, unsigned short* w2f, int Do) {
    int t = blockIdx.x * blockDim.x + threadIdx.x;
    int NOC = Do >> 4;
    int total = 8 * NOC * 64 * 8;
    if (t >= total) return;
    int j = t & 7;
    int lane = (t >> 3) & 63;
    int rest = t >> 9;
    int oc = rest % NOC;
    int ks = rest / NOC;
    int k = ks * 32 + ((lane >> 4) << 3) + j;
    int o = oc * 16 + (lane & 15);
    float v = (k < 128) ? Wl[o * 128 + k] : Wr[o * 128 + (k - 128)];
    w2f[t] = f2bf(v);
}

__global__ void k_prep_w2(const float* Wl, const float* Wr, unsigned short* wf) {
    int t = blockIdx.x * blockDim.x + threadIdx.x;
    int total = 4 * 8 * 64 * 8;
    if (t >= total) return;
    int j = t & 7;
    int lane = (t >> 3) & 63;
    int rest = t >> 9;
    int oc = rest % 8;
    int ks = rest / 8;
    int k = ks * 32 + ((lane >> 4) << 3) + j;
    int o16 = lane & 15;
    float v = (oc < 4) ? Wl[(oc * 16 + o16) * 128 + k] : Wr[((oc - 4) * 16 + o16) * 128 + k];
    wf[t] = f2bf(v);
}

// ---------------- fp8 mean aggregation (32-lane group per node, unroll-8) ----------------
__global__ __launch_bounds__(256) void k_aggr8(const unsigned char* feat, const int* rowptr,
                                               const int* adj, unsigned short* aggr, int N) {
    int g = (blockIdx.x * blockDim.x + threadIdx.x) >> 5;
    int lane = threadIdx.x & 31;
    if (g >= N) return;
    int lo = rowptr[g], hi = rowptr[g + 1];
    float a0 = 0.f, a1 = 0.f, a2 = 0.f, a3 = 0.f;
    const unsigned char* fb = feat + lane * 4;
    int j = lo;
    for (; j + 8 <= hi; j += 8) {
        unsigned int v[8];
#pragma unroll
        for (int u = 0; u < 8; u++) {
            int s = adj[j + u];
            v[u] = *(const unsigned int*)(fb + (size_t)s * 128);
        }
#pragma unroll
        for (int u = 0; u < 8; u++) {
            floatx2 l2 = fp8pk2f<false>(v[u]);
            floatx2 h2 = fp8pk2f<true>(v[u]);
            a0 += l2[0]; a1 += l2[1]; a2 += h2[0]; a3 += h2[1];
        }
    }
    if (j < hi) {  // masked tail chunk
        unsigned int v[8];
        float w[8];
#pragma unroll
        for (int u = 0; u < 8; u++) {
            int jj = j + u;
            int s = adj[jj < hi ? jj : hi - 1];
            v[u] = *(const unsigned int*)(fb + (size_t)s * 128);
            w[u] = (jj < hi) ? 1.0f : 0.0f;
        }
#pragma unroll
        for (int u = 0; u < 8; u++) {
            floatx2 l2 = fp8pk2f<false>(v[u]);
            floatx2 h2 = fp8pk2f<true>(v[u]);
            a0 = fmaf(w[u], l2[0], a0);
            a1 = fmaf(w[u], l2[1], a1);
            a2 = fmaf(w[u], h2[0], a2);
            a3 = fmaf(w[u], h2[1], a3);
        }
    }
    float inv = 1.0f / (float)max(hi - lo, 1);
    ushortx4 o;
    o[0] = f2bf(a0 * inv); o[1] = f2bf(a1 * inv); o[2] = f2bf(a2 * inv); o[3] = f2bf(a3 * inv);
    *(ushortx4*)(aggr + (size_t)g * 128 + lane * 4) = o;
}

// 64-wide bf16 mean aggregation of t2, added into f32 out (16-lane group per node)
__global__ __launch_bounds__(256) void k_aggr64(const unsigned short* t2, const int* rowptr,
                                                const int* adj, float* out, int N) {
    int g = (blockIdx.x * blockDim.x + threadIdx.x) >> 4;
    int lane = threadIdx.x & 15;
    if (g >= N) return;
    int lo = rowptr[g], hi = rowptr[g + 1];
    float a0 = 0.f, a1 = 0.f, a2 = 0.f, a3 = 0.f;
    const unsigned short* fb = t2 + lane * 4;
    int j = lo;
    for (; j + 8 <= hi; j += 8) {
        ushortx4 v[8];
#pragma unroll
        for (int u = 0; u < 8; u++) {
            int s = adj[j + u];
            v[u] = *(const ushortx4*)(fb + (size_t)s * 64);
        }
#pragma unroll
        for (int u = 0; u < 8; u++) {
            a0 += bf2f(v[u][0]); a1 += bf2f(v[u][1]);
            a2 += bf2f(v[u][2]); a3 += bf2f(v[u][3]);
        }
    }
    if (j < hi) {
        ushortx4 v[8];
        float w[8];
#pragma unroll
        for (int u = 0; u < 8; u++) {
            int jj = j + u;
            int s = adj[jj < hi ? jj : hi - 1];
            v[u] = *(const ushortx4*)(fb + (size_t)s * 64);
            w[u] = (jj < hi) ? 1.0f : 0.0f;
        }
#pragma unroll
        for (int u = 0; u < 8; u++) {
            a0 = fmaf(w[u], bf2f(v[u][0]), a0);
            a1 = fmaf(w[u], bf2f(v[u][1]), a1);
            a2 = fmaf(w[u], bf2f(v[u][2]), a2);
            a3 = fmaf(w[u], bf2f(v[u][3]), a3);
        }
    }
    float inv = 1.0f / (float)max(hi - lo, 1);
    float* op = out + (size_t)g * 64 + lane * 4;
    float4 cur = *(float4*)op;
    cur.x += a0 * inv; cur.y += a1 * inv; cur.z += a2 * inv; cur.w += a3 * inv;
    *(float4*)op = cur;
}

// ---------------- fused transform: out = [aggr|feat] @ W + b (+relu) ----------------
template <int DO, bool RELU, bool OUTBF, bool WRITEQ>
__global__ __launch_bounds__(256) void k_xform(const unsigned short* aggr,
                                               const unsigned short* feat,
                                               const unsigned short* w2f,
                                               const float* bias, void* outp,
                                               unsigned char* q8, int N) {
    const int wave = threadIdx.x >> 6;
    const int lane = threadIdx.x & 63;
    const int nodeBase = blockIdx.x * 64 + wave * 16;
    const int row = nodeBase + (lane & 15);
    const int kq = lane >> 4;
    constexpr int NOC = DO / 16;
    floatx4 acc[NOC];
#pragma unroll
    for (int i = 0; i < NOC; i++) acc[i] = (floatx4)0.0f;
    const bool rowOK = row < N;
    const unsigned short* arow = aggr + (size_t)row * 128;
    const unsigned short* frow = feat + (size_t)row * 128;
    const short8* bbase = (const short8*)w2f;
#pragma unroll
    for (int ks = 0; ks < 8; ks++) {
        short8 a;
        if (rowOK) {
            const unsigned short* srcp =
                (ks < 4) ? (arow + ks * 32 + kq * 8) : (frow + (ks - 4) * 32 + kq * 8);
            a = *(const short8*)srcp;
        } else {
            a = (short8)0;
        }
#pragma unroll
        for (int oc = 0; oc < NOC; oc++) {
            short8 b = bbase[(ks * NOC + oc) * 64 + lane];
            acc[oc] = __builtin_amdgcn_mfma_f32_16x16x32_bf16(a, b, acc[oc], 0, 0, 0);
        }
    }
#pragma unroll
    for (int oc = 0; oc < NOC; oc++) {
        int o = oc * 16 + (lane & 15);
        float bv = bias[o];
#pragma unroll
        for (int j = 0; j < 4; j++) {
            int node = nodeBase + kq * 4 + j;
            if (node < N) {
                float v = acc[oc][j] + bv;
                if (RELU) v = fmaxf(v, 0.0f);
                if (OUTBF)
                    ((unsigned short*)outp)[(size_t)node * DO + o] = f2bf(v);
                else
                    ((float*)outp)[(size_t)node * DO + o] = v;
                if (WRITEQ) q8[(size_t)node * DO + o] = f2fp8(v);
            }
        }
    }
}

// layer-2 split transform: t2 = h @ Wl2^T (bf16), self = h @ Wr2^T + bl2 (f32 -> out)
__global__ __launch_bounds__(256) void k_xform2(const unsigned short* feat,
                                                const unsigned short* wf,
                                                const float* bias,
                                                unsigned short* t2, float* out, int N) {
    const int wave = threadIdx.x >> 6;
    const int lane = threadIdx.x & 63;
    const int nodeBase = blockIdx.x * 64 + wave * 16;
    const int row = nodeBase + (lane & 15);
    const int kq = lane >> 4;
    floatx4 acc[8];
#pragma unroll
    for (int i = 0; i < 8; i++) acc[i] = (floatx4)0.0f;
    const bool rowOK = row < N;
    const unsigned short* frow = feat + (size_t)row * 128;
    const short8* bbase = (const short8*)wf;
#pragma unroll
    for (int ks = 0; ks < 4; ks++) {
        short8 a;
        if (rowOK)
            a = *(const short8*)(frow + ks * 32 + kq * 8);
        else
            a = (short8)0;
#pragma unroll
        for (int oc = 0; oc < 8; oc++) {
            short8 b = bbase[(ks * 8 + oc) * 64 + lane];
            acc[oc] = __builtin_amdgcn_mfma_f32_16x16x32_bf16(a, b, acc[oc], 0, 0, 0);
        }
    }
#pragma unroll
    for (int oc = 0; oc < 8; oc++) {
        int o16 = lane & 15;
#pragma unroll
        for (int j = 0; j < 4; j++) {
            int node = nodeBase + kq * 4 + j;
            if (node < N) {
                if (oc < 4) {
                    t2[(size_t)node * 64 + oc * 16 + o16] = f2bf(acc[oc][j]);
                } else {
                    int o = (oc - 4) * 16 + o16;
                    out[(size_t)node * 64 + o] = acc[oc][j] + bias[o];
                }
            }
        }
    }
}

// ---------------- row-wise log_softmax ----------------
__global__ void k_lsm(float* out, int N) {
    int wave = threadIdx.x >> 6;
    int lane = threadIdx.x & 63;
    int rowi = blockIdx.x * 4 + wave;
    if (rowi >= N) return;
    float v = out[(size_t)rowi * 64 + lane];
    float m = v;
    for (int off = 32; off; off >>= 1) m = fmaxf(m, __shfl_xor(m, off, 64));
    float e = expf(v - m);
    float s = e;
    for (int off = 32; off; off >>= 1) s += __shfl_xor(s, off, 64);
    out[(size_t)rowi * 64 + lane] = v - m - logf(s);
}

extern "C" void kernel_launch(void* const* d_in, const int* in_sizes, int n_in,
                              void* d_out, int out_size, void* d_ws, size_t ws_size,
                              hipStream_t stream) {
    const float* x = (const float*)d_in[0];
    const int* ei = (const int*)d_in[1];
    const float* Wl0 = (const float*)d_in[2];
    const float* bl0 = (const float*)d_in[3];
    const float* Wr0 = (const float*)d_in[4];
    const float* Wl1 = (const float*)d_in[5];
    const float* bl1 = (const float*)d_in[6];
    const float* Wr1 = (const float*)d_in[7];
    const float* Wl2 = (const float*)d_in[8];
    const float* bl2 = (const float*)d_in[9];
    const float* Wr2 = (const float*)d_in[10];

    const int N = in_sizes[0] / 128;
    const int E = in_sizes[1] / 2;
    const int* src = ei;
    const int* dst = ei + E;

    char* ws = (char*)d_ws;
    size_t off = 0;
    auto alloc = [&](size_t bytes) {
        void* p = ws + off;
        off += (bytes + 255) & ~(size_t)255;
        return p;
    };
    int* cntin = (int*)alloc((size_t)NB * B1 * 4);
    int* cntoff = (int*)alloc(((size_t)NB * B1 + 1) * 4);
    int* bsum = (int*)alloc(1024 * 4);
    unsigned int* ebuf = (unsigned int*)alloc((size_t)E * 4);
    int* rowptr = (int*)alloc((size_t)(N + 1) * 4);
    int* adj = (int*)alloc((size_t)E * 4);
    unsigned short* xb = (unsigned short*)alloc((size_t)N * 128 * 2);
    unsigned short* aggr = (unsigned short*)alloc((size_t)N * 128 * 2);  // also t2
    unsigned short* hA = (unsigned short*)alloc((size_t)N * 128 * 2);
    unsigned short* hB = (unsigned short*)alloc((size_t)N * 128 * 2);
    unsigned char* q8 = (unsigned char*)alloc((size_t)N * 128);  // xq, then hAq
    unsigned short* w0 = (unsigned short*)alloc(8 * 8 * 64 * 8 * 2);
    unsigned short* w1 = (unsigned short*)alloc(8 * 8 * 64 * 8 * 2);
    unsigned short* w2 = (unsigned short*)alloc(4 * 8 * 64 * 8 * 2);

    // ---- bucketed CSR build ----
    const int NBUCK = (N + 255) >> 8;
    k_bhist<<<B1, 256, 0, stream>>>(dst, E, cntin);
    const int scanLen = NB * B1;
    const int nScanBlocks = (scanLen + SCAN_CHUNK - 1) / SCAN_CHUNK;
    k_scan_part<<<nScanBlocks, SCAN_T, 0, stream>>>(cntin, bsum, scanLen);
    k_scan_top<<<1, 64, 0, stream>>>(bsum, nScanBlocks);
    k_scan_apply<<<nScanBlocks, SCAN_T, 0, stream>>>(cntin, bsum, cntoff, scanLen);
    k_bscatter<<<B1, 256, 0, stream>>>(src, dst, E, cntoff, ebuf);
    k_build<<<NBUCK, 256, 0, stream>>>(ebuf, cntoff, rowptr, adj, N, E);

    // conversions / weight prep
    k_cvt<<<((N * 128 / 4) + 255) / 256, 256, 0, stream>>>(x, xb, q8, N * 128);
    k_prep_w<<<(32768 + 255) / 256, 256, 0, stream>>>(Wl0, Wr0, w0, 128);
    k_prep_w<<<(32768 + 255) / 256, 256, 0, stream>>>(Wl1, Wr1, w1, 128);
    k_prep_w2<<<(16384 + 255) / 256, 256, 0, stream>>>(Wl2, Wr2, w2);

    const int aggrGrid = ((N * 32) + 255) / 256;
    const int aggr64Grid = ((N * 16) + 255) / 256;
    const int xfGrid = (N + 63) / 64;

    // layer 0 (fp8 gather; xform writes bf16 hA + fp8 q8 for next layer)
    k_aggr8<<<aggrGrid, 256, 0, stream>>>(q8, rowptr, adj, aggr, N);
    k_xform<128, true, true, true><<<xfGrid, 256, 0, stream>>>(aggr, xb, w0, bl0, hA, q8, N);
    // layer 1 (fp8 gather)
    k_aggr8<<<aggrGrid, 256, 0, stream>>>(q8, rowptr, adj, aggr, N);
    k_xform<128, true, true, false><<<xfGrid, 256, 0, stream>>>(aggr, hA, w1, bl1, hB, nullptr, N);
    // layer 2: transform first (commutes with mean), then 64-wide bf16 aggregate
    k_xform2<<<xfGrid, 256, 0, stream>>>(hB, w2, bl2, aggr /*t2*/, (float*)d_out, N);
    k_aggr64<<<aggr64Grid, 256, 0, stream>>>(aggr /*t2*/, rowptr, adj, (float*)d_out, N);

    // log_softmax
    k_lsm<<<(N + 3) / 4, 256, 0, stream>>>((float*)d_out, N);
}

// Round 7
// 277.235 us; speedup vs baseline: 2.7166x; 1.0753x over previous
//
#include <hip/hip_runtime.h>
#include <hip/hip_bf16.h>
#include <math.h>

typedef __attribute__((ext_vector_type(8))) short short8;
typedef __attribute__((ext_vector_type(4))) float floatx4;
typedef __attribute__((ext_vector_type(2))) float floatx2;
typedef __attribute__((ext_vector_type(4))) unsigned short ushortx4;

__device__ __forceinline__ float bf2f(unsigned short u) {
    union { unsigned int i; float f; } c; c.i = ((unsigned int)u) << 16; return c.f;
}
__device__ __forceinline__ unsigned short f2bf(float f) {
    union { float f; unsigned int i; } c; c.f = f;
    unsigned int x = c.i;
    return (unsigned short)((x + 0x7FFFu + ((x >> 16) & 1u)) >> 16);
}

// ---------- fp8 e4m3fn (OCP) encode/decode ----------
__device__ __forceinline__ unsigned char f2fp8(float f) {
    unsigned int u = __float_as_uint(f);
    unsigned int sign = (u >> 24) & 0x80u;
    unsigned int a = u & 0x7FFFFFFFu;
    if (a >= 0x43E00000u) return (unsigned char)(sign | 0x7Eu);  // saturate at 448
    if (a < 0x3C800000u) {  // below smallest normal 2^-6: denormal units of 2^-9
        int unit = (int)rintf(__uint_as_float(a) * 512.0f);
        return (unsigned char)(sign | (unsigned int)unit);
    }
    unsigned int r = a + 0x7FFFFu + ((a >> 20) & 1u);  // RNE at bit 20
    unsigned int e = (r >> 23) - 120u;
    unsigned int m = (r >> 20) & 7u;
    return (unsigned char)(sign | (e << 3) | m);
}

__device__ __forceinline__ float fp8dec1(unsigned int b) {
    unsigned int s = (b & 0x80u) << 24;
    unsigned int mag = (b & 0x7Fu) << 20;
    return __uint_as_float(s | mag) * __uint_as_float(0x7B800000u);  // * 2^120
}

template <bool W>
__device__ __forceinline__ floatx2 fp8pk2f(unsigned int v) {
#if defined(__has_builtin) && __has_builtin(__builtin_amdgcn_cvt_pk_f32_fp8)
    return __builtin_amdgcn_cvt_pk_f32_fp8(v, W);
#else
    floatx2 r;
    r[0] = fp8dec1((v >> (W ? 16 : 0)) & 0xFFu);
    r[1] = fp8dec1((v >> (W ? 24 : 8)) & 0xFFu);
    return r;
#endif
}

// ================= bucketed CSR build =================
constexpr int NB = 512;
constexpr int B1 = 256;

__global__ __launch_bounds__(256) void k_bhist(const int* dst, int E, int* cnt) {
    __shared__ int h[NB];
    int t = threadIdx.x, b = blockIdx.x;
    h[t] = 0; h[t + 256] = 0;
    __syncthreads();
    int chunk = (E + B1 - 1) / B1;
    int lo = b * chunk, hi = min(E, lo + chunk);
    for (int e = lo + t; e < hi; e += 256) atomicAdd(&h[dst[e] >> 8], 1);
    __syncthreads();
    cnt[(size_t)t * B1 + b] = h[t];
    cnt[(size_t)(t + 256) * B1 + b] = h[t + 256];
}

constexpr int SCAN_T = 256;
constexpr int SCAN_V = 8;
constexpr int SCAN_CHUNK = SCAN_T * SCAN_V;

__global__ void k_scan_part(const int* in, int* bsum, int N) {
    int b = blockIdx.x, t = threadIdx.x;
    int base = b * SCAN_CHUNK + t * SCAN_V;
    int s = 0;
#pragma unroll
    for (int j = 0; j < SCAN_V; j++) {
        int i = base + j;
        if (i < N) s += in[i];
    }
    __shared__ int wsums[SCAN_T / 64];
    for (int off = 32; off; off >>= 1) s += __shfl_down(s, off, 64);
    if ((t & 63) == 0) wsums[t >> 6] = s;
    __syncthreads();
    if (t == 0) {
        int tot = 0;
#pragma unroll
        for (int w = 0; w < SCAN_T / 64; w++) tot += wsums[w];
        bsum[b] = tot;
    }
}

__global__ void k_scan_top(int* bsum, int nb) {
    if (threadIdx.x == 0) {
        int run = 0;
        for (int i = 0; i < nb; i++) {
            int v = bsum[i];
            bsum[i] = run;
            run += v;
        }
    }
}

__global__ void k_scan_apply(const int* in, const int* bsum, int* out, int N) {
    int b = blockIdx.x, t = threadIdx.x;
    int base = b * SCAN_CHUNK + t * SCAN_V;
    int v[SCAN_V];
    int s = 0;
#pragma unroll
    for (int j = 0; j < SCAN_V; j++) {
        int i = base + j;
        v[j] = (i < N) ? in[i] : 0;
        s += v[j];
    }
    __shared__ int sums[SCAN_T];
    sums[t] = s;
    __syncthreads();
    for (int off = 1; off < SCAN_T; off <<= 1) {
        int x = (t >= off) ? sums[t - off] : 0;
        __syncthreads();
        sums[t] += x;
        __syncthreads();
    }
    int pre = bsum[b] + ((t == 0) ? 0 : sums[t - 1]);
#pragma unroll
    for (int j = 0; j < SCAN_V; j++) {
        int i = base + j;
        if (i < N) {
            out[i] = pre;
            pre += v[j];
            if (i == N - 1) out[N] = pre;
        }
    }
}

__global__ __launch_bounds__(256) void k_bscatter(const int* src, const int* dst, int E,
                                                  const int* cntoff, unsigned int* ebuf) {
    __shared__ int base[NB];
    __shared__ int lcur[NB];
    int t = threadIdx.x, b = blockIdx.x;
    for (int i = t; i < NB; i += 256) {
        base[i] = cntoff[(size_t)i * B1 + b];
        lcur[i] = 0;
    }
    __syncthreads();
    int chunk = (E + B1 - 1) / B1;
    int lo = b * chunk, hi = min(E, lo + chunk);
    for (int e = lo + t; e < hi; e += 256) {
        int d = dst[e];
        int cb = d >> 8;
        int slot = atomicAdd(&lcur[cb], 1);
        ebuf[base[cb] + slot] = (unsigned int)src[e] | ((unsigned int)(d & 255) << 17);
    }
}

__global__ __launch_bounds__(256) void k_build(const unsigned int* ebuf, const int* cntoff,
                                               int* rowptr, int* adj, int N, int E) {
    __shared__ int ldeg[256];
    __shared__ int lptr[256];
    __shared__ int lcur[256];
    __shared__ int tsum[256];
    int t = threadIdx.x, cb = blockIdx.x;
    int bbase = cntoff[(size_t)cb * B1];
    int bend = cntoff[(size_t)(cb + 1) * B1];
    ldeg[t] = 0;
    lcur[t] = 0;
    __syncthreads();
    for (int e = bbase + t; e < bend; e += 256) atomicAdd(&ldeg[ebuf[e] >> 17], 1);
    __syncthreads();
    tsum[t] = ldeg[t];
    __syncthreads();
    for (int off = 1; off < 256; off <<= 1) {
        int v = (t >= off) ? tsum[t - off] : 0;
        __syncthreads();
        tsum[t] += v;
        __syncthreads();
    }
    lptr[t] = tsum[t] - ldeg[t];
    __syncthreads();
    int node = cb * 256 + t;
    if (node < N) rowptr[node] = bbase + lptr[t];
    if (cb == 0 && t == 0) rowptr[N] = E;
    for (int e = bbase + t; e < bend; e += 256) {
        unsigned int pk = ebuf[e];
        int dl = pk >> 17;
        int ls = atomicAdd(&lcur[dl], 1);
        adj[bbase + lptr[dl] + ls] = (int)(pk & 0x1FFFF);
    }
}

// ---------------- dtype conversion (f32 -> bf16 + fp8) ----------------
__global__ void k_cvt(const float* x, unsigned short* xb, unsigned char* xq, int n) {
    int i = blockIdx.x * blockDim.x + threadIdx.x;
    int idx = i * 4;
    if (idx < n) {
        float4 v = *(const float4*)(x + idx);
        ushortx4 o;
        o[0] = f2bf(v.x); o[1] = f2bf(v.y); o[2] = f2bf(v.z); o[3] = f2bf(v.w);
        *(ushortx4*)(xb + idx) = o;
        unsigned int qw = (unsigned int)f2fp8(v.x) | ((unsigned int)f2fp8(v.y) << 8) |
                          ((unsigned int)f2fp8(v.z) << 16) | ((unsigned int)f2fp8(v.w) << 24);
        *(unsigned int*)(xq + idx) = qw;
    }
}

// arrange W = [Wl^T ; Wr^T] (256 x Do) into MFMA B-fragment order
__global__ void k_prep_w(const float* Wl, const float* Wr, unsigned short* w2f, int Do) {
    int t = blockIdx.x * blockDim.x + threadIdx.x;
    int NOC = Do >> 4;
    int total = 8 * NOC * 64 * 8;
    if (t >= total) return;
    int j = t & 7;
    int lane = (t >> 3) & 63;
    int rest = t >> 9;
    int oc = rest % NOC;
    int ks = rest / NOC;
    int k = ks * 32 + ((lane >> 4) << 3) + j;
    int o = oc * 16 + (lane & 15);
    float v = (k < 128) ? Wl[o * 128 + k] : Wr[o * 128 + (k - 128)];
    w2f[t] = f2bf(v);
}

__global__ void k_prep_w2(const float* Wl, const float* Wr, unsigned short* wf) {
    int t = blockIdx.x * blockDim.x + threadIdx.x;
    int total = 4 * 8 * 64 * 8;
    if (t >= total) return;
    int j = t & 7;
    int lane = (t >> 3) & 63;
    int rest = t >> 9;
    int oc = rest % 8;
    int ks = rest / 8;
    int k = ks * 32 + ((lane >> 4) << 3) + j;
    int o16 = lane & 15;
    float v = (oc < 4) ? Wl[(oc * 16 + o16) * 128 + k] : Wr[((oc - 4) * 16 + o16) * 128 + k];
    wf[t] = f2bf(v);
}

// ---------------- fp8 mean aggregation (32-lane group per node, unroll-8) ----------------
__global__ __launch_bounds__(256) void k_aggr8(const unsigned char* feat, const int* rowptr,
                                               const int* adj, unsigned short* aggr, int N) {
    int g = (blockIdx.x * blockDim.x + threadIdx.x) >> 5;
    int lane = threadIdx.x & 31;
    if (g >= N) return;
    int lo = rowptr[g], hi = rowptr[g + 1];
    float a0 = 0.f, a1 = 0.f, a2 = 0.f, a3 = 0.f;
    const unsigned char* fb = feat + lane * 4;
    int j = lo;
    for (; j + 8 <= hi; j += 8) {
        unsigned int v[8];
#pragma unroll
        for (int u = 0; u < 8; u++) {
            int s = adj[j + u];
            v[u] = *(const unsigned int*)(fb + (size_t)s * 128);
        }
#pragma unroll
        for (int u = 0; u < 8; u++) {
            floatx2 l2 = fp8pk2f<false>(v[u]);
            floatx2 h2 = fp8pk2f<true>(v[u]);
            a0 += l2[0]; a1 += l2[1]; a2 += h2[0]; a3 += h2[1];
        }
    }
    if (j < hi) {
        unsigned int v[8];
        float w[8];
#pragma unroll
        for (int u = 0; u < 8; u++) {
            int jj = j + u;
            int s = adj[jj < hi ? jj : hi - 1];
            v[u] = *(const unsigned int*)(fb + (size_t)s * 128);
            w[u] = (jj < hi) ? 1.0f : 0.0f;
        }
#pragma unroll
        for (int u = 0; u < 8; u++) {
            floatx2 l2 = fp8pk2f<false>(v[u]);
            floatx2 h2 = fp8pk2f<true>(v[u]);
            a0 = fmaf(w[u], l2[0], a0);
            a1 = fmaf(w[u], l2[1], a1);
            a2 = fmaf(w[u], h2[0], a2);
            a3 = fmaf(w[u], h2[1], a3);
        }
    }
    float inv = 1.0f / (float)max(hi - lo, 1);
    ushortx4 o;
    o[0] = f2bf(a0 * inv); o[1] = f2bf(a1 * inv); o[2] = f2bf(a2 * inv); o[3] = f2bf(a3 * inv);
    *(ushortx4*)(aggr + (size_t)g * 128 + lane * 4) = o;
}

// 64-wide bf16 mean aggregation of t2, added into f32 out (16-lane group per node)
__global__ __launch_bounds__(256) void k_aggr64(const unsigned short* t2, const int* rowptr,
                                                const int* adj, float* out, int N) {
    int g = (blockIdx.x * blockDim.x + threadIdx.x) >> 4;
    int lane = threadIdx.x & 15;
    if (g >= N) return;
    int lo = rowptr[g], hi = rowptr[g + 1];
    float a0 = 0.f, a1 = 0.f, a2 = 0.f, a3 = 0.f;
    const unsigned short* fb = t2 + lane * 4;
    int j = lo;
    for (; j + 8 <= hi; j += 8) {
        ushortx4 v[8];
#pragma unroll
        for (int u = 0; u < 8; u++) {
            int s = adj[j + u];
            v[u] = *(const ushortx4*)(fb + (size_t)s * 64);
        }
#pragma unroll
        for (int u = 0; u < 8; u++) {
            a0 += bf2f(v[u][0]); a1 += bf2f(v[u][1]);
            a2 += bf2f(v[u][2]); a3 += bf2f(v[u][3]);
        }
    }
    if (j < hi) {
        ushortx4 v[8];
        float w[8];
#pragma unroll
        for (int u = 0; u < 8; u++) {
            int jj = j + u;
            int s = adj[jj < hi ? jj : hi - 1];
            v[u] = *(const ushortx4*)(fb + (size_t)s * 64);
            w[u] = (jj < hi) ? 1.0f : 0.0f;
        }
#pragma unroll
        for (int u = 0; u < 8; u++) {
            a0 = fmaf(w[u], bf2f(v[u][0]), a0);
            a1 = fmaf(w[u], bf2f(v[u][1]), a1);
            a2 = fmaf(w[u], bf2f(v[u][2]), a2);
            a3 = fmaf(w[u], bf2f(v[u][3]), a3);
        }
    }
    float inv = 1.0f / (float)max(hi - lo, 1);
    float* op = out + (size_t)g * 64 + lane * 4;
    float4 cur = *(float4*)op;
    cur.x += a0 * inv; cur.y += a1 * inv; cur.z += a2 * inv; cur.w += a3 * inv;
    *(float4*)op = cur;
}

// ---------------- fused transform (DO=128, relu): out = [aggr|feat] @ W + b ----------------
// LDS-staged epilogue: full-line coalesced stores for bf16 out (+ derived fp8 q8)
template <bool WRITEQ>
__global__ __launch_bounds__(256) void k_xform(const unsigned short* aggr,
                                               const unsigned short* feat,
                                               const unsigned short* w2f,
                                               const float* bias, unsigned short* outp,
                                               unsigned char* q8, int N) {
    __shared__ unsigned short st[64][132];  // pad 132: kq-groups hit disjoint bank octets
    const int wave = threadIdx.x >> 6;
    const int lane = threadIdx.x & 63;
    const int nodeBase = blockIdx.x * 64 + wave * 16;
    const int row = nodeBase + (lane & 15);
    const int kq = lane >> 4;
    floatx4 acc[8];
#pragma unroll
    for (int i = 0; i < 8; i++) acc[i] = (floatx4)0.0f;
    const bool rowOK = row < N;
    const unsigned short* arow = aggr + (size_t)row * 128;
    const unsigned short* frow = feat + (size_t)row * 128;
    const short8* bbase = (const short8*)w2f;
#pragma unroll
    for (int ks = 0; ks < 8; ks++) {
        short8 a;
        if (rowOK) {
            const unsigned short* srcp =
                (ks < 4) ? (arow + ks * 32 + kq * 8) : (frow + (ks - 4) * 32 + kq * 8);
            a = *(const short8*)srcp;
        } else {
            a = (short8)0;
        }
#pragma unroll
        for (int oc = 0; oc < 8; oc++) {
            short8 b = bbase[(ks * 8 + oc) * 64 + lane];
            acc[oc] = __builtin_amdgcn_mfma_f32_16x16x32_bf16(a, b, acc[oc], 0, 0, 0);
        }
    }
    // stage to LDS (bank-conflict-free: see pad)
    const int rl = wave * 16 + kq * 4;
#pragma unroll
    for (int oc = 0; oc < 8; oc++) {
        int o = oc * 16 + (lane & 15);
        float bv = bias[o];
#pragma unroll
        for (int j = 0; j < 4; j++) {
            float v = fmaxf(acc[oc][j] + bv, 0.0f);
            st[rl + j][o] = f2bf(v);
        }
    }
    __syncthreads();
    // coalesced bf16 stores: 1024 chunks of 16 B (full 64B lines per 4 threads)
    const int bRow0 = blockIdx.x * 64;
    const int t = threadIdx.x;
#pragma unroll
    for (int i = 0; i < 4; i++) {
        int c = t + i * 256;
        int r = c >> 4;
        int pos = (c & 15) * 8;
        int node = bRow0 + r;
        if (node < N) {
            short8 v = *(const short8*)&st[r][pos];
            *(short8*)(outp + (size_t)node * 128 + pos) = v;
        }
    }
    if (WRITEQ) {
        // packed fp8 stores: 512 chunks of 16 B
#pragma unroll
        for (int i = 0; i < 2; i++) {
            int c = t + i * 256;
            int r = c >> 3;
            int pos = (c & 7) * 16;
            int node = bRow0 + r;
            if (node < N) {
                short8 v0 = *(const short8*)&st[r][pos];
                short8 v1 = *(const short8*)&st[r][pos + 8];
                unsigned int w[4];
#pragma unroll
                for (int q = 0; q < 2; q++) {
                    w[q] = (unsigned int)f2fp8(bf2f((unsigned short)v0[q * 4 + 0])) |
                           ((unsigned int)f2fp8(bf2f((unsigned short)v0[q * 4 + 1])) << 8) |
                           ((unsigned int)f2fp8(bf2f((unsigned short)v0[q * 4 + 2])) << 16) |
                           ((unsigned int)f2fp8(bf2f((unsigned short)v0[q * 4 + 3])) << 24);
                    w[q + 2] = (unsigned int)f2fp8(bf2f((unsigned short)v1[q * 4 + 0])) |
                               ((unsigned int)f2fp8(bf2f((unsigned short)v1[q * 4 + 1])) << 8) |
                               ((unsigned int)f2fp8(bf2f((unsigned short)v1[q * 4 + 2])) << 16) |
                               ((unsigned int)f2fp8(bf2f((unsigned short)v1[q * 4 + 3])) << 24);
                }
                uint4 u;
                u.x = w[0]; u.y = w[1]; u.z = w[2]; u.w = w[3];
                *(uint4*)(q8 + (size_t)node * 128 + pos) = u;
            }
        }
    }
}

// layer-2 split transform: t2 = h @ Wl2^T (bf16, LDS-staged), self = h @ Wr2^T + bl2 (f32)
__global__ __launch_bounds__(256) void k_xform2(const unsigned short* feat,
                                                const unsigned short* wf,
                                                const float* bias,
                                                unsigned short* t2, float* out, int N) {
    __shared__ unsigned short st[64][68];  // pad 68: kq-groups on disjoint banks
    const int wave = threadIdx.x >> 6;
    const int lane = threadIdx.x & 63;
    const int nodeBase = blockIdx.x * 64 + wave * 16;
    const int row = nodeBase + (lane & 15);
    const int kq = lane >> 4;
    floatx4 acc[8];
#pragma unroll
    for (int i = 0; i < 8; i++) acc[i] = (floatx4)0.0f;
    const bool rowOK = row < N;
    const unsigned short* frow = feat + (size_t)row * 128;
    const short8* bbase = (const short8*)wf;
#pragma unroll
    for (int ks = 0; ks < 4; ks++) {
        short8 a;
        if (rowOK)
            a = *(const short8*)(frow + ks * 32 + kq * 8);
        else
            a = (short8)0;
#pragma unroll
        for (int oc = 0; oc < 8; oc++) {
            short8 b = bbase[(ks * 8 + oc) * 64 + lane];
            acc[oc] = __builtin_amdgcn_mfma_f32_16x16x32_bf16(a, b, acc[oc], 0, 0, 0);
        }
    }
    const int rl = wave * 16 + kq * 4;
    const int o16 = lane & 15;
#pragma unroll
    for (int oc = 0; oc < 8; oc++) {
#pragma unroll
        for (int j = 0; j < 4; j++) {
            int node = nodeBase + kq * 4 + j;
            if (oc < 4) {
                st[rl + j][oc * 16 + o16] = f2bf(acc[oc][j]);
            } else if (node < N) {
                int o = (oc - 4) * 16 + o16;
                out[(size_t)node * 64 + o] = acc[oc][j] + bias[o];  // full-line (64B/16 lanes)
            }
        }
    }
    __syncthreads();
    // coalesced t2 stores: 512 chunks of 16 B
    const int bRow0 = blockIdx.x * 64;
    const int t = threadIdx.x;
#pragma unroll
    for (int i = 0; i < 2; i++) {
        int c = t + i * 256;
        int r = c >> 3;
        int pos = (c & 7) * 8;
        int node = bRow0 + r;
        if (node < N) {
            short8 v = *(const short8*)&st[r][pos];
            *(short8*)(t2 + (size_t)node * 64 + pos) = v;
        }
    }
}

// ---------------- row-wise log_softmax ----------------
__global__ void k_lsm(float* out, int N) {
    int wave = threadIdx.x >> 6;
    int lane = threadIdx.x & 63;
    int rowi = blockIdx.x * 4 + wave;
    if (rowi >= N) return;
    float v = out[(size_t)rowi * 64 + lane];
    float m = v;
    for (int off = 32; off; off >>= 1) m = fmaxf(m, __shfl_xor(m, off, 64));
    float e = expf(v - m);
    float s = e;
    for (int off = 32; off; off >>= 1) s += __shfl_xor(s, off, 64);
    out[(size_t)rowi * 64 + lane] = v - m - logf(s);
}

extern "C" void kernel_launch(void* const* d_in, const int* in_sizes, int n_in,
                              void* d_out, int out_size, void* d_ws, size_t ws_size,
                              hipStream_t stream) {
    const float* x = (const float*)d_in[0];
    const int* ei = (const int*)d_in[1];
    const float* Wl0 = (const float*)d_in[2];
    const float* bl0 = (const float*)d_in[3];
    const float* Wr0 = (const float*)d_in[4];
    const float* Wl1 = (const float*)d_in[5];
    const float* bl1 = (const float*)d_in[6];
    const float* Wr1 = (const float*)d_in[7];
    const float* Wl2 = (const float*)d_in[8];
    const float* bl2 = (const float*)d_in[9];
    const float* Wr2 = (const float*)d_in[10];

    const int N = in_sizes[0] / 128;
    const int E = in_sizes[1] / 2;
    const int* src = ei;
    const int* dst = ei + E;

    char* ws = (char*)d_ws;
    size_t off = 0;
    auto alloc = [&](size_t bytes) {
        void* p = ws + off;
        off += (bytes + 255) & ~(size_t)255;
        return p;
    };
    int* cntin = (int*)alloc((size_t)NB * B1 * 4);
    int* cntoff = (int*)alloc(((size_t)NB * B1 + 1) * 4);
    int* bsum = (int*)alloc(1024 * 4);
    unsigned int* ebuf = (unsigned int*)alloc((size_t)E * 4);
    int* rowptr = (int*)alloc((size_t)(N + 1) * 4);
    int* adj = (int*)alloc((size_t)E * 4);
    unsigned short* xb = (unsigned short*)alloc((size_t)N * 128 * 2);
    unsigned short* aggr = (unsigned short*)alloc((size_t)N * 128 * 2);  // also t2
    unsigned short* hA = (unsigned short*)alloc((size_t)N * 128 * 2);
    unsigned short* hB = (unsigned short*)alloc((size_t)N * 128 * 2);
    unsigned char* q8 = (unsigned char*)alloc((size_t)N * 128);  // xq, then hAq
    unsigned short* w0 = (unsigned short*)alloc(8 * 8 * 64 * 8 * 2);
    unsigned short* w1 = (unsigned short*)alloc(8 * 8 * 64 * 8 * 2);
    unsigned short* w2 = (unsigned short*)alloc(4 * 8 * 64 * 8 * 2);

    // ---- bucketed CSR build ----
    const int NBUCK = (N + 255) >> 8;
    k_bhist<<<B1, 256, 0, stream>>>(dst, E, cntin);
    const int scanLen = NB * B1;
    const int nScanBlocks = (scanLen + SCAN_CHUNK - 1) / SCAN_CHUNK;
    k_scan_part<<<nScanBlocks, SCAN_T, 0, stream>>>(cntin, bsum, scanLen);
    k_scan_top<<<1, 64, 0, stream>>>(bsum, nScanBlocks);
    k_scan_apply<<<nScanBlocks, SCAN_T, 0, stream>>>(cntin, bsum, cntoff, scanLen);
    k_bscatter<<<B1, 256, 0, stream>>>(src, dst, E, cntoff, ebuf);
    k_build<<<NBUCK, 256, 0, stream>>>(ebuf, cntoff, rowptr, adj, N, E);

    // conversions / weight prep
    k_cvt<<<((N * 128 / 4) + 255) / 256, 256, 0, stream>>>(x, xb, q8, N * 128);
    k_prep_w<<<(32768 + 255) / 256, 256, 0, stream>>>(Wl0, Wr0, w0, 128);
    k_prep_w<<<(32768 + 255) / 256, 256, 0, stream>>>(Wl1, Wr1, w1, 128);
    k_prep_w2<<<(16384 + 255) / 256, 256, 0, stream>>>(Wl2, Wr2, w2);

    const int aggrGrid = ((N * 32) + 255) / 256;
    const int aggr64Grid = ((N * 16) + 255) / 256;
    const int xfGrid = (N + 63) / 64;

    // layer 0 (fp8 gather; xform writes bf16 hA + fp8 q8 for next layer)
    k_aggr8<<<aggrGrid, 256, 0, stream>>>(q8, rowptr, adj, aggr, N);
    k_xform<true><<<xfGrid, 256, 0, stream>>>(aggr, xb, w0, bl0, hA, q8, N);
    // layer 1 (fp8 gather)
    k_aggr8<<<aggrGrid, 256, 0, stream>>>(q8, rowptr, adj, aggr, N);
    k_xform<false><<<xfGrid, 256, 0, stream>>>(aggr, hA, w1, bl1, hB, nullptr, N);
    // layer 2: transform first (commutes with mean), then 64-wide bf16 aggregate
    k_xform2<<<xfGrid, 256, 0, stream>>>(hB, w2, bl2, aggr /*t2*/, (float*)d_out, N);
    k_aggr64<<<aggr64Grid, 256, 0, stream>>>(aggr /*t2*/, rowptr, adj, (float*)d_out, N);

    // log_softmax
    k_lsm<<<(N + 3) / 4, 256, 0, stream>>>((float*)d_out, N);
}

// Round 9
// 275.361 us; speedup vs baseline: 2.7351x; 1.0068x over previous
//
#include <hip/hip_runtime.h>
#include <hip/hip_bf16.h>
#include <math.h>

typedef __attribute__((ext_vector_type(8))) short short8;
typedef __attribute__((ext_vector_type(4))) float floatx4;
typedef __attribute__((ext_vector_type(2))) float floatx2;
typedef __attribute__((ext_vector_type(4))) unsigned short ushortx4;

__device__ __forceinline__ float bf2f(unsigned short u) {
    union { unsigned int i; float f; } c; c.i = ((unsigned int)u) << 16; return c.f;
}
__device__ __forceinline__ unsigned short f2bf(float f) {
    union { float f; unsigned int i; } c; c.f = f;
    unsigned int x = c.i;
    return (unsigned short)((x + 0x7FFFu + ((x >> 16) & 1u)) >> 16);
}

// ---------- fp8 e4m3fn (OCP) encode/decode ----------
__device__ __forceinline__ unsigned char f2fp8(float f) {
    unsigned int u = __float_as_uint(f);
    unsigned int sign = (u >> 24) & 0x80u;
    unsigned int a = u & 0x7FFFFFFFu;
    if (a >= 0x43E00000u) return (unsigned char)(sign | 0x7Eu);  // saturate at 448
    if (a < 0x3C800000u) {  // below smallest normal 2^-6: denormal units of 2^-9
        int unit = (int)rintf(__uint_as_float(a) * 512.0f);
        return (unsigned char)(sign | (unsigned int)unit);
    }
    unsigned int r = a + 0x7FFFFu + ((a >> 20) & 1u);  // RNE at bit 20
    unsigned int e = (r >> 23) - 120u;
    unsigned int m = (r >> 20) & 7u;
    return (unsigned char)(sign | (e << 3) | m);
}

__device__ __forceinline__ float fp8dec1(unsigned int b) {
    unsigned int s = (b & 0x80u) << 24;
    unsigned int mag = (b & 0x7Fu) << 20;
    return __uint_as_float(s | mag) * __uint_as_float(0x7B800000u);  // * 2^120
}

template <bool W>
__device__ __forceinline__ floatx2 fp8pk2f(unsigned int v) {
#if defined(__has_builtin) && __has_builtin(__builtin_amdgcn_cvt_pk_f32_fp8)
    return __builtin_amdgcn_cvt_pk_f32_fp8(v, W);
#else
    floatx2 r;
    r[0] = fp8dec1((v >> (W ? 16 : 0)) & 0xFFu);
    r[1] = fp8dec1((v >> (W ? 24 : 8)) & 0xFFu);
    return r;
#endif
}

// ================= bucketed CSR build =================
constexpr int NB = 512;
constexpr int B1 = 256;

__global__ __launch_bounds__(256) void k_bhist(const int* dst, int E, int* cnt) {
    __shared__ int h[NB];
    int t = threadIdx.x, b = blockIdx.x;
    h[t] = 0; h[t + 256] = 0;
    __syncthreads();
    int chunk = (E + B1 - 1) / B1;
    int lo = b * chunk, hi = min(E, lo + chunk);
    for (int e = lo + t; e < hi; e += 256) atomicAdd(&h[dst[e] >> 8], 1);
    __syncthreads();
    cnt[(size_t)t * B1 + b] = h[t];
    cnt[(size_t)(t + 256) * B1 + b] = h[t + 256];
}

constexpr int SCAN_T = 256;
constexpr int SCAN_V = 8;
constexpr int SCAN_CHUNK = SCAN_T * SCAN_V;

__global__ void k_scan_part(const int* in, int* bsum, int N) {
    int b = blockIdx.x, t = threadIdx.x;
    int base = b * SCAN_CHUNK + t * SCAN_V;
    int s = 0;
#pragma unroll
    for (int j = 0; j < SCAN_V; j++) {
        int i = base + j;
        if (i < N) s += in[i];
    }
    __shared__ int wsums[SCAN_T / 64];
    for (int off = 32; off; off >>= 1) s += __shfl_down(s, off, 64);
    if ((t & 63) == 0) wsums[t >> 6] = s;
    __syncthreads();
    if (t == 0) {
        int tot = 0;
#pragma unroll
        for (int w = 0; w < SCAN_T / 64; w++) tot += wsums[w];
        bsum[b] = tot;
    }
}

__global__ void k_scan_top(int* bsum, int nb) {
    if (threadIdx.x == 0) {
        int run = 0;
        for (int i = 0; i < nb; i++) {
            int v = bsum[i];
            bsum[i] = run;
            run += v;
        }
    }
}

__global__ void k_scan_apply(const int* in, const int* bsum, int* out, int N) {
    int b = blockIdx.x, t = threadIdx.x;
    int base = b * SCAN_CHUNK + t * SCAN_V;
    int v[SCAN_V];
    int s = 0;
#pragma unroll
    for (int j = 0; j < SCAN_V; j++) {
        int i = base + j;
        v[j] = (i < N) ? in[i] : 0;
        s += v[j];
    }
    __shared__ int sums[SCAN_T];
    sums[t] = s;
    __syncthreads();
    for (int off = 1; off < SCAN_T; off <<= 1) {
        int x = (t >= off) ? sums[t - off] : 0;
        __syncthreads();
        sums[t] += x;
        __syncthreads();
    }
    int pre = bsum[b] + ((t == 0) ? 0 : sums[t - 1]);
#pragma unroll
    for (int j = 0; j < SCAN_V; j++) {
        int i = base + j;
        if (i < N) {
            out[i] = pre;
            pre += v[j];
            if (i == N - 1) out[N] = pre;
        }
    }
}

__global__ __launch_bounds__(256) void k_bscatter(const int* src, const int* dst, int E,
                                                  const int* cntoff, unsigned int* ebuf) {
    __shared__ int base[NB];
    __shared__ int lcur[NB];
    int t = threadIdx.x, b = blockIdx.x;
    for (int i = t; i < NB; i += 256) {
        base[i] = cntoff[(size_t)i * B1 + b];
        lcur[i] = 0;
    }
    __syncthreads();
    int chunk = (E + B1 - 1) / B1;
    int lo = b * chunk, hi = min(E, lo + chunk);
    for (int e = lo + t; e < hi; e += 256) {
        int d = dst[e];
        int cb = d >> 8;
        int slot = atomicAdd(&lcur[cb], 1);
        ebuf[base[cb] + slot] = (unsigned int)src[e] | ((unsigned int)(d & 255) << 17);
    }
}

__global__ __launch_bounds__(256) void k_build(const unsigned int* ebuf, const int* cntoff,
                                               int* rowptr, int* adj, int N, int E) {
    __shared__ int ldeg[256];
    __shared__ int lptr[256];
    __shared__ int lcur[256];
    __shared__ int tsum[256];
    int t = threadIdx.x, cb = blockIdx.x;
    int bbase = cntoff[(size_t)cb * B1];
    int bend = cntoff[(size_t)(cb + 1) * B1];
    ldeg[t] = 0;
    lcur[t] = 0;
    __syncthreads();
    for (int e = bbase + t; e < bend; e += 256) atomicAdd(&ldeg[ebuf[e] >> 17], 1);
    __syncthreads();
    tsum[t] = ldeg[t];
    __syncthreads();
    for (int off = 1; off < 256; off <<= 1) {
        int v = (t >= off) ? tsum[t - off] : 0;
        __syncthreads();
        tsum[t] += v;
        __syncthreads();
    }
    lptr[t] = tsum[t] - ldeg[t];
    __syncthreads();
    int node = cb * 256 + t;
    if (node < N) rowptr[node] = bbase + lptr[t];
    if (cb == 0 && t == 0) rowptr[N] = E;
    for (int e = bbase + t; e < bend; e += 256) {
        unsigned int pk = ebuf[e];
        int dl = pk >> 17;
        int ls = atomicAdd(&lcur[dl], 1);
        adj[bbase + lptr[dl] + ls] = (int)(pk & 0x1FFFF);
    }
}

// ---------------- dtype conversion (f32 -> bf16 + fp8) ----------------
__global__ void k_cvt(const float* x, unsigned short* xb, unsigned char* xq, int n) {
    int i = blockIdx.x * blockDim.x + threadIdx.x;
    int idx = i * 4;
    if (idx < n) {
        float4 v = *(const float4*)(x + idx);
        ushortx4 o;
        o[0] = f2bf(v.x); o[1] = f2bf(v.y); o[2] = f2bf(v.z); o[3] = f2bf(v.w);
        *(ushortx4*)(xb + idx) = o;
        unsigned int qw = (unsigned int)f2fp8(v.x) | ((unsigned int)f2fp8(v.y) << 8) |
                          ((unsigned int)f2fp8(v.z) << 16) | ((unsigned int)f2fp8(v.w) << 24);
        *(unsigned int*)(xq + idx) = qw;
    }
}

// arrange W = [Wl^T ; Wr^T] (256 x Do) into MFMA B-fragment order
__global__ void k_prep_w(const float* Wl, const float* Wr, unsigned short* w2f, int Do) {
    int t = blockIdx.x * blockDim.x + threadIdx.x;
    int NOC = Do >> 4;
    int total = 8 * NOC * 64 * 8;
    if (t >= total) return;
    int j = t & 7;
    int lane = (t >> 3) & 63;
    int rest = t >> 9;
    int oc = rest % NOC;
    int ks = rest / NOC;
    int k = ks * 32 + ((lane >> 4) << 3) + j;
    int o = oc * 16 + (lane & 15);
    float v = (k < 128) ? Wl[o * 128 + k] : Wr[o * 128 + (k - 128)];
    w2f[t] = f2bf(v);
}

__global__ void k_prep_w2(const float* Wl, const float* Wr, unsigned short* wf) {
    int t = blockIdx.x * blockDim.x + threadIdx.x;
    int total = 4 * 8 * 64 * 8;
    if (t >= total) return;
    int j = t & 7;
    int lane = (t >> 3) & 63;
    int rest = t >> 9;
    int oc = rest % 8;
    int ks = rest / 8;
    int k = ks * 32 + ((lane >> 4) << 3) + j;
    int o16 = lane & 15;
    float v = (oc < 4) ? Wl[(oc * 16 + o16) * 128 + k] : Wr[((oc - 4) * 16 + o16) * 128 + k];
    wf[t] = f2bf(v);
}

// ======== fused: fp8 gather-mean (LDS) + MFMA transform + coalesced epilogue ========
// out = relu([mean_agg | feat] @ W + b); optional fp8 copy of out (q8out MUST differ from q8in)
template <bool WRITEQ>
__global__ __launch_bounds__(256) void k_fx(const unsigned char* q8in,
                                            const unsigned short* feat,
                                            const int* rowptr, const int* adj,
                                            const unsigned short* w2f, const float* bias,
                                            unsigned short* outp, unsigned char* q8out, int N) {
    __shared__ unsigned short st[64][136];  // 272B row stride: 16B-aligned, <=2-way banks
    const int t = threadIdx.x;
    const int bRow0 = blockIdx.x * 64;

    // ---- phase 1: gather-mean of fp8 rows into st (bf16) ----
    {
        const int grp = t >> 5;   // 0..7
        const int gl = t & 31;    // lane in 32-group
        const unsigned char* fb = q8in + gl * 4;
        for (int pass = 0; pass < 8; pass++) {
            int node = bRow0 + pass * 8 + grp;
            int lo = 0, hi = 0;
            if (node < N) { lo = rowptr[node]; hi = rowptr[node + 1]; }
            float a0 = 0.f, a1 = 0.f, a2 = 0.f, a3 = 0.f;
            int j = lo;
            for (; j + 8 <= hi; j += 8) {
                unsigned int v[8];
#pragma unroll
                for (int u = 0; u < 8; u++) {
                    int s = adj[j + u];
                    v[u] = *(const unsigned int*)(fb + (size_t)s * 128);
                }
#pragma unroll
                for (int u = 0; u < 8; u++) {
                    floatx2 l2 = fp8pk2f<false>(v[u]);
                    floatx2 h2 = fp8pk2f<true>(v[u]);
                    a0 += l2[0]; a1 += l2[1]; a2 += h2[0]; a3 += h2[1];
                }
            }
            if (j < hi) {  // masked tail chunk
                unsigned int v[8];
                float w[8];
#pragma unroll
                for (int u = 0; u < 8; u++) {
                    int jj = j + u;
                    int s = adj[jj < hi ? jj : hi - 1];
                    v[u] = *(const unsigned int*)(fb + (size_t)s * 128);
                    w[u] = (jj < hi) ? 1.0f : 0.0f;
                }
#pragma unroll
                for (int u = 0; u < 8; u++) {
                    floatx2 l2 = fp8pk2f<false>(v[u]);
                    floatx2 h2 = fp8pk2f<true>(v[u]);
                    a0 = fmaf(w[u], l2[0], a0);
                    a1 = fmaf(w[u], l2[1], a1);
                    a2 = fmaf(w[u], h2[0], a2);
                    a3 = fmaf(w[u], h2[1], a3);
                }
            }
            float inv = 1.0f / (float)max(hi - lo, 1);
            ushortx4 o;
            o[0] = f2bf(a0 * inv); o[1] = f2bf(a1 * inv);
            o[2] = f2bf(a2 * inv); o[3] = f2bf(a3 * inv);
            *(ushortx4*)&st[pass * 8 + grp][gl * 4] = o;  // zeros if node>=N
        }
    }
    __syncthreads();

    // ---- phase 2: MFMA ----
    const int wave = t >> 6;
    const int lane = t & 63;
    const int row = bRow0 + wave * 16 + (lane & 15);
    const int rloc = wave * 16 + (lane & 15);
    const int kq = lane >> 4;
    floatx4 acc[8];
#pragma unroll
    for (int i = 0; i < 8; i++) acc[i] = (floatx4)0.0f;
    const bool rowOK = row < N;
    const unsigned short* frow = feat + (size_t)row * 128;
    const short8* bbase = (const short8*)w2f;
#pragma unroll
    for (int ks = 0; ks < 8; ks++) {
        short8 a;
        if (ks < 4) {
            a = *(const short8*)&st[rloc][ks * 32 + kq * 8];  // aggr from LDS
        } else if (rowOK) {
            a = *(const short8*)(frow + (ks - 4) * 32 + kq * 8);
        } else {
            a = (short8)0;
        }
#pragma unroll
        for (int oc = 0; oc < 8; oc++) {
            short8 b = bbase[(ks * 8 + oc) * 64 + lane];
            acc[oc] = __builtin_amdgcn_mfma_f32_16x16x32_bf16(a, b, acc[oc], 0, 0, 0);
        }
    }
    __syncthreads();  // done reading gather data from st

    // ---- phase 3: stage output in st, coalesced stores ----
    const int rl = wave * 16 + kq * 4;
#pragma unroll
    for (int oc = 0; oc < 8; oc++) {
        int o = oc * 16 + (lane & 15);
        float bv = bias[o];
#pragma unroll
        for (int j = 0; j < 4; j++) {
            float v = fmaxf(acc[oc][j] + bv, 0.0f);
            st[rl + j][o] = f2bf(v);
        }
    }
    __syncthreads();
#pragma unroll
    for (int i = 0; i < 4; i++) {
        int c = t + i * 256;
        int r = c >> 4;
        int pos = (c & 15) * 8;
        int node = bRow0 + r;
        if (node < N) {
            short8 v = *(const short8*)&st[r][pos];
            *(short8*)(outp + (size_t)node * 128 + pos) = v;
        }
    }
    if (WRITEQ) {
#pragma unroll
        for (int i = 0; i < 2; i++) {
            int c = t + i * 256;
            int r = c >> 3;
            int pos = (c & 7) * 16;
            int node = bRow0 + r;
            if (node < N) {
                short8 v0 = *(const short8*)&st[r][pos];
                short8 v1 = *(const short8*)&st[r][pos + 8];
                unsigned int w[4];
#pragma unroll
                for (int q = 0; q < 2; q++) {
                    w[q] = (unsigned int)f2fp8(bf2f((unsigned short)v0[q * 4 + 0])) |
                           ((unsigned int)f2fp8(bf2f((unsigned short)v0[q * 4 + 1])) << 8) |
                           ((unsigned int)f2fp8(bf2f((unsigned short)v0[q * 4 + 2])) << 16) |
                           ((unsigned int)f2fp8(bf2f((unsigned short)v0[q * 4 + 3])) << 24);
                    w[q + 2] = (unsigned int)f2fp8(bf2f((unsigned short)v1[q * 4 + 0])) |
                               ((unsigned int)f2fp8(bf2f((unsigned short)v1[q * 4 + 1])) << 8) |
                               ((unsigned int)f2fp8(bf2f((unsigned short)v1[q * 4 + 2])) << 16) |
                               ((unsigned int)f2fp8(bf2f((unsigned short)v1[q * 4 + 3])) << 24);
                }
                uint4 u;
                u.x = w[0]; u.y = w[1]; u.z = w[2]; u.w = w[3];
                *(uint4*)(q8out + (size_t)node * 128 + pos) = u;
            }
        }
    }
}

// layer-2 split transform: t2 = h @ Wl2^T (bf16, LDS-staged), self = h @ Wr2^T + bl2 (f32)
__global__ __launch_bounds__(256) void k_xform2(const unsigned short* feat,
                                                const unsigned short* wf,
                                                const float* bias,
                                                unsigned short* t2, float* out, int N) {
    __shared__ unsigned short st[64][68];
    const int wave = threadIdx.x >> 6;
    const int lane = threadIdx.x & 63;
    const int nodeBase = blockIdx.x * 64 + wave * 16;
    const int row = nodeBase + (lane & 15);
    const int kq = lane >> 4;
    floatx4 acc[8];
#pragma unroll
    for (int i = 0; i < 8; i++) acc[i] = (floatx4)0.0f;
    const bool rowOK = row < N;
    const unsigned short* frow = feat + (size_t)row * 128;
    const short8* bbase = (const short8*)wf;
#pragma unroll
    for (int ks = 0; ks < 4; ks++) {
        short8 a;
        if (rowOK)
            a = *(const short8*)(frow + ks * 32 + kq * 8);
        else
            a = (short8)0;
#pragma unroll
        for (int oc = 0; oc < 8; oc++) {
            short8 b = bbase[(ks * 8 + oc) * 64 + lane];
            acc[oc] = __builtin_amdgcn_mfma_f32_16x16x32_bf16(a, b, acc[oc], 0, 0, 0);
        }
    }
    const int rl = wave * 16 + kq * 4;
    const int o16 = lane & 15;
#pragma unroll
    for (int oc = 0; oc < 8; oc++) {
#pragma unroll
        for (int j = 0; j < 4; j++) {
            int node = nodeBase + kq * 4 + j;
            if (oc < 4) {
                st[rl + j][oc * 16 + o16] = f2bf(acc[oc][j]);
            } else if (node < N) {
                int o = (oc - 4) * 16 + o16;
                out[(size_t)node * 64 + o] = acc[oc][j] + bias[o];
            }
        }
    }
    __syncthreads();
    const int bRow0 = blockIdx.x * 64;
    const int t = threadIdx.x;
#pragma unroll
    for (int i = 0; i < 2; i++) {
        int c = t + i * 256;
        int r = c >> 3;
        int pos = (c & 7) * 8;
        int node = bRow0 + r;
        if (node < N) {
            short8 v = *(const short8*)&st[r][pos];
            *(short8*)(t2 + (size_t)node * 64 + pos) = v;
        }
    }
}

// 64-wide bf16 mean aggregation of t2 + add self + fused log_softmax (16-lane group/node)
__global__ __launch_bounds__(256) void k_aggr64lsm(const unsigned short* t2, const int* rowptr,
                                                   const int* adj, float* out, int N) {
    int g = (blockIdx.x * blockDim.x + threadIdx.x) >> 4;
    int lane = threadIdx.x & 15;
    if (g >= N) return;
    int lo = rowptr[g], hi = rowptr[g + 1];
    float a0 = 0.f, a1 = 0.f, a2 = 0.f, a3 = 0.f;
    const unsigned short* fb = t2 + lane * 4;
    int j = lo;
    for (; j + 8 <= hi; j += 8) {
        ushortx4 v[8];
#pragma unroll
        for (int u = 0; u < 8; u++) {
            int s = adj[j + u];
            v[u] = *(const ushortx4*)(fb + (size_t)s * 64);
        }
#pragma unroll
        for (int u = 0; u < 8; u++) {
            a0 += bf2f(v[u][0]); a1 += bf2f(v[u][1]);
            a2 += bf2f(v[u][2]); a3 += bf2f(v[u][3]);
        }
    }
    if (j < hi) {
        ushortx4 v[8];
        float w[8];
#pragma unroll
        for (int u = 0; u < 8; u++) {
            int jj = j + u;
            int s = adj[jj < hi ? jj : hi - 1];
            v[u] = *(const ushortx4*)(fb + (size_t)s * 64);
            w[u] = (jj < hi) ? 1.0f : 0.0f;
        }
#pragma unroll
        for (int u = 0; u < 8; u++) {
            a0 = fmaf(w[u], bf2f(v[u][0]), a0);
            a1 = fmaf(w[u], bf2f(v[u][1]), a1);
            a2 = fmaf(w[u], bf2f(v[u][2]), a2);
            a3 = fmaf(w[u], bf2f(v[u][3]), a3);
        }
    }
    float inv = 1.0f / (float)max(hi - lo, 1);
    float* op = out + (size_t)g * 64 + lane * 4;
    float4 cur = *(float4*)op;
    float v0 = cur.x + a0 * inv, v1 = cur.y + a1 * inv;
    float v2 = cur.z + a2 * inv, v3 = cur.w + a3 * inv;
    // log_softmax across the 16-lane group (64 values)
    float m = fmaxf(fmaxf(v0, v1), fmaxf(v2, v3));
#pragma unroll
    for (int off = 8; off; off >>= 1) m = fmaxf(m, __shfl_xor(m, off));
    float s = expf(v0 - m) + expf(v1 - m) + expf(v2 - m) + expf(v3 - m);
#pragma unroll
    for (int off = 8; off; off >>= 1) s += __shfl_xor(s, off);
    float ls = m + logf(s);
    float4 o;
    o.x = v0 - ls; o.y = v1 - ls; o.z = v2 - ls; o.w = v3 - ls;
    *(float4*)op = o;
}

extern "C" void kernel_launch(void* const* d_in, const int* in_sizes, int n_in,
                              void* d_out, int out_size, void* d_ws, size_t ws_size,
                              hipStream_t stream) {
    const float* x = (const float*)d_in[0];
    const int* ei = (const int*)d_in[1];
    const float* Wl0 = (const float*)d_in[2];
    const float* bl0 = (const float*)d_in[3];
    const float* Wr0 = (const float*)d_in[4];
    const float* Wl1 = (const float*)d_in[5];
    const float* bl1 = (const float*)d_in[6];
    const float* Wr1 = (const float*)d_in[7];
    const float* Wl2 = (const float*)d_in[8];
    const float* bl2 = (const float*)d_in[9];
    const float* Wr2 = (const float*)d_in[10];

    const int N = in_sizes[0] / 128;
    const int E = in_sizes[1] / 2;
    const int* src = ei;
    const int* dst = ei + E;

    char* ws = (char*)d_ws;
    size_t off = 0;
    auto alloc = [&](size_t bytes) {
        void* p = ws + off;
        off += (bytes + 255) & ~(size_t)255;
        return p;
    };
    int* cntin = (int*)alloc((size_t)NB * B1 * 4);
    int* cntoff = (int*)alloc(((size_t)NB * B1 + 1) * 4);
    int* bsum = (int*)alloc(1024 * 4);
    unsigned int* ebuf = (unsigned int*)alloc((size_t)E * 4);
    int* rowptr = (int*)alloc((size_t)(N + 1) * 4);
    int* adj = (int*)alloc((size_t)E * 4);
    unsigned short* xb = (unsigned short*)alloc((size_t)N * 128 * 2);
    unsigned short* t2 = (unsigned short*)alloc((size_t)N * 128 * 2);
    unsigned short* hA = (unsigned short*)alloc((size_t)N * 128 * 2);
    unsigned short* hB = (unsigned short*)alloc((size_t)N * 128 * 2);
    unsigned char* q8a = (unsigned char*)alloc((size_t)N * 128);  // fp8(x)
    unsigned char* q8b = (unsigned char*)alloc((size_t)N * 128);  // fp8(h0) — separate: no RW race
    unsigned short* w0 = (unsigned short*)alloc(8 * 8 * 64 * 8 * 2);
    unsigned short* w1 = (unsigned short*)alloc(8 * 8 * 64 * 8 * 2);
    unsigned short* w2 = (unsigned short*)alloc(4 * 8 * 64 * 8 * 2);

    // ---- bucketed CSR build ----
    const int NBUCK = (N + 255) >> 8;
    k_bhist<<<B1, 256, 0, stream>>>(dst, E, cntin);
    const int scanLen = NB * B1;
    const int nScanBlocks = (scanLen + SCAN_CHUNK - 1) / SCAN_CHUNK;
    k_scan_part<<<nScanBlocks, SCAN_T, 0, stream>>>(cntin, bsum, scanLen);
    k_scan_top<<<1, 64, 0, stream>>>(bsum, nScanBlocks);
    k_scan_apply<<<nScanBlocks, SCAN_T, 0, stream>>>(cntin, bsum, cntoff, scanLen);
    k_bscatter<<<B1, 256, 0, stream>>>(src, dst, E, cntoff, ebuf);
    k_build<<<NBUCK, 256, 0, stream>>>(ebuf, cntoff, rowptr, adj, N, E);

    // conversions / weight prep
    k_cvt<<<((N * 128 / 4) + 255) / 256, 256, 0, stream>>>(x, xb, q8a, N * 128);
    k_prep_w<<<(32768 + 255) / 256, 256, 0, stream>>>(Wl0, Wr0, w0, 128);
    k_prep_w<<<(32768 + 255) / 256, 256, 0, stream>>>(Wl1, Wr1, w1, 128);
    k_prep_w2<<<(16384 + 255) / 256, 256, 0, stream>>>(Wl2, Wr2, w2);

    const int aggr64Grid = ((N * 16) + 255) / 256;
    const int xfGrid = (N + 63) / 64;

    // layer 0: fused gather(q8a) + xform -> hA bf16 + fp8(hA) in q8b
    k_fx<true><<<xfGrid, 256, 0, stream>>>(q8a, xb, rowptr, adj, w0, bl0, hA, q8b, N);
    // layer 1: fused gather(q8b) + xform -> hB
    k_fx<false><<<xfGrid, 256, 0, stream>>>(q8b, hA, rowptr, adj, w1, bl1, hB, nullptr, N);
    // layer 2: transform first (commutes with mean), then fused aggregate+log_softmax
    k_xform2<<<xfGrid, 256, 0, stream>>>(hB, w2, bl2, t2, (float*)d_out, N);
    k_aggr64lsm<<<aggr64Grid, 256, 0, stream>>>(t2, rowptr, adj, (float*)d_out, N);
}

// Round 10
// 263.933 us; speedup vs baseline: 2.8535x; 1.0433x over previous
//
#include <hip/hip_runtime.h>
#include <hip/hip_bf16.h>
#include <math.h>

typedef __attribute__((ext_vector_type(8))) short short8;
typedef __attribute__((ext_vector_type(4))) float floatx4;
typedef __attribute__((ext_vector_type(2))) float floatx2;
typedef __attribute__((ext_vector_type(4))) unsigned short ushortx4;

__device__ __forceinline__ float bf2f(unsigned short u) {
    union { unsigned int i; float f; } c; c.i = ((unsigned int)u) << 16; return c.f;
}
__device__ __forceinline__ unsigned short f2bf(float f) {
    union { float f; unsigned int i; } c; c.f = f;
    unsigned int x = c.i;
    return (unsigned short)((x + 0x7FFFu + ((x >> 16) & 1u)) >> 16);
}

// ---------- fp8 e4m3fn (OCP) encode/decode ----------
__device__ __forceinline__ unsigned char f2fp8(float f) {
    unsigned int u = __float_as_uint(f);
    unsigned int sign = (u >> 24) & 0x80u;
    unsigned int a = u & 0x7FFFFFFFu;
    if (a >= 0x43E00000u) return (unsigned char)(sign | 0x7Eu);  // saturate at 448
    if (a < 0x3C800000u) {  // below smallest normal 2^-6: denormal units of 2^-9
        int unit = (int)rintf(__uint_as_float(a) * 512.0f);
        return (unsigned char)(sign | (unsigned int)unit);
    }
    unsigned int r = a + 0x7FFFFu + ((a >> 20) & 1u);  // RNE at bit 20
    unsigned int e = (r >> 23) - 120u;
    unsigned int m = (r >> 20) & 7u;
    return (unsigned char)(sign | (e << 3) | m);
}

__device__ __forceinline__ float fp8dec1(unsigned int b) {
    unsigned int s = (b & 0x80u) << 24;
    unsigned int mag = (b & 0x7Fu) << 20;
    return __uint_as_float(s | mag) * __uint_as_float(0x7B800000u);  // * 2^120
}

template <bool W>
__device__ __forceinline__ floatx2 fp8pk2f(unsigned int v) {
#if defined(__has_builtin) && __has_builtin(__builtin_amdgcn_cvt_pk_f32_fp8)
    return __builtin_amdgcn_cvt_pk_f32_fp8(v, W);
#else
    floatx2 r;
    r[0] = fp8dec1((v >> (W ? 16 : 0)) & 0xFFu);
    r[1] = fp8dec1((v >> (W ? 24 : 8)) & 0xFFu);
    return r;
#endif
}

// ================= bucketed CSR build =================
constexpr int NB = 512;
constexpr int B1 = 256;

__global__ __launch_bounds__(256) void k_bhist(const int* dst, int E, int* cnt) {
    __shared__ int h[NB];
    int t = threadIdx.x, b = blockIdx.x;
    h[t] = 0; h[t + 256] = 0;
    __syncthreads();
    int chunk = (E + B1 - 1) / B1;
    int lo = b * chunk, hi = min(E, lo + chunk);
    for (int e = lo + t; e < hi; e += 256) atomicAdd(&h[dst[e] >> 8], 1);
    __syncthreads();
    cnt[(size_t)t * B1 + b] = h[t];
    cnt[(size_t)(t + 256) * B1 + b] = h[t + 256];
}

constexpr int SCAN_T = 256;
constexpr int SCAN_V = 8;
constexpr int SCAN_CHUNK = SCAN_T * SCAN_V;

__global__ void k_scan_part(const int* in, int* bsum, int N) {
    int b = blockIdx.x, t = threadIdx.x;
    int base = b * SCAN_CHUNK + t * SCAN_V;
    int s = 0;
#pragma unroll
    for (int j = 0; j < SCAN_V; j++) {
        int i = base + j;
        if (i < N) s += in[i];
    }
    __shared__ int wsums[SCAN_T / 64];
    for (int off = 32; off; off >>= 1) s += __shfl_down(s, off, 64);
    if ((t & 63) == 0) wsums[t >> 6] = s;
    __syncthreads();
    if (t == 0) {
        int tot = 0;
#pragma unroll
        for (int w = 0; w < SCAN_T / 64; w++) tot += wsums[w];
        bsum[b] = tot;
    }
}

__global__ void k_scan_top(int* bsum, int nb) {
    if (threadIdx.x == 0) {
        int run = 0;
        for (int i = 0; i < nb; i++) {
            int v = bsum[i];
            bsum[i] = run;
            run += v;
        }
    }
}

__global__ void k_scan_apply(const int* in, const int* bsum, int* out, int N) {
    int b = blockIdx.x, t = threadIdx.x;
    int base = b * SCAN_CHUNK + t * SCAN_V;
    int v[SCAN_V];
    int s = 0;
#pragma unroll
    for (int j = 0; j < SCAN_V; j++) {
        int i = base + j;
        v[j] = (i < N) ? in[i] : 0;
        s += v[j];
    }
    __shared__ int sums[SCAN_T];
    sums[t] = s;
    __syncthreads();
    for (int off = 1; off < SCAN_T; off <<= 1) {
        int x = (t >= off) ? sums[t - off] : 0;
        __syncthreads();
        sums[t] += x;
        __syncthreads();
    }
    int pre = bsum[b] + ((t == 0) ? 0 : sums[t - 1]);
#pragma unroll
    for (int j = 0; j < SCAN_V; j++) {
        int i = base + j;
        if (i < N) {
            out[i] = pre;
            pre += v[j];
            if (i == N - 1) out[N] = pre;
        }
    }
}

__global__ __launch_bounds__(256) void k_bscatter(const int* src, const int* dst, int E,
                                                  const int* cntoff, unsigned int* ebuf) {
    __shared__ int base[NB];
    __shared__ int lcur[NB];
    int t = threadIdx.x, b = blockIdx.x;
    for (int i = t; i < NB; i += 256) {
        base[i] = cntoff[(size_t)i * B1 + b];
        lcur[i] = 0;
    }
    __syncthreads();
    int chunk = (E + B1 - 1) / B1;
    int lo = b * chunk, hi = min(E, lo + chunk);
    for (int e = lo + t; e < hi; e += 256) {
        int d = dst[e];
        int cb = d >> 8;
        int slot = atomicAdd(&lcur[cb], 1);
        ebuf[base[cb] + slot] = (unsigned int)src[e] | ((unsigned int)(d & 255) << 17);
    }
}

__global__ __launch_bounds__(256) void k_build(const unsigned int* ebuf, const int* cntoff,
                                               int* rowptr, int* adj, int N, int E) {
    __shared__ int ldeg[256];
    __shared__ int lptr[256];
    __shared__ int lcur[256];
    __shared__ int tsum[256];
    int t = threadIdx.x, cb = blockIdx.x;
    int bbase = cntoff[(size_t)cb * B1];
    int bend = cntoff[(size_t)(cb + 1) * B1];
    ldeg[t] = 0;
    lcur[t] = 0;
    __syncthreads();
    for (int e = bbase + t; e < bend; e += 256) atomicAdd(&ldeg[ebuf[e] >> 17], 1);
    __syncthreads();
    tsum[t] = ldeg[t];
    __syncthreads();
    for (int off = 1; off < 256; off <<= 1) {
        int v = (t >= off) ? tsum[t - off] : 0;
        __syncthreads();
        tsum[t] += v;
        __syncthreads();
    }
    lptr[t] = tsum[t] - ldeg[t];
    __syncthreads();
    int node = cb * 256 + t;
    if (node < N) rowptr[node] = bbase + lptr[t];
    if (cb == 0 && t == 0) rowptr[N] = E;
    for (int e = bbase + t; e < bend; e += 256) {
        unsigned int pk = ebuf[e];
        int dl = pk >> 17;
        int ls = atomicAdd(&lcur[dl], 1);
        adj[bbase + lptr[dl] + ls] = (int)(pk & 0x1FFFF);
    }
}

// ---------------- dtype conversion (f32 -> bf16 + fp8) ----------------
__global__ void k_cvt(const float* x, unsigned short* xb, unsigned char* xq, int n) {
    int i = blockIdx.x * blockDim.x + threadIdx.x;
    int idx = i * 4;
    if (idx < n) {
        float4 v = *(const float4*)(x + idx);
        ushortx4 o;
        o[0] = f2bf(v.x); o[1] = f2bf(v.y); o[2] = f2bf(v.z); o[3] = f2bf(v.w);
        *(ushortx4*)(xb + idx) = o;
        unsigned int qw = (unsigned int)f2fp8(v.x) | ((unsigned int)f2fp8(v.y) << 8) |
                          ((unsigned int)f2fp8(v.z) << 16) | ((unsigned int)f2fp8(v.w) << 24);
        *(unsigned int*)(xq + idx) = qw;
    }
}

// arrange W = [Wl^T ; Wr^T] (256 x Do) into MFMA B-fragment order
__global__ void k_prep_w(const float* Wl, const float* Wr, unsigned short* w2f, int Do) {
    int t = blockIdx.x * blockDim.x + threadIdx.x;
    int NOC = Do >> 4;
    int total = 8 * NOC * 64 * 8;
    if (t >= total) return;
    int j = t & 7;
    int lane = (t >> 3) & 63;
    int rest = t >> 9;
    int oc = rest % NOC;
    int ks = rest / NOC;
    int k = ks * 32 + ((lane >> 4) << 3) + j;
    int o = oc * 16 + (lane & 15);
    float v = (k < 128) ? Wl[o * 128 + k] : Wr[o * 128 + (k - 128)];
    w2f[t] = f2bf(v);
}

__global__ void k_prep_w2(const float* Wl, const float* Wr, unsigned short* wf) {
    int t = blockIdx.x * blockDim.x + threadIdx.x;
    int total = 4 * 8 * 64 * 8;
    if (t >= total) return;
    int j = t & 7;
    int lane = (t >> 3) & 63;
    int rest = t >> 9;
    int oc = rest % 8;
    int ks = rest / 8;
    int k = ks * 32 + ((lane >> 4) << 3) + j;
    int o16 = lane & 15;
    float v = (oc < 4) ? Wl[(oc * 16 + o16) * 128 + k] : Wr[((oc - 4) * 16 + o16) * 128 + k];
    wf[t] = f2bf(v);
}

// ---------------- fp8 mean aggregation -> fp8 mean (32-lane group per node) ----------------
__global__ __launch_bounds__(256) void k_aggr8(const unsigned char* feat, const int* rowptr,
                                               const int* adj, unsigned char* aggr, int N) {
    int g = (blockIdx.x * blockDim.x + threadIdx.x) >> 5;
    int lane = threadIdx.x & 31;
    if (g >= N) return;
    int lo = rowptr[g], hi = rowptr[g + 1];
    float a0 = 0.f, a1 = 0.f, a2 = 0.f, a3 = 0.f;
    const unsigned char* fb = feat + lane * 4;
    int j = lo;
    for (; j + 8 <= hi; j += 8) {
        unsigned int v[8];
#pragma unroll
        for (int u = 0; u < 8; u++) {
            int s = adj[j + u];
            v[u] = *(const unsigned int*)(fb + (size_t)s * 128);
        }
#pragma unroll
        for (int u = 0; u < 8; u++) {
            floatx2 l2 = fp8pk2f<false>(v[u]);
            floatx2 h2 = fp8pk2f<true>(v[u]);
            a0 += l2[0]; a1 += l2[1]; a2 += h2[0]; a3 += h2[1];
        }
    }
    if (j < hi) {  // masked tail chunk: loads issued back-to-back
        unsigned int v[8];
        float w[8];
#pragma unroll
        for (int u = 0; u < 8; u++) {
            int jj = j + u;
            int s = adj[jj < hi ? jj : hi - 1];
            v[u] = *(const unsigned int*)(fb + (size_t)s * 128);
            w[u] = (jj < hi) ? 1.0f : 0.0f;
        }
#pragma unroll
        for (int u = 0; u < 8; u++) {
            floatx2 l2 = fp8pk2f<false>(v[u]);
            floatx2 h2 = fp8pk2f<true>(v[u]);
            a0 = fmaf(w[u], l2[0], a0);
            a1 = fmaf(w[u], l2[1], a1);
            a2 = fmaf(w[u], h2[0], a2);
            a3 = fmaf(w[u], h2[1], a3);
        }
    }
    float inv = 1.0f / (float)max(hi - lo, 1);
    unsigned int qw = (unsigned int)f2fp8(a0 * inv) | ((unsigned int)f2fp8(a1 * inv) << 8) |
                      ((unsigned int)f2fp8(a2 * inv) << 16) | ((unsigned int)f2fp8(a3 * inv) << 24);
    *(unsigned int*)(aggr + (size_t)g * 128 + lane * 4) = qw;
}

// ---------------- fused transform (DO=128, relu): out = [aggr|feat] @ W + b ----------------
// aggr input is fp8 (exact-decode to bf16); LDS-staged coalesced epilogue (+ derived fp8 out)
template <bool WRITEQ>
__global__ __launch_bounds__(256) void k_xform(const unsigned char* aggr,
                                               const unsigned short* feat,
                                               const unsigned short* w2f,
                                               const float* bias, unsigned short* outp,
                                               unsigned char* q8, int N) {
    __shared__ unsigned short st[64][132];
    const int wave = threadIdx.x >> 6;
    const int lane = threadIdx.x & 63;
    const int row = blockIdx.x * 64 + wave * 16 + (lane & 15);
    const int kq = lane >> 4;
    floatx4 acc[8];
#pragma unroll
    for (int i = 0; i < 8; i++) acc[i] = (floatx4)0.0f;
    const bool rowOK = row < N;
    const unsigned char* arow = aggr + (size_t)row * 128;
    const unsigned short* frow = feat + (size_t)row * 128;
    const short8* bbase = (const short8*)w2f;
#pragma unroll
    for (int ks = 0; ks < 8; ks++) {
        short8 a;
        if (!rowOK) {
            a = (short8)0;
        } else if (ks < 4) {
            uint2 q = *(const uint2*)(arow + ks * 32 + kq * 8);
            floatx2 p0 = fp8pk2f<false>(q.x), p1 = fp8pk2f<true>(q.x);
            floatx2 p2 = fp8pk2f<false>(q.y), p3 = fp8pk2f<true>(q.y);
            a[0] = (short)f2bf(p0[0]); a[1] = (short)f2bf(p0[1]);
            a[2] = (short)f2bf(p1[0]); a[3] = (short)f2bf(p1[1]);
            a[4] = (short)f2bf(p2[0]); a[5] = (short)f2bf(p2[1]);
            a[6] = (short)f2bf(p3[0]); a[7] = (short)f2bf(p3[1]);
        } else {
            a = *(const short8*)(frow + (ks - 4) * 32 + kq * 8);
        }
#pragma unroll
        for (int oc = 0; oc < 8; oc++) {
            short8 b = bbase[(ks * 8 + oc) * 64 + lane];
            acc[oc] = __builtin_amdgcn_mfma_f32_16x16x32_bf16(a, b, acc[oc], 0, 0, 0);
        }
    }
    // stage to LDS
    const int rl = wave * 16 + kq * 4;
#pragma unroll
    for (int oc = 0; oc < 8; oc++) {
        int o = oc * 16 + (lane & 15);
        float bv = bias[o];
#pragma unroll
        for (int j = 0; j < 4; j++) {
            float v = fmaxf(acc[oc][j] + bv, 0.0f);
            st[rl + j][o] = f2bf(v);
        }
    }
    __syncthreads();
    const int bRow0 = blockIdx.x * 64;
    const int t = threadIdx.x;
#pragma unroll
    for (int i = 0; i < 4; i++) {
        int c = t + i * 256;
        int r = c >> 4;
        int pos = (c & 15) * 8;
        int node = bRow0 + r;
        if (node < N) {
            short8 v = *(const short8*)&st[r][pos];
            *(short8*)(outp + (size_t)node * 128 + pos) = v;
        }
    }
    if (WRITEQ) {
#pragma unroll
        for (int i = 0; i < 2; i++) {
            int c = t + i * 256;
            int r = c >> 3;
            int pos = (c & 7) * 16;
            int node = bRow0 + r;
            if (node < N) {
                short8 v0 = *(const short8*)&st[r][pos];
                short8 v1 = *(const short8*)&st[r][pos + 8];
                unsigned int w[4];
#pragma unroll
                for (int q = 0; q < 2; q++) {
                    w[q] = (unsigned int)f2fp8(bf2f((unsigned short)v0[q * 4 + 0])) |
                           ((unsigned int)f2fp8(bf2f((unsigned short)v0[q * 4 + 1])) << 8) |
                           ((unsigned int)f2fp8(bf2f((unsigned short)v0[q * 4 + 2])) << 16) |
                           ((unsigned int)f2fp8(bf2f((unsigned short)v0[q * 4 + 3])) << 24);
                    w[q + 2] = (unsigned int)f2fp8(bf2f((unsigned short)v1[q * 4 + 0])) |
                               ((unsigned int)f2fp8(bf2f((unsigned short)v1[q * 4 + 1])) << 8) |
                               ((unsigned int)f2fp8(bf2f((unsigned short)v1[q * 4 + 2])) << 16) |
                               ((unsigned int)f2fp8(bf2f((unsigned short)v1[q * 4 + 3])) << 24);
                }
                uint4 u;
                u.x = w[0]; u.y = w[1]; u.z = w[2]; u.w = w[3];
                *(uint4*)(q8 + (size_t)node * 128 + pos) = u;
            }
        }
    }
}

// layer-2 split transform: t2 = h @ Wl2^T (bf16, LDS-staged), self = h @ Wr2^T + bl2 (f32)
__global__ __launch_bounds__(256) void k_xform2(const unsigned short* feat,
                                                const unsigned short* wf,
                                                const float* bias,
                                                unsigned short* t2, float* out, int N) {
    __shared__ unsigned short st[64][68];
    const int wave = threadIdx.x >> 6;
    const int lane = threadIdx.x & 63;
    const int nodeBase = blockIdx.x * 64 + wave * 16;
    const int row = nodeBase + (lane & 15);
    const int kq = lane >> 4;
    floatx4 acc[8];
#pragma unroll
    for (int i = 0; i < 8; i++) acc[i] = (floatx4)0.0f;
    const bool rowOK = row < N;
    const unsigned short* frow = feat + (size_t)row * 128;
    const short8* bbase = (const short8*)wf;
#pragma unroll
    for (int ks = 0; ks < 4; ks++) {
        short8 a;
        if (rowOK)
            a = *(const short8*)(frow + ks * 32 + kq * 8);
        else
            a = (short8)0;
#pragma unroll
        for (int oc = 0; oc < 8; oc++) {
            short8 b = bbase[(ks * 8 + oc) * 64 + lane];
            acc[oc] = __builtin_amdgcn_mfma_f32_16x16x32_bf16(a, b, acc[oc], 0, 0, 0);
        }
    }
    const int rl = wave * 16 + kq * 4;
    const int o16 = lane & 15;
#pragma unroll
    for (int oc = 0; oc < 8; oc++) {
#pragma unroll
        for (int j = 0; j < 4; j++) {
            int node = nodeBase + kq * 4 + j;
            if (oc < 4) {
                st[rl + j][oc * 16 + o16] = f2bf(acc[oc][j]);
            } else if (node < N) {
                int o = (oc - 4) * 16 + o16;
                out[(size_t)node * 64 + o] = acc[oc][j] + bias[o];
            }
        }
    }
    __syncthreads();
    const int bRow0 = blockIdx.x * 64;
    const int t = threadIdx.x;
#pragma unroll
    for (int i = 0; i < 2; i++) {
        int c = t + i * 256;
        int r = c >> 3;
        int pos = (c & 7) * 8;
        int node = bRow0 + r;
        if (node < N) {
            short8 v = *(const short8*)&st[r][pos];
            *(short8*)(t2 + (size_t)node * 64 + pos) = v;
        }
    }
}

// 64-wide bf16 mean aggregation of t2 + add self + fused log_softmax (16-lane group/node)
__global__ __launch_bounds__(256) void k_aggr64lsm(const unsigned short* t2, const int* rowptr,
                                                   const int* adj, float* out, int N) {
    int g = (blockIdx.x * blockDim.x + threadIdx.x) >> 4;
    int lane = threadIdx.x & 15;
    if (g >= N) return;
    int lo = rowptr[g], hi = rowptr[g + 1];
    float a0 = 0.f, a1 = 0.f, a2 = 0.f, a3 = 0.f;
    const unsigned short* fb = t2 + lane * 4;
    int j = lo;
    for (; j + 8 <= hi; j += 8) {
        ushortx4 v[8];
#pragma unroll
        for (int u = 0; u < 8; u++) {
            int s = adj[j + u];
            v[u] = *(const ushortx4*)(fb + (size_t)s * 64);
        }
#pragma unroll
        for (int u = 0; u < 8; u++) {
            a0 += bf2f(v[u][0]); a1 += bf2f(v[u][1]);
            a2 += bf2f(v[u][2]); a3 += bf2f(v[u][3]);
        }
    }
    if (j < hi) {
        ushortx4 v[8];
        float w[8];
#pragma unroll
        for (int u = 0; u < 8; u++) {
            int jj = j + u;
            int s = adj[jj < hi ? jj : hi - 1];
            v[u] = *(const ushortx4*)(fb + (size_t)s * 64);
            w[u] = (jj < hi) ? 1.0f : 0.0f;
        }
#pragma unroll
        for (int u = 0; u < 8; u++) {
            a0 = fmaf(w[u], bf2f(v[u][0]), a0);
            a1 = fmaf(w[u], bf2f(v[u][1]), a1);
            a2 = fmaf(w[u], bf2f(v[u][2]), a2);
            a3 = fmaf(w[u], bf2f(v[u][3]), a3);
        }
    }
    float inv = 1.0f / (float)max(hi - lo, 1);
    float* op = out + (size_t)g * 64 + lane * 4;
    float4 cur = *(float4*)op;
    float v0 = cur.x + a0 * inv, v1 = cur.y + a1 * inv;
    float v2 = cur.z + a2 * inv, v3 = cur.w + a3 * inv;
    float m = fmaxf(fmaxf(v0, v1), fmaxf(v2, v3));
#pragma unroll
    for (int off = 8; off; off >>= 1) m = fmaxf(m, __shfl_xor(m, off));
    float s = expf(v0 - m) + expf(v1 - m) + expf(v2 - m) + expf(v3 - m);
#pragma unroll
    for (int off = 8; off; off >>= 1) s += __shfl_xor(s, off);
    float ls = m + logf(s);
    float4 o;
    o.x = v0 - ls; o.y = v1 - ls; o.z = v2 - ls; o.w = v3 - ls;
    *(float4*)op = o;
}

extern "C" void kernel_launch(void* const* d_in, const int* in_sizes, int n_in,
                              void* d_out, int out_size, void* d_ws, size_t ws_size,
                              hipStream_t stream) {
    const float* x = (const float*)d_in[0];
    const int* ei = (const int*)d_in[1];
    const float* Wl0 = (const float*)d_in[2];
    const float* bl0 = (const float*)d_in[3];
    const float* Wr0 = (const float*)d_in[4];
    const float* Wl1 = (const float*)d_in[5];
    const float* bl1 = (const float*)d_in[6];
    const float* Wr1 = (const float*)d_in[7];
    const float* Wl2 = (const float*)d_in[8];
    const float* bl2 = (const float*)d_in[9];
    const float* Wr2 = (const float*)d_in[10];

    const int N = in_sizes[0] / 128;
    const int E = in_sizes[1] / 2;
    const int* src = ei;
    const int* dst = ei + E;

    char* ws = (char*)d_ws;
    size_t off = 0;
    auto alloc = [&](size_t bytes) {
        void* p = ws + off;
        off += (bytes + 255) & ~(size_t)255;
        return p;
    };
    int* cntin = (int*)alloc((size_t)NB * B1 * 4);
    int* cntoff = (int*)alloc(((size_t)NB * B1 + 1) * 4);
    int* bsum = (int*)alloc(1024 * 4);
    unsigned int* ebuf = (unsigned int*)alloc((size_t)E * 4);
    int* rowptr = (int*)alloc((size_t)(N + 1) * 4);
    int* adj = (int*)alloc((size_t)E * 4);
    unsigned short* xb = (unsigned short*)alloc((size_t)N * 128 * 2);
    unsigned char* abuf = (unsigned char*)alloc((size_t)N * 128);  // fp8 aggr; reused as bf16 t2
    unsigned short* hA = (unsigned short*)alloc((size_t)N * 128 * 2);
    unsigned short* hB = (unsigned short*)alloc((size_t)N * 128 * 2);
    unsigned char* q8a = (unsigned char*)alloc((size_t)N * 128);  // fp8(x)
    unsigned char* q8b = (unsigned char*)alloc((size_t)N * 128);  // fp8(h0)
    unsigned short* w0 = (unsigned short*)alloc(8 * 8 * 64 * 8 * 2);
    unsigned short* w1 = (unsigned short*)alloc(8 * 8 * 64 * 8 * 2);
    unsigned short* w2 = (unsigned short*)alloc(4 * 8 * 64 * 8 * 2);

    // ---- bucketed CSR build ----
    const int NBUCK = (N + 255) >> 8;
    k_bhist<<<B1, 256, 0, stream>>>(dst, E, cntin);
    const int scanLen = NB * B1;
    const int nScanBlocks = (scanLen + SCAN_CHUNK - 1) / SCAN_CHUNK;
    k_scan_part<<<nScanBlocks, SCAN_T, 0, stream>>>(cntin, bsum, scanLen);
    k_scan_top<<<1, 64, 0, stream>>>(bsum, nScanBlocks);
    k_scan_apply<<<nScanBlocks, SCAN_T, 0, stream>>>(cntin, bsum, cntoff, scanLen);
    k_bscatter<<<B1, 256, 0, stream>>>(src, dst, E, cntoff, ebuf);
    k_build<<<NBUCK, 256, 0, stream>>>(ebuf, cntoff, rowptr, adj, N, E);

    // conversions / weight prep
    k_cvt<<<((N * 128 / 4) + 255) / 256, 256, 0, stream>>>(x, xb, q8a, N * 128);
    k_prep_w<<<(32768 + 255) / 256, 256, 0, stream>>>(Wl0, Wr0, w0, 128);
    k_prep_w<<<(32768 + 255) / 256, 256, 0, stream>>>(Wl1, Wr1, w1, 128);
    k_prep_w2<<<(16384 + 255) / 256, 256, 0, stream>>>(Wl2, Wr2, w2);

    const int aggrGrid = ((N * 32) + 255) / 256;
    const int aggr64Grid = ((N * 16) + 255) / 256;
    const int xfGrid = (N + 63) / 64;

    unsigned char* aggr = abuf;
    unsigned short* t2 = (unsigned short*)abuf;

    // layer 0: gather fp8(x) -> fp8 mean; xform -> hA bf16 + fp8(hA) in q8b
    k_aggr8<<<aggrGrid, 256, 0, stream>>>(q8a, rowptr, adj, aggr, N);
    k_xform<true><<<xfGrid, 256, 0, stream>>>(aggr, xb, w0, bl0, hA, q8b, N);
    // layer 1: gather fp8(hA) -> fp8 mean; xform -> hB
    k_aggr8<<<aggrGrid, 256, 0, stream>>>(q8b, rowptr, adj, aggr, N);
    k_xform<false><<<xfGrid, 256, 0, stream>>>(aggr, hA, w1, bl1, hB, nullptr, N);
    // layer 2: transform first (commutes with mean), then fused aggregate + log_softmax
    k_xform2<<<xfGrid, 256, 0, stream>>>(hB, w2, bl2, t2, (float*)d_out, N);
    k_aggr64lsm<<<aggr64Grid, 256, 0, stream>>>(t2, rowptr, adj, (float*)d_out, N);
}

// Round 11
// 253.269 us; speedup vs baseline: 2.9737x; 1.0421x over previous
//
#include <hip/hip_runtime.h>
#include <hip/hip_bf16.h>
#include <math.h>

typedef __attribute__((ext_vector_type(8))) short short8;
typedef __attribute__((ext_vector_type(4))) float floatx4;
typedef __attribute__((ext_vector_type(2))) float floatx2;
typedef __attribute__((ext_vector_type(4))) unsigned short ushortx4;

__device__ __forceinline__ float bf2f(unsigned short u) {
    union { unsigned int i; float f; } c; c.i = ((unsigned int)u) << 16; return c.f;
}
__device__ __forceinline__ unsigned short f2bf(float f) {
    union { float f; unsigned int i; } c; c.f = f;
    unsigned int x = c.i;
    return (unsigned short)((x + 0x7FFFu + ((x >> 16) & 1u)) >> 16);
}

// ---------- fp8 e4m3fn (OCP) encode/decode ----------
__device__ __forceinline__ unsigned char f2fp8(float f) {
    unsigned int u = __float_as_uint(f);
    unsigned int sign = (u >> 24) & 0x80u;
    unsigned int a = u & 0x7FFFFFFFu;
    if (a >= 0x43E00000u) return (unsigned char)(sign | 0x7Eu);  // saturate at 448
    if (a < 0x3C800000u) {  // below smallest normal 2^-6: denormal units of 2^-9
        int unit = (int)rintf(__uint_as_float(a) * 512.0f);
        return (unsigned char)(sign | (unsigned int)unit);
    }
    unsigned int r = a + 0x7FFFFu + ((a >> 20) & 1u);  // RNE at bit 20
    unsigned int e = (r >> 23) - 120u;
    unsigned int m = (r >> 20) & 7u;
    return (unsigned char)(sign | (e << 3) | m);
}

__device__ __forceinline__ float fp8dec1(unsigned int b) {
    unsigned int s = (b & 0x80u) << 24;
    unsigned int mag = (b & 0x7Fu) << 20;
    return __uint_as_float(s | mag) * __uint_as_float(0x7B800000u);  // * 2^120
}

template <bool W>
__device__ __forceinline__ floatx2 fp8pk2f(unsigned int v) {
#if defined(__has_builtin) && __has_builtin(__builtin_amdgcn_cvt_pk_f32_fp8)
    return __builtin_amdgcn_cvt_pk_f32_fp8(v, W);
#else
    floatx2 r;
    r[0] = fp8dec1((v >> (W ? 16 : 0)) & 0xFFu);
    r[1] = fp8dec1((v >> (W ? 24 : 8)) & 0xFFu);
    return r;
#endif
}

// ================= bucketed CSR build =================
constexpr int NB = 512;
constexpr int B1 = 256;

__global__ __launch_bounds__(256) void k_bhist(const int* dst, int E, int* cnt) {
    __shared__ int h[NB];
    int t = threadIdx.x, b = blockIdx.x;
    h[t] = 0; h[t + 256] = 0;
    __syncthreads();
    int chunk = (E + B1 - 1) / B1;
    int lo = b * chunk, hi = min(E, lo + chunk);
    for (int e = lo + t; e < hi; e += 256) atomicAdd(&h[dst[e] >> 8], 1);
    __syncthreads();
    cnt[(size_t)t * B1 + b] = h[t];
    cnt[(size_t)(t + 256) * B1 + b] = h[t + 256];
}

constexpr int SCAN_T = 256;
constexpr int SCAN_V = 8;
constexpr int SCAN_CHUNK = SCAN_T * SCAN_V;

__global__ void k_scan_part(const int* in, int* bsum, int N) {
    int b = blockIdx.x, t = threadIdx.x;
    int base = b * SCAN_CHUNK + t * SCAN_V;
    int s = 0;
#pragma unroll
    for (int j = 0; j < SCAN_V; j++) {
        int i = base + j;
        if (i < N) s += in[i];
    }
    __shared__ int wsums[SCAN_T / 64];
    for (int off = 32; off; off >>= 1) s += __shfl_down(s, off, 64);
    if ((t & 63) == 0) wsums[t >> 6] = s;
    __syncthreads();
    if (t == 0) {
        int tot = 0;
#pragma unroll
        for (int w = 0; w < SCAN_T / 64; w++) tot += wsums[w];
        bsum[b] = tot;
    }
}

__global__ void k_scan_top(int* bsum, int nb) {
    if (threadIdx.x == 0) {
        int run = 0;
        for (int i = 0; i < nb; i++) {
            int v = bsum[i];
            bsum[i] = run;
            run += v;
        }
    }
}

__global__ void k_scan_apply(const int* in, const int* bsum, int* out, int N) {
    int b = blockIdx.x, t = threadIdx.x;
    int base = b * SCAN_CHUNK + t * SCAN_V;
    int v[SCAN_V];
    int s = 0;
#pragma unroll
    for (int j = 0; j < SCAN_V; j++) {
        int i = base + j;
        v[j] = (i < N) ? in[i] : 0;
        s += v[j];
    }
    __shared__ int sums[SCAN_T];
    sums[t] = s;
    __syncthreads();
    for (int off = 1; off < SCAN_T; off <<= 1) {
        int x = (t >= off) ? sums[t - off] : 0;
        __syncthreads();
        sums[t] += x;
        __syncthreads();
    }
    int pre = bsum[b] + ((t == 0) ? 0 : sums[t - 1]);
#pragma unroll
    for (int j = 0; j < SCAN_V; j++) {
        int i = base + j;
        if (i < N) {
            out[i] = pre;
            pre += v[j];
            if (i == N - 1) out[N] = pre;
        }
    }
}

__global__ __launch_bounds__(256) void k_bscatter(const int* src, const int* dst, int E,
                                                  const int* cntoff, unsigned int* ebuf) {
    __shared__ int base[NB];
    __shared__ int lcur[NB];
    int t = threadIdx.x, b = blockIdx.x;
    for (int i = t; i < NB; i += 256) {
        base[i] = cntoff[(size_t)i * B1 + b];
        lcur[i] = 0;
    }
    __syncthreads();
    int chunk = (E + B1 - 1) / B1;
    int lo = b * chunk, hi = min(E, lo + chunk);
    for (int e = lo + t; e < hi; e += 256) {
        int d = dst[e];
        int cb = d >> 8;
        int slot = atomicAdd(&lcur[cb], 1);
        ebuf[base[cb] + slot] = (unsigned int)src[e] | ((unsigned int)(d & 255) << 17);
    }
}

__global__ __launch_bounds__(256) void k_build(const unsigned int* ebuf, const int* cntoff,
                                               int* rowptr, int* adj, int N, int E) {
    __shared__ int ldeg[256];
    __shared__ int lptr[256];
    __shared__ int lcur[256];
    __shared__ int tsum[256];
    int t = threadIdx.x, cb = blockIdx.x;
    int bbase = cntoff[(size_t)cb * B1];
    int bend = cntoff[(size_t)(cb + 1) * B1];
    ldeg[t] = 0;
    lcur[t] = 0;
    __syncthreads();
    for (int e = bbase + t; e < bend; e += 256) atomicAdd(&ldeg[ebuf[e] >> 17], 1);
    __syncthreads();
    tsum[t] = ldeg[t];
    __syncthreads();
    for (int off = 1; off < 256; off <<= 1) {
        int v = (t >= off) ? tsum[t - off] : 0;
        __syncthreads();
        tsum[t] += v;
        __syncthreads();
    }
    lptr[t] = tsum[t] - ldeg[t];
    __syncthreads();
    int node = cb * 256 + t;
    if (node < N) rowptr[node] = bbase + lptr[t];
    if (cb == 0 && t == 0) rowptr[N] = E;
    for (int e = bbase + t; e < bend; e += 256) {
        unsigned int pk = ebuf[e];
        int dl = pk >> 17;
        int ls = atomicAdd(&lcur[dl], 1);
        adj[bbase + lptr[dl] + ls] = (int)(pk & 0x1FFFF);
    }
}

// ---------------- combined prep: x->bf16+fp8 conversion AND 3x weight prep ----------------
__device__ __forceinline__ void prep_w_body(const float* Wl, const float* Wr,
                                            unsigned short* wf, int NOC, int t) {
    int total = 8 * NOC * 64 * 8;
    if (t >= total) return;
    int j = t & 7;
    int lane = (t >> 3) & 63;
    int rest = t >> 9;
    int oc = rest % NOC;
    int ks = rest / NOC;
    int k = ks * 32 + ((lane >> 4) << 3) + j;
    int o = oc * 16 + (lane & 15);
    float v = (k < 128) ? Wl[o * 128 + k] : Wr[o * 128 + (k - 128)];
    wf[t] = f2bf(v);
}

// layer-2 weights: K=128, 8 out blocks (0..3 = Wl2 -> t2, 4..7 = Wr2 -> self)
__device__ __forceinline__ void prep_w2_body(const float* Wl, const float* Wr,
                                             unsigned short* wf, int t) {
    int total = 4 * 8 * 64 * 8;
    if (t >= total) return;
    int j = t & 7;
    int lane = (t >> 3) & 63;
    int rest = t >> 9;
    int oc = rest % 8;
    int ks = rest / 8;
    int k = ks * 32 + ((lane >> 4) << 3) + j;
    int o16 = lane & 15;
    float v = (oc < 4) ? Wl[(oc * 16 + o16) * 128 + k] : Wr[((oc - 4) * 16 + o16) * 128 + k];
    wf[t] = f2bf(v);
}

__global__ __launch_bounds__(256) void k_prep(const float* x, unsigned short* xb,
                                              unsigned char* xq, int n4,
                                              const float* Wl0, const float* Wr0, unsigned short* w0,
                                              const float* Wl1, const float* Wr1, unsigned short* w1,
                                              const float* Wl2, const float* Wr2, unsigned short* w2,
                                              int cvtBlocks) {
    int b = blockIdx.x;
    if (b < cvtBlocks) {
        int i = b * 256 + threadIdx.x;
        int idx = i * 4;
        if (idx < n4 * 4) {
            float4 v = *(const float4*)(x + idx);
            ushortx4 o;
            o[0] = f2bf(v.x); o[1] = f2bf(v.y); o[2] = f2bf(v.z); o[3] = f2bf(v.w);
            *(ushortx4*)(xb + idx) = o;
            unsigned int qw = (unsigned int)f2fp8(v.x) | ((unsigned int)f2fp8(v.y) << 8) |
                              ((unsigned int)f2fp8(v.z) << 16) | ((unsigned int)f2fp8(v.w) << 24);
            *(unsigned int*)(xq + idx) = qw;
        }
    } else if (b < cvtBlocks + 128) {
        prep_w_body(Wl0, Wr0, w0, 8, (b - cvtBlocks) * 256 + threadIdx.x);
    } else if (b < cvtBlocks + 256) {
        prep_w_body(Wl1, Wr1, w1, 8, (b - cvtBlocks - 128) * 256 + threadIdx.x);
    } else {
        prep_w2_body(Wl2, Wr2, w2, (b - cvtBlocks - 256) * 256 + threadIdx.x);
    }
}

// ---------------- fp8 mean aggregation -> fp8 mean (32-lane group per node) ----------------
__global__ __launch_bounds__(256) void k_aggr8(const unsigned char* feat, const int* rowptr,
                                               const int* adj, unsigned char* aggr, int N) {
    int g = (blockIdx.x * blockDim.x + threadIdx.x) >> 5;
    int lane = threadIdx.x & 31;
    if (g >= N) return;
    int lo = rowptr[g], hi = rowptr[g + 1];
    float a0 = 0.f, a1 = 0.f, a2 = 0.f, a3 = 0.f;
    const unsigned char* fb = feat + lane * 4;
    int j = lo;
    for (; j + 8 <= hi; j += 8) {
        unsigned int v[8];
#pragma unroll
        for (int u = 0; u < 8; u++) {
            int s = adj[j + u];
            v[u] = *(const unsigned int*)(fb + (size_t)s * 128);
        }
#pragma unroll
        for (int u = 0; u < 8; u++) {
            floatx2 l2 = fp8pk2f<false>(v[u]);
            floatx2 h2 = fp8pk2f<true>(v[u]);
            a0 += l2[0]; a1 += l2[1]; a2 += h2[0]; a3 += h2[1];
        }
    }
    if (j < hi) {  // masked tail chunk: loads issued back-to-back
        unsigned int v[8];
        float w[8];
#pragma unroll
        for (int u = 0; u < 8; u++) {
            int jj = j + u;
            int s = adj[jj < hi ? jj : hi - 1];
            v[u] = *(const unsigned int*)(fb + (size_t)s * 128);
            w[u] = (jj < hi) ? 1.0f : 0.0f;
        }
#pragma unroll
        for (int u = 0; u < 8; u++) {
            floatx2 l2 = fp8pk2f<false>(v[u]);
            floatx2 h2 = fp8pk2f<true>(v[u]);
            a0 = fmaf(w[u], l2[0], a0);
            a1 = fmaf(w[u], l2[1], a1);
            a2 = fmaf(w[u], h2[0], a2);
            a3 = fmaf(w[u], h2[1], a3);
        }
    }
    float inv = 1.0f / (float)max(hi - lo, 1);
    unsigned int qw = (unsigned int)f2fp8(a0 * inv) | ((unsigned int)f2fp8(a1 * inv) << 8) |
                      ((unsigned int)f2fp8(a2 * inv) << 16) | ((unsigned int)f2fp8(a3 * inv) << 24);
    *(unsigned int*)(aggr + (size_t)g * 128 + lane * 4) = qw;
}

// ---------------- fused transform (DO=128, relu): out = [aggr|feat] @ W + b ----------------
template <bool WRITEQ>
__global__ __launch_bounds__(256) void k_xform(const unsigned char* aggr,
                                               const unsigned short* feat,
                                               const unsigned short* w2f,
                                               const float* bias, unsigned short* outp,
                                               unsigned char* q8, int N) {
    __shared__ unsigned short st[64][132];
    const int wave = threadIdx.x >> 6;
    const int lane = threadIdx.x & 63;
    const int row = blockIdx.x * 64 + wave * 16 + (lane & 15);
    const int kq = lane >> 4;
    floatx4 acc[8];
#pragma unroll
    for (int i = 0; i < 8; i++) acc[i] = (floatx4)0.0f;
    const bool rowOK = row < N;
    const unsigned char* arow = aggr + (size_t)row * 128;
    const unsigned short* frow = feat + (size_t)row * 128;
    const short8* bbase = (const short8*)w2f;
#pragma unroll
    for (int ks = 0; ks < 8; ks++) {
        short8 a;
        if (!rowOK) {
            a = (short8)0;
        } else if (ks < 4) {
            uint2 q = *(const uint2*)(arow + ks * 32 + kq * 8);
            floatx2 p0 = fp8pk2f<false>(q.x), p1 = fp8pk2f<true>(q.x);
            floatx2 p2 = fp8pk2f<false>(q.y), p3 = fp8pk2f<true>(q.y);
            a[0] = (short)f2bf(p0[0]); a[1] = (short)f2bf(p0[1]);
            a[2] = (short)f2bf(p1[0]); a[3] = (short)f2bf(p1[1]);
            a[4] = (short)f2bf(p2[0]); a[5] = (short)f2bf(p2[1]);
            a[6] = (short)f2bf(p3[0]); a[7] = (short)f2bf(p3[1]);
        } else {
            a = *(const short8*)(frow + (ks - 4) * 32 + kq * 8);
        }
#pragma unroll
        for (int oc = 0; oc < 8; oc++) {
            short8 b = bbase[(ks * 8 + oc) * 64 + lane];
            acc[oc] = __builtin_amdgcn_mfma_f32_16x16x32_bf16(a, b, acc[oc], 0, 0, 0);
        }
    }
    const int rl = wave * 16 + kq * 4;
#pragma unroll
    for (int oc = 0; oc < 8; oc++) {
        int o = oc * 16 + (lane & 15);
        float bv = bias[o];
#pragma unroll
        for (int j = 0; j < 4; j++) {
            float v = fmaxf(acc[oc][j] + bv, 0.0f);
            st[rl + j][o] = f2bf(v);
        }
    }
    __syncthreads();
    const int bRow0 = blockIdx.x * 64;
    const int t = threadIdx.x;
#pragma unroll
    for (int i = 0; i < 4; i++) {
        int c = t + i * 256;
        int r = c >> 4;
        int pos = (c & 15) * 8;
        int node = bRow0 + r;
        if (node < N) {
            short8 v = *(const short8*)&st[r][pos];
            *(short8*)(outp + (size_t)node * 128 + pos) = v;
        }
    }
    if (WRITEQ) {
#pragma unroll
        for (int i = 0; i < 2; i++) {
            int c = t + i * 256;
            int r = c >> 3;
            int pos = (c & 7) * 16;
            int node = bRow0 + r;
            if (node < N) {
                short8 v0 = *(const short8*)&st[r][pos];
                short8 v1 = *(const short8*)&st[r][pos + 8];
                unsigned int w[4];
#pragma unroll
                for (int q = 0; q < 2; q++) {
                    w[q] = (unsigned int)f2fp8(bf2f((unsigned short)v0[q * 4 + 0])) |
                           ((unsigned int)f2fp8(bf2f((unsigned short)v0[q * 4 + 1])) << 8) |
                           ((unsigned int)f2fp8(bf2f((unsigned short)v0[q * 4 + 2])) << 16) |
                           ((unsigned int)f2fp8(bf2f((unsigned short)v0[q * 4 + 3])) << 24);
                    w[q + 2] = (unsigned int)f2fp8(bf2f((unsigned short)v1[q * 4 + 0])) |
                               ((unsigned int)f2fp8(bf2f((unsigned short)v1[q * 4 + 1])) << 8) |
                               ((unsigned int)f2fp8(bf2f((unsigned short)v1[q * 4 + 2])) << 16) |
                               ((unsigned int)f2fp8(bf2f((unsigned short)v1[q * 4 + 3])) << 24);
                }
                uint4 u;
                u.x = w[0]; u.y = w[1]; u.z = w[2]; u.w = w[3];
                *(uint4*)(q8 + (size_t)node * 128 + pos) = u;
            }
        }
    }
}

// layer-2 split transform: t2 = h @ Wl2^T (fp8, LDS-staged), self = h @ Wr2^T + bl2 (f32)
__global__ __launch_bounds__(256) void k_xform2(const unsigned short* feat,
                                                const unsigned short* wf,
                                                const float* bias,
                                                unsigned char* t2q, float* out, int N) {
    __shared__ unsigned short st[64][68];
    const int wave = threadIdx.x >> 6;
    const int lane = threadIdx.x & 63;
    const int nodeBase = blockIdx.x * 64 + wave * 16;
    const int row = nodeBase + (lane & 15);
    const int kq = lane >> 4;
    floatx4 acc[8];
#pragma unroll
    for (int i = 0; i < 8; i++) acc[i] = (floatx4)0.0f;
    const bool rowOK = row < N;
    const unsigned short* frow = feat + (size_t)row * 128;
    const short8* bbase = (const short8*)wf;
#pragma unroll
    for (int ks = 0; ks < 4; ks++) {
        short8 a;
        if (rowOK)
            a = *(const short8*)(frow + ks * 32 + kq * 8);
        else
            a = (short8)0;
#pragma unroll
        for (int oc = 0; oc < 8; oc++) {
            short8 b = bbase[(ks * 8 + oc) * 64 + lane];
            acc[oc] = __builtin_amdgcn_mfma_f32_16x16x32_bf16(a, b, acc[oc], 0, 0, 0);
        }
    }
    const int rl = wave * 16 + kq * 4;
    const int o16 = lane & 15;
#pragma unroll
    for (int oc = 0; oc < 8; oc++) {
#pragma unroll
        for (int j = 0; j < 4; j++) {
            int node = nodeBase + kq * 4 + j;
            if (oc < 4) {
                st[rl + j][oc * 16 + o16] = f2bf(acc[oc][j]);
            } else if (node < N) {
                int o = (oc - 4) * 16 + o16;
                out[(size_t)node * 64 + o] = acc[oc][j] + bias[o];
            }
        }
    }
    __syncthreads();
    // coalesced fp8 t2 stores: 256 chunks of 16 B (64 rows x 64 B)
    const int bRow0 = blockIdx.x * 64;
    const int t = threadIdx.x;
    {
        int r = t >> 2;
        int pos = (t & 3) * 16;
        int node = bRow0 + r;
        if (node < N) {
            short8 v0 = *(const short8*)&st[r][pos];
            short8 v1 = *(const short8*)&st[r][pos + 8];
            unsigned int w[4];
#pragma unroll
            for (int q = 0; q < 2; q++) {
                w[q] = (unsigned int)f2fp8(bf2f((unsigned short)v0[q * 4 + 0])) |
                       ((unsigned int)f2fp8(bf2f((unsigned short)v0[q * 4 + 1])) << 8) |
                       ((unsigned int)f2fp8(bf2f((unsigned short)v0[q * 4 + 2])) << 16) |
                       ((unsigned int)f2fp8(bf2f((unsigned short)v0[q * 4 + 3])) << 24);
                w[q + 2] = (unsigned int)f2fp8(bf2f((unsigned short)v1[q * 4 + 0])) |
                           ((unsigned int)f2fp8(bf2f((unsigned short)v1[q * 4 + 1])) << 8) |
                           ((unsigned int)f2fp8(bf2f((unsigned short)v1[q * 4 + 2])) << 16) |
                           ((unsigned int)f2fp8(bf2f((unsigned short)v1[q * 4 + 3])) << 24);
            }
            uint4 u;
            u.x = w[0]; u.y = w[1]; u.z = w[2]; u.w = w[3];
            *(uint4*)(t2q + (size_t)node * 64 + pos) = u;
        }
    }
}

// 64-wide fp8 mean aggregation of t2 + add self + fused log_softmax (16-lane group/node)
__global__ __launch_bounds__(256) void k_aggr64lsm(const unsigned char* t2q, const int* rowptr,
                                                   const int* adj, float* out, int N) {
    int g = (blockIdx.x * blockDim.x + threadIdx.x) >> 4;
    int lane = threadIdx.x & 15;
    if (g >= N) return;
    int lo = rowptr[g], hi = rowptr[g + 1];
    float a0 = 0.f, a1 = 0.f, a2 = 0.f, a3 = 0.f;
    const unsigned char* fb = t2q + lane * 4;
    int j = lo;
    for (; j + 8 <= hi; j += 8) {
        unsigned int v[8];
#pragma unroll
        for (int u = 0; u < 8; u++) {
            int s = adj[j + u];
            v[u] = *(const unsigned int*)(fb + (size_t)s * 64);
        }
#pragma unroll
        for (int u = 0; u < 8; u++) {
            floatx2 l2 = fp8pk2f<false>(v[u]);
            floatx2 h2 = fp8pk2f<true>(v[u]);
            a0 += l2[0]; a1 += l2[1]; a2 += h2[0]; a3 += h2[1];
        }
    }
    if (j < hi) {
        unsigned int v[8];
        float w[8];
#pragma unroll
        for (int u = 0; u < 8; u++) {
            int jj = j + u;
            int s = adj[jj < hi ? jj : hi - 1];
            v[u] = *(const unsigned int*)(fb + (size_t)s * 64);
            w[u] = (jj < hi) ? 1.0f : 0.0f;
        }
#pragma unroll
        for (int u = 0; u < 8; u++) {
            floatx2 l2 = fp8pk2f<false>(v[u]);
            floatx2 h2 = fp8pk2f<true>(v[u]);
            a0 = fmaf(w[u], l2[0], a0);
            a1 = fmaf(w[u], l2[1], a1);
            a2 = fmaf(w[u], h2[0], a2);
            a3 = fmaf(w[u], h2[1], a3);
        }
    }
    float inv = 1.0f / (float)max(hi - lo, 1);
    float* op = out + (size_t)g * 64 + lane * 4;
    float4 cur = *(float4*)op;
    float v0 = cur.x + a0 * inv, v1 = cur.y + a1 * inv;
    float v2 = cur.z + a2 * inv, v3 = cur.w + a3 * inv;
    float m = fmaxf(fmaxf(v0, v1), fmaxf(v2, v3));
#pragma unroll
    for (int off = 8; off; off >>= 1) m = fmaxf(m, __shfl_xor(m, off));
    float s = expf(v0 - m) + expf(v1 - m) + expf(v2 - m) + expf(v3 - m);
#pragma unroll
    for (int off = 8; off; off >>= 1) s += __shfl_xor(s, off);
    float ls = m + logf(s);
    float4 o;
    o.x = v0 - ls; o.y = v1 - ls; o.z = v2 - ls; o.w = v3 - ls;
    *(float4*)op = o;
}

extern "C" void kernel_launch(void* const* d_in, const int* in_sizes, int n_in,
                              void* d_out, int out_size, void* d_ws, size_t ws_size,
                              hipStream_t stream) {
    const float* x = (const float*)d_in[0];
    const int* ei = (const int*)d_in[1];
    const float* Wl0 = (const float*)d_in[2];
    const float* bl0 = (const float*)d_in[3];
    const float* Wr0 = (const float*)d_in[4];
    const float* Wl1 = (const float*)d_in[5];
    const float* bl1 = (const float*)d_in[6];
    const float* Wr1 = (const float*)d_in[7];
    const float* Wl2 = (const float*)d_in[8];
    const float* bl2 = (const float*)d_in[9];
    const float* Wr2 = (const float*)d_in[10];

    const int N = in_sizes[0] / 128;
    const int E = in_sizes[1] / 2;
    const int* src = ei;
    const int* dst = ei + E;

    char* ws = (char*)d_ws;
    size_t off = 0;
    auto alloc = [&](size_t bytes) {
        void* p = ws + off;
        off += (bytes + 255) & ~(size_t)255;
        return p;
    };
    int* cntin = (int*)alloc((size_t)NB * B1 * 4);
    int* cntoff = (int*)alloc(((size_t)NB * B1 + 1) * 4);
    int* bsum = (int*)alloc(1024 * 4);
    unsigned int* ebuf = (unsigned int*)alloc((size_t)E * 4);
    int* rowptr = (int*)alloc((size_t)(N + 1) * 4);
    int* adj = (int*)alloc((size_t)E * 4);
    unsigned short* xb = (unsigned short*)alloc((size_t)N * 128 * 2);
    unsigned char* abuf = (unsigned char*)alloc((size_t)N * 128);  // fp8 aggr; reused as fp8 t2
    unsigned short* hA = (unsigned short*)alloc((size_t)N * 128 * 2);
    unsigned short* hB = (unsigned short*)alloc((size_t)N * 128 * 2);
    unsigned char* q8a = (unsigned char*)alloc((size_t)N * 128);  // fp8(x)
    unsigned char* q8b = (unsigned char*)alloc((size_t)N * 128);  // fp8(h0)
    unsigned short* w0 = (unsigned short*)alloc(8 * 8 * 64 * 8 * 2);
    unsigned short* w1 = (unsigned short*)alloc(8 * 8 * 64 * 8 * 2);
    unsigned short* w2 = (unsigned short*)alloc(4 * 8 * 64 * 8 * 2);

    // ---- bucketed CSR build ----
    const int NBUCK = (N + 255) >> 8;
    k_bhist<<<B1, 256, 0, stream>>>(dst, E, cntin);
    const int scanLen = NB * B1;
    const int nScanBlocks = (scanLen + SCAN_CHUNK - 1) / SCAN_CHUNK;
    k_scan_part<<<nScanBlocks, SCAN_T, 0, stream>>>(cntin, bsum, scanLen);
    k_scan_top<<<1, 64, 0, stream>>>(bsum, nScanBlocks);
    k_scan_apply<<<nScanBlocks, SCAN_T, 0, stream>>>(cntin, bsum, cntoff, scanLen);
    k_bscatter<<<B1, 256, 0, stream>>>(src, dst, E, cntoff, ebuf);
    k_build<<<NBUCK, 256, 0, stream>>>(ebuf, cntoff, rowptr, adj, N, E);

    // combined conversion + weight prep (one launch)
    const int cvtBlocks = ((N * 128 / 4) + 255) / 256;
    k_prep<<<cvtBlocks + 128 + 128 + 64, 256, 0, stream>>>(
        x, xb, q8a, N * 128 / 4, Wl0, Wr0, w0, Wl1, Wr1, w1, Wl2, Wr2, w2, cvtBlocks);

    const int aggrGrid = ((N * 32) + 255) / 256;
    const int aggr64Grid = ((N * 16) + 255) / 256;
    const int xfGrid = (N + 63) / 64;

    unsigned char* aggr = abuf;
    unsigned char* t2q = abuf;

    // layer 0: gather fp8(x) -> fp8 mean; xform -> hA bf16 + fp8(hA) in q8b
    k_aggr8<<<aggrGrid, 256, 0, stream>>>(q8a, rowptr, adj, aggr, N);
    k_xform<true><<<xfGrid, 256, 0, stream>>>(aggr, xb, w0, bl0, hA, q8b, N);
    // layer 1: gather fp8(hA) -> fp8 mean; xform -> hB
    k_aggr8<<<aggrGrid, 256, 0, stream>>>(q8b, rowptr, adj, aggr, N);
    k_xform<false><<<xfGrid, 256, 0, stream>>>(aggr, hA, w1, bl1, hB, nullptr, N);
    // layer 2: transform first (commutes with mean), then fused fp8 aggregate + log_softmax
    k_xform2<<<xfGrid, 256, 0, stream>>>(hB, w2, bl2, t2q, (float*)d_out, N);
    k_aggr64lsm<<<aggr64Grid, 256, 0, stream>>>(t2q, rowptr, adj, (float*)d_out, N);
}

// Round 12
// 252.949 us; speedup vs baseline: 2.9775x; 1.0013x over previous
//
#include <hip/hip_runtime.h>
#include <hip/hip_bf16.h>
#include <math.h>

typedef __attribute__((ext_vector_type(8))) short short8;
typedef __attribute__((ext_vector_type(4))) float floatx4;
typedef __attribute__((ext_vector_type(2))) float floatx2;
typedef __attribute__((ext_vector_type(4))) unsigned short ushortx4;

__device__ __forceinline__ float bf2f(unsigned short u) {
    union { unsigned int i; float f; } c; c.i = ((unsigned int)u) << 16; return c.f;
}
__device__ __forceinline__ unsigned short f2bf(float f) {
    union { float f; unsigned int i; } c; c.f = f;
    unsigned int x = c.i;
    return (unsigned short)((x + 0x7FFFu + ((x >> 16) & 1u)) >> 16);
}

// ---------- fp8 e4m3fn (OCP) encode/decode ----------
__device__ __forceinline__ unsigned char f2fp8(float f) {
    unsigned int u = __float_as_uint(f);
    unsigned int sign = (u >> 24) & 0x80u;
    unsigned int a = u & 0x7FFFFFFFu;
    if (a >= 0x43E00000u) return (unsigned char)(sign | 0x7Eu);  // saturate at 448
    if (a < 0x3C800000u) {  // below smallest normal 2^-6: denormal units of 2^-9
        int unit = (int)rintf(__uint_as_float(a) * 512.0f);
        return (unsigned char)(sign | (unsigned int)unit);
    }
    unsigned int r = a + 0x7FFFFu + ((a >> 20) & 1u);  // RNE at bit 20
    unsigned int e = (r >> 23) - 120u;
    unsigned int m = (r >> 20) & 7u;
    return (unsigned char)(sign | (e << 3) | m);
}

__device__ __forceinline__ float fp8dec1(unsigned int b) {
    unsigned int s = (b & 0x80u) << 24;
    unsigned int mag = (b & 0x7Fu) << 20;
    return __uint_as_float(s | mag) * __uint_as_float(0x7B800000u);  // * 2^120
}

template <bool W>
__device__ __forceinline__ floatx2 fp8pk2f(unsigned int v) {
#if defined(__has_builtin) && __has_builtin(__builtin_amdgcn_cvt_pk_f32_fp8)
    return __builtin_amdgcn_cvt_pk_f32_fp8(v, W);
#else
    floatx2 r;
    r[0] = fp8dec1((v >> (W ? 16 : 0)) & 0xFFu);
    r[1] = fp8dec1((v >> (W ? 24 : 8)) & 0xFFu);
    return r;
#endif
}

// decode 8 fp8 (as uint2) -> bf16x8 MFMA A-fragment (exact: e4m3 subset of bf16)
__device__ __forceinline__ short8 fp8x8_to_bf16x8(uint2 q) {
    floatx2 p0 = fp8pk2f<false>(q.x), p1 = fp8pk2f<true>(q.x);
    floatx2 p2 = fp8pk2f<false>(q.y), p3 = fp8pk2f<true>(q.y);
    short8 a;
    a[0] = (short)f2bf(p0[0]); a[1] = (short)f2bf(p0[1]);
    a[2] = (short)f2bf(p1[0]); a[3] = (short)f2bf(p1[1]);
    a[4] = (short)f2bf(p2[0]); a[5] = (short)f2bf(p2[1]);
    a[6] = (short)f2bf(p3[0]); a[7] = (short)f2bf(p3[1]);
    return a;
}

// ================= bucketed CSR build =================
constexpr int NB = 512;
constexpr int B1 = 256;

__global__ __launch_bounds__(256) void k_bhist(const int* dst, int E, int* cnt) {
    __shared__ int h[NB];
    int t = threadIdx.x, b = blockIdx.x;
    h[t] = 0; h[t + 256] = 0;
    __syncthreads();
    int chunk = (E + B1 - 1) / B1;
    int lo = b * chunk, hi = min(E, lo + chunk);
    for (int e = lo + t; e < hi; e += 256) atomicAdd(&h[dst[e] >> 8], 1);
    __syncthreads();
    cnt[(size_t)t * B1 + b] = h[t];
    cnt[(size_t)(t + 256) * B1 + b] = h[t + 256];
}

constexpr int SCAN_T = 256;
constexpr int SCAN_V = 8;
constexpr int SCAN_CHUNK = SCAN_T * SCAN_V;

__global__ void k_scan_part(const int* in, int* bsum, int N) {
    int b = blockIdx.x, t = threadIdx.x;
    int base = b * SCAN_CHUNK + t * SCAN_V;
    int s = 0;
#pragma unroll
    for (int j = 0; j < SCAN_V; j++) {
        int i = base + j;
        if (i < N) s += in[i];
    }
    __shared__ int wsums[SCAN_T / 64];
    for (int off = 32; off; off >>= 1) s += __shfl_down(s, off, 64);
    if ((t & 63) == 0) wsums[t >> 6] = s;
    __syncthreads();
    if (t == 0) {
        int tot = 0;
#pragma unroll
        for (int w = 0; w < SCAN_T / 64; w++) tot += wsums[w];
        bsum[b] = tot;
    }
}

__global__ void k_scan_top(int* bsum, int nb) {
    if (threadIdx.x == 0) {
        int run = 0;
        for (int i = 0; i < nb; i++) {
            int v = bsum[i];
            bsum[i] = run;
            run += v;
        }
    }
}

__global__ void k_scan_apply(const int* in, const int* bsum, int* out, int N) {
    int b = blockIdx.x, t = threadIdx.x;
    int base = b * SCAN_CHUNK + t * SCAN_V;
    int v[SCAN_V];
    int s = 0;
#pragma unroll
    for (int j = 0; j < SCAN_V; j++) {
        int i = base + j;
        v[j] = (i < N) ? in[i] : 0;
        s += v[j];
    }
    __shared__ int sums[SCAN_T];
    sums[t] = s;
    __syncthreads();
    for (int off = 1; off < SCAN_T; off <<= 1) {
        int x = (t >= off) ? sums[t - off] : 0;
        __syncthreads();
        sums[t] += x;
        __syncthreads();
    }
    int pre = bsum[b] + ((t == 0) ? 0 : sums[t - 1]);
#pragma unroll
    for (int j = 0; j < SCAN_V; j++) {
        int i = base + j;
        if (i < N) {
            out[i] = pre;
            pre += v[j];
            if (i == N - 1) out[N] = pre;
        }
    }
}

__global__ __launch_bounds__(256) void k_bscatter(const int* src, const int* dst, int E,
                                                  const int* cntoff, unsigned int* ebuf) {
    __shared__ int base[NB];
    __shared__ int lcur[NB];
    int t = threadIdx.x, b = blockIdx.x;
    for (int i = t; i < NB; i += 256) {
        base[i] = cntoff[(size_t)i * B1 + b];
        lcur[i] = 0;
    }
    __syncthreads();
    int chunk = (E + B1 - 1) / B1;
    int lo = b * chunk, hi = min(E, lo + chunk);
    for (int e = lo + t; e < hi; e += 256) {
        int d = dst[e];
        int cb = d >> 8;
        int slot = atomicAdd(&lcur[cb], 1);
        ebuf[base[cb] + slot] = (unsigned int)src[e] | ((unsigned int)(d & 255) << 17);
    }
}

__global__ __launch_bounds__(256) void k_build(const unsigned int* ebuf, const int* cntoff,
                                               int* rowptr, int* adj, int N, int E) {
    __shared__ int ldeg[256];
    __shared__ int lptr[256];
    __shared__ int lcur[256];
    __shared__ int tsum[256];
    int t = threadIdx.x, cb = blockIdx.x;
    int bbase = cntoff[(size_t)cb * B1];
    int bend = cntoff[(size_t)(cb + 1) * B1];
    ldeg[t] = 0;
    lcur[t] = 0;
    __syncthreads();
    for (int e = bbase + t; e < bend; e += 256) atomicAdd(&ldeg[ebuf[e] >> 17], 1);
    __syncthreads();
    tsum[t] = ldeg[t];
    __syncthreads();
    for (int off = 1; off < 256; off <<= 1) {
        int v = (t >= off) ? tsum[t - off] : 0;
        __syncthreads();
        tsum[t] += v;
        __syncthreads();
    }
    lptr[t] = tsum[t] - ldeg[t];
    __syncthreads();
    int node = cb * 256 + t;
    if (node < N) rowptr[node] = bbase + lptr[t];
    if (cb == 0 && t == 0) rowptr[N] = E;
    for (int e = bbase + t; e < bend; e += 256) {
        unsigned int pk = ebuf[e];
        int dl = pk >> 17;
        int ls = atomicAdd(&lcur[dl], 1);
        adj[bbase + lptr[dl] + ls] = (int)(pk & 0x1FFFF);
    }
}

// ---------------- combined prep: x->fp8 conversion AND 3x weight prep ----------------
__device__ __forceinline__ void prep_w_body(const float* Wl, const float* Wr,
                                            unsigned short* wf, int NOC, int t) {
    int total = 8 * NOC * 64 * 8;
    if (t >= total) return;
    int j = t & 7;
    int lane = (t >> 3) & 63;
    int rest = t >> 9;
    int oc = rest % NOC;
    int ks = rest / NOC;
    int k = ks * 32 + ((lane >> 4) << 3) + j;
    int o = oc * 16 + (lane & 15);
    float v = (k < 128) ? Wl[o * 128 + k] : Wr[o * 128 + (k - 128)];
    wf[t] = f2bf(v);
}

__device__ __forceinline__ void prep_w2_body(const float* Wl, const float* Wr,
                                             unsigned short* wf, int t) {
    int total = 4 * 8 * 64 * 8;
    if (t >= total) return;
    int j = t & 7;
    int lane = (t >> 3) & 63;
    int rest = t >> 9;
    int oc = rest % 8;
    int ks = rest / 8;
    int k = ks * 32 + ((lane >> 4) << 3) + j;
    int o16 = lane & 15;
    float v = (oc < 4) ? Wl[(oc * 16 + o16) * 128 + k] : Wr[((oc - 4) * 16 + o16) * 128 + k];
    wf[t] = f2bf(v);
}

__global__ __launch_bounds__(256) void k_prep(const float* x, unsigned char* xq, int n4,
                                              const float* Wl0, const float* Wr0, unsigned short* w0,
                                              const float* Wl1, const float* Wr1, unsigned short* w1,
                                              const float* Wl2, const float* Wr2, unsigned short* w2,
                                              int cvtBlocks) {
    int b = blockIdx.x;
    if (b < cvtBlocks) {
        int i = b * 256 + threadIdx.x;
        int idx = i * 4;
        if (idx < n4 * 4) {
            float4 v = *(const float4*)(x + idx);
            unsigned int qw = (unsigned int)f2fp8(v.x) | ((unsigned int)f2fp8(v.y) << 8) |
                              ((unsigned int)f2fp8(v.z) << 16) | ((unsigned int)f2fp8(v.w) << 24);
            *(unsigned int*)(xq + idx) = qw;
        }
    } else if (b < cvtBlocks + 128) {
        prep_w_body(Wl0, Wr0, w0, 8, (b - cvtBlocks) * 256 + threadIdx.x);
    } else if (b < cvtBlocks + 256) {
        prep_w_body(Wl1, Wr1, w1, 8, (b - cvtBlocks - 128) * 256 + threadIdx.x);
    } else {
        prep_w2_body(Wl2, Wr2, w2, (b - cvtBlocks - 256) * 256 + threadIdx.x);
    }
}

// ---------------- fp8 mean aggregation -> fp8 mean (32-lane group per node) ----------------
__global__ __launch_bounds__(256) void k_aggr8(const unsigned char* feat, const int* rowptr,
                                               const int* adj, unsigned char* aggr, int N) {
    int g = (blockIdx.x * blockDim.x + threadIdx.x) >> 5;
    int lane = threadIdx.x & 31;
    if (g >= N) return;
    int lo = rowptr[g], hi = rowptr[g + 1];
    float a0 = 0.f, a1 = 0.f, a2 = 0.f, a3 = 0.f;
    const unsigned char* fb = feat + lane * 4;
    int j = lo;
    for (; j + 8 <= hi; j += 8) {
        unsigned int v[8];
#pragma unroll
        for (int u = 0; u < 8; u++) {
            int s = adj[j + u];
            v[u] = *(const unsigned int*)(fb + (size_t)s * 128);
        }
#pragma unroll
        for (int u = 0; u < 8; u++) {
            floatx2 l2 = fp8pk2f<false>(v[u]);
            floatx2 h2 = fp8pk2f<true>(v[u]);
            a0 += l2[0]; a1 += l2[1]; a2 += h2[0]; a3 += h2[1];
        }
    }
    if (j < hi) {  // masked tail chunk: loads issued back-to-back
        unsigned int v[8];
        float w[8];
#pragma unroll
        for (int u = 0; u < 8; u++) {
            int jj = j + u;
            int s = adj[jj < hi ? jj : hi - 1];
            v[u] = *(const unsigned int*)(fb + (size_t)s * 128);
            w[u] = (jj < hi) ? 1.0f : 0.0f;
        }
#pragma unroll
        for (int u = 0; u < 8; u++) {
            floatx2 l2 = fp8pk2f<false>(v[u]);
            floatx2 h2 = fp8pk2f<true>(v[u]);
            a0 = fmaf(w[u], l2[0], a0);
            a1 = fmaf(w[u], l2[1], a1);
            a2 = fmaf(w[u], h2[0], a2);
            a3 = fmaf(w[u], h2[1], a3);
        }
    }
    float inv = 1.0f / (float)max(hi - lo, 1);
    unsigned int qw = (unsigned int)f2fp8(a0 * inv) | ((unsigned int)f2fp8(a1 * inv) << 8) |
                      ((unsigned int)f2fp8(a2 * inv) << 16) | ((unsigned int)f2fp8(a3 * inv) << 24);
    *(unsigned int*)(aggr + (size_t)g * 128 + lane * 4) = qw;
}

// ---------------- fused transform (DO=128, relu): outq = fp8(relu([aggr|feat] @ W + b)) ----------------
// all activations fp8; decode to bf16 (exact) for the MFMA
__global__ __launch_bounds__(256) void k_xform(const unsigned char* aggr,
                                               const unsigned char* featq,
                                               const unsigned short* w2f,
                                               const float* bias, unsigned char* outq, int N) {
    __shared__ unsigned short st[64][132];
    const int wave = threadIdx.x >> 6;
    const int lane = threadIdx.x & 63;
    const int row = blockIdx.x * 64 + wave * 16 + (lane & 15);
    const int kq = lane >> 4;
    floatx4 acc[8];
#pragma unroll
    for (int i = 0; i < 8; i++) acc[i] = (floatx4)0.0f;
    const bool rowOK = row < N;
    const unsigned char* arow = aggr + (size_t)row * 128;
    const unsigned char* frow = featq + (size_t)row * 128;
    const short8* bbase = (const short8*)w2f;
#pragma unroll
    for (int ks = 0; ks < 8; ks++) {
        short8 a;
        if (!rowOK) {
            a = (short8)0;
        } else {
            const unsigned char* p =
                (ks < 4) ? (arow + ks * 32 + kq * 8) : (frow + (ks - 4) * 32 + kq * 8);
            a = fp8x8_to_bf16x8(*(const uint2*)p);
        }
#pragma unroll
        for (int oc = 0; oc < 8; oc++) {
            short8 b = bbase[(ks * 8 + oc) * 64 + lane];
            acc[oc] = __builtin_amdgcn_mfma_f32_16x16x32_bf16(a, b, acc[oc], 0, 0, 0);
        }
    }
    const int rl = wave * 16 + kq * 4;
#pragma unroll
    for (int oc = 0; oc < 8; oc++) {
        int o = oc * 16 + (lane & 15);
        float bv = bias[o];
#pragma unroll
        for (int j = 0; j < 4; j++) {
            float v = fmaxf(acc[oc][j] + bv, 0.0f);
            st[rl + j][o] = f2bf(v);
        }
    }
    __syncthreads();
    // coalesced fp8 stores: 512 chunks of 16 B
    const int bRow0 = blockIdx.x * 64;
    const int t = threadIdx.x;
#pragma unroll
    for (int i = 0; i < 2; i++) {
        int c = t + i * 256;
        int r = c >> 3;
        int pos = (c & 7) * 16;
        int node = bRow0 + r;
        if (node < N) {
            short8 v0 = *(const short8*)&st[r][pos];
            short8 v1 = *(const short8*)&st[r][pos + 8];
            unsigned int w[4];
#pragma unroll
            for (int q = 0; q < 2; q++) {
                w[q] = (unsigned int)f2fp8(bf2f((unsigned short)v0[q * 4 + 0])) |
                       ((unsigned int)f2fp8(bf2f((unsigned short)v0[q * 4 + 1])) << 8) |
                       ((unsigned int)f2fp8(bf2f((unsigned short)v0[q * 4 + 2])) << 16) |
                       ((unsigned int)f2fp8(bf2f((unsigned short)v0[q * 4 + 3])) << 24);
                w[q + 2] = (unsigned int)f2fp8(bf2f((unsigned short)v1[q * 4 + 0])) |
                           ((unsigned int)f2fp8(bf2f((unsigned short)v1[q * 4 + 1])) << 8) |
                           ((unsigned int)f2fp8(bf2f((unsigned short)v1[q * 4 + 2])) << 16) |
                           ((unsigned int)f2fp8(bf2f((unsigned short)v1[q * 4 + 3])) << 24);
            }
            uint4 u;
            u.x = w[0]; u.y = w[1]; u.z = w[2]; u.w = w[3];
            *(uint4*)(outq + (size_t)node * 128 + pos) = u;
        }
    }
}

// layer-2 split transform (fp8 input): t2 = h @ Wl2^T (fp8), self = h @ Wr2^T + bl2 (f32)
__global__ __launch_bounds__(256) void k_xform2(const unsigned char* featq,
                                                const unsigned short* wf,
                                                const float* bias,
                                                unsigned char* t2q, float* out, int N) {
    __shared__ unsigned short st[64][68];
    const int wave = threadIdx.x >> 6;
    const int lane = threadIdx.x & 63;
    const int nodeBase = blockIdx.x * 64 + wave * 16;
    const int row = nodeBase + (lane & 15);
    const int kq = lane >> 4;
    floatx4 acc[8];
#pragma unroll
    for (int i = 0; i < 8; i++) acc[i] = (floatx4)0.0f;
    const bool rowOK = row < N;
    const unsigned char* frow = featq + (size_t)row * 128;
    const short8* bbase = (const short8*)wf;
#pragma unroll
    for (int ks = 0; ks < 4; ks++) {
        short8 a;
        if (rowOK)
            a = fp8x8_to_bf16x8(*(const uint2*)(frow + ks * 32 + kq * 8));
        else
            a = (short8)0;
#pragma unroll
        for (int oc = 0; oc < 8; oc++) {
            short8 b = bbase[(ks * 8 + oc) * 64 + lane];
            acc[oc] = __builtin_amdgcn_mfma_f32_16x16x32_bf16(a, b, acc[oc], 0, 0, 0);
        }
    }
    const int rl = wave * 16 + kq * 4;
    const int o16 = lane & 15;
#pragma unroll
    for (int oc = 0; oc < 8; oc++) {
#pragma unroll
        for (int j = 0; j < 4; j++) {
            int node = nodeBase + kq * 4 + j;
            if (oc < 4) {
                st[rl + j][oc * 16 + o16] = f2bf(acc[oc][j]);
            } else if (node < N) {
                int o = (oc - 4) * 16 + o16;
                out[(size_t)node * 64 + o] = acc[oc][j] + bias[o];
            }
        }
    }
    __syncthreads();
    // coalesced fp8 t2 stores: 256 chunks of 16 B
    const int bRow0 = blockIdx.x * 64;
    const int t = threadIdx.x;
    {
        int r = t >> 2;
        int pos = (t & 3) * 16;
        int node = bRow0 + r;
        if (node < N) {
            short8 v0 = *(const short8*)&st[r][pos];
            short8 v1 = *(const short8*)&st[r][pos + 8];
            unsigned int w[4];
#pragma unroll
            for (int q = 0; q < 2; q++) {
                w[q] = (unsigned int)f2fp8(bf2f((unsigned short)v0[q * 4 + 0])) |
                       ((unsigned int)f2fp8(bf2f((unsigned short)v0[q * 4 + 1])) << 8) |
                       ((unsigned int)f2fp8(bf2f((unsigned short)v0[q * 4 + 2])) << 16) |
                       ((unsigned int)f2fp8(bf2f((unsigned short)v0[q * 4 + 3])) << 24);
                w[q + 2] = (unsigned int)f2fp8(bf2f((unsigned short)v1[q * 4 + 0])) |
                           ((unsigned int)f2fp8(bf2f((unsigned short)v1[q * 4 + 1])) << 8) |
                           ((unsigned int)f2fp8(bf2f((unsigned short)v1[q * 4 + 2])) << 16) |
                           ((unsigned int)f2fp8(bf2f((unsigned short)v1[q * 4 + 3])) << 24);
            }
            uint4 u;
            u.x = w[0]; u.y = w[1]; u.z = w[2]; u.w = w[3];
            *(uint4*)(t2q + (size_t)node * 64 + pos) = u;
        }
    }
}

// 64-wide fp8 mean aggregation of t2 + add self + fused log_softmax (16-lane group/node)
__global__ __launch_bounds__(256) void k_aggr64lsm(const unsigned char* t2q, const int* rowptr,
                                                   const int* adj, float* out, int N) {
    int g = (blockIdx.x * blockDim.x + threadIdx.x) >> 4;
    int lane = threadIdx.x & 15;
    if (g >= N) return;
    int lo = rowptr[g], hi = rowptr[g + 1];
    float a0 = 0.f, a1 = 0.f, a2 = 0.f, a3 = 0.f;
    const unsigned char* fb = t2q + lane * 4;
    int j = lo;
    for (; j + 8 <= hi; j += 8) {
        unsigned int v[8];
#pragma unroll
        for (int u = 0; u < 8; u++) {
            int s = adj[j + u];
            v[u] = *(const unsigned int*)(fb + (size_t)s * 64);
        }
#pragma unroll
        for (int u = 0; u < 8; u++) {
            floatx2 l2 = fp8pk2f<false>(v[u]);
            floatx2 h2 = fp8pk2f<true>(v[u]);
            a0 += l2[0]; a1 += l2[1]; a2 += h2[0]; a3 += h2[1];
        }
    }
    if (j < hi) {
        unsigned int v[8];
        float w[8];
#pragma unroll
        for (int u = 0; u < 8; u++) {
            int jj = j + u;
            int s = adj[jj < hi ? jj : hi - 1];
            v[u] = *(const unsigned int*)(fb + (size_t)s * 64);
            w[u] = (jj < hi) ? 1.0f : 0.0f;
        }
#pragma unroll
        for (int u = 0; u < 8; u++) {
            floatx2 l2 = fp8pk2f<false>(v[u]);
            floatx2 h2 = fp8pk2f<true>(v[u]);
            a0 = fmaf(w[u], l2[0], a0);
            a1 = fmaf(w[u], l2[1], a1);
            a2 = fmaf(w[u], h2[0], a2);
            a3 = fmaf(w[u], h2[1], a3);
        }
    }
    float inv = 1.0f / (float)max(hi - lo, 1);
    float* op = out + (size_t)g * 64 + lane * 4;
    float4 cur = *(float4*)op;
    float v0 = cur.x + a0 * inv, v1 = cur.y + a1 * inv;
    float v2 = cur.z + a2 * inv, v3 = cur.w + a3 * inv;
    float m = fmaxf(fmaxf(v0, v1), fmaxf(v2, v3));
#pragma unroll
    for (int off = 8; off; off >>= 1) m = fmaxf(m, __shfl_xor(m, off));
    float s = expf(v0 - m) + expf(v1 - m) + expf(v2 - m) + expf(v3 - m);
#pragma unroll
    for (int off = 8; off; off >>= 1) s += __shfl_xor(s, off);
    float ls = m + logf(s);
    float4 o;
    o.x = v0 - ls; o.y = v1 - ls; o.z = v2 - ls; o.w = v3 - ls;
    *(float4*)op = o;
}

extern "C" void kernel_launch(void* const* d_in, const int* in_sizes, int n_in,
                              void* d_out, int out_size, void* d_ws, size_t ws_size,
                              hipStream_t stream) {
    const float* x = (const float*)d_in[0];
    const int* ei = (const int*)d_in[1];
    const float* Wl0 = (const float*)d_in[2];
    const float* bl0 = (const float*)d_in[3];
    const float* Wr0 = (const float*)d_in[4];
    const float* Wl1 = (const float*)d_in[5];
    const float* bl1 = (const float*)d_in[6];
    const float* Wr1 = (const float*)d_in[7];
    const float* Wl2 = (const float*)d_in[8];
    const float* bl2 = (const float*)d_in[9];
    const float* Wr2 = (const float*)d_in[10];

    const int N = in_sizes[0] / 128;
    const int E = in_sizes[1] / 2;
    const int* src = ei;
    const int* dst = ei + E;

    char* ws = (char*)d_ws;
    size_t off = 0;
    auto alloc = [&](size_t bytes) {
        void* p = ws + off;
        off += (bytes + 255) & ~(size_t)255;
        return p;
    };
    int* cntin = (int*)alloc((size_t)NB * B1 * 4);
    int* cntoff = (int*)alloc(((size_t)NB * B1 + 1) * 4);
    int* bsum = (int*)alloc(1024 * 4);
    unsigned int* ebuf = (unsigned int*)alloc((size_t)E * 4);
    int* rowptr = (int*)alloc((size_t)(N + 1) * 4);
    int* adj = (int*)alloc((size_t)E * 4);
    unsigned char* abuf = (unsigned char*)alloc((size_t)N * 128);  // fp8 aggr; reused as fp8 t2
    unsigned char* q8a = (unsigned char*)alloc((size_t)N * 128);   // fp8(x)
    unsigned char* q8b = (unsigned char*)alloc((size_t)N * 128);   // fp8(h0)
    unsigned char* q8c = (unsigned char*)alloc((size_t)N * 128);   // fp8(h1)
    unsigned short* w0 = (unsigned short*)alloc(8 * 8 * 64 * 8 * 2);
    unsigned short* w1 = (unsigned short*)alloc(8 * 8 * 64 * 8 * 2);
    unsigned short* w2 = (unsigned short*)alloc(4 * 8 * 64 * 8 * 2);

    // ---- bucketed CSR build ----
    const int NBUCK = (N + 255) >> 8;
    k_bhist<<<B1, 256, 0, stream>>>(dst, E, cntin);
    const int scanLen = NB * B1;
    const int nScanBlocks = (scanLen + SCAN_CHUNK - 1) / SCAN_CHUNK;
    k_scan_part<<<nScanBlocks, SCAN_T, 0, stream>>>(cntin, bsum, scanLen);
    k_scan_top<<<1, 64, 0, stream>>>(bsum, nScanBlocks);
    k_scan_apply<<<nScanBlocks, SCAN_T, 0, stream>>>(cntin, bsum, cntoff, scanLen);
    k_bscatter<<<B1, 256, 0, stream>>>(src, dst, E, cntoff, ebuf);
    k_build<<<NBUCK, 256, 0, stream>>>(ebuf, cntoff, rowptr, adj, N, E);

    // combined conversion + weight prep (one launch)
    const int cvtBlocks = ((N * 128 / 4) + 255) / 256;
    k_prep<<<cvtBlocks + 128 + 128 + 64, 256, 0, stream>>>(
        x, q8a, N * 128 / 4, Wl0, Wr0, w0, Wl1, Wr1, w1, Wl2, Wr2, w2, cvtBlocks);

    const int aggrGrid = ((N * 32) + 255) / 256;
    const int aggr64Grid = ((N * 16) + 255) / 256;
    const int xfGrid = (N + 63) / 64;

    unsigned char* aggr = abuf;
    unsigned char* t2q = abuf;

    // layer 0: gather fp8(x) -> fp8 mean; xform([aggr|x]) -> fp8(h0)
    k_aggr8<<<aggrGrid, 256, 0, stream>>>(q8a, rowptr, adj, aggr, N);
    k_xform<<<xfGrid, 256, 0, stream>>>(aggr, q8a, w0, bl0, q8b, N);
    // layer 1: gather fp8(h0) -> fp8 mean; xform([aggr|h0]) -> fp8(h1)
    k_aggr8<<<aggrGrid, 256, 0, stream>>>(q8b, rowptr, adj, aggr, N);
    k_xform<<<xfGrid, 256, 0, stream>>>(aggr, q8b, w1, bl1, q8c, N);
    // layer 2: transform first (commutes with mean), then fused fp8 aggregate + log_softmax
    k_xform2<<<xfGrid, 256, 0, stream>>>(q8c, w2, bl2, t2q, (float*)d_out, N);
    k_aggr64lsm<<<aggr64Grid, 256, 0, stream>>>(t2q, rowptr, adj, (float*)d_out, N);
}